// Round 1
// baseline (30363.849 us; speedup 1.0000x reference)
//
#include <hip/hip_runtime.h>
#include <cstddef>

#define DM    1024     // model dim
#define TSEQ  1024     // seq len
#define NB    2        // batch
#define NHEAD 16
#define HDIM  64
#define NLAYER 8
#define DFFN  4096
#define NVOC  32000
#define NROWS (NB*TSEQ) // 2048

// ---------------- embedding + positional encoding ----------------
__global__ __launch_bounds__(256)
void embed_pos_k(const int* __restrict__ idx, const float* __restrict__ embed,
                 float* __restrict__ x)
{
    int row = blockIdx.x;            // b*TSEQ + t
    int t   = row & (TSEQ - 1);
    int tid = threadIdx.x;
    int token = idx[row];
    const float* er = embed + (size_t)token * DM;
    float* xr = x + (size_t)row * DM;
    const float neg_ln1e4_over_d = -9.210340371976184f / (float)DM; // -ln(10000)/D
    for (int i = tid; i < DM; i += 256) {
        int half = i >> 1;
        float div = expf((float)(2 * half) * neg_ln1e4_over_d);
        float ang = (float)t * div;
        float pe = (i & 1) ? cosf(ang) : sinf(ang);
        xr[i] = er[i] + pe;
    }
}

// ---------------- layernorm (one row per block) ----------------
__global__ __launch_bounds__(256)
void layernorm_k(const float* __restrict__ x, const float* __restrict__ g,
                 const float* __restrict__ b, float* __restrict__ y)
{
    int row = blockIdx.x;
    int tid = threadIdx.x;
    const float* xr = x + (size_t)row * DM;
    float* yr = y + (size_t)row * DM;
    float vals[4];
    float s = 0.f;
    #pragma unroll
    for (int i = 0; i < 4; ++i) { vals[i] = xr[tid + 256 * i]; s += vals[i]; }
    __shared__ float red[256];
    red[tid] = s; __syncthreads();
    for (int st = 128; st > 0; st >>= 1) {
        if (tid < st) red[tid] += red[tid + st];
        __syncthreads();
    }
    float mu = red[0] * (1.f / DM);
    __syncthreads();
    float v = 0.f;
    #pragma unroll
    for (int i = 0; i < 4; ++i) { float d = vals[i] - mu; v += d * d; }
    red[tid] = v; __syncthreads();
    for (int st = 128; st > 0; st >>= 1) {
        if (tid < st) red[tid] += red[tid + st];
        __syncthreads();
    }
    float rstd = rsqrtf(red[0] * (1.f / DM) + 1e-5f);
    #pragma unroll
    for (int i = 0; i < 4; ++i) {
        int c = tid + 256 * i;
        yr[c] = (vals[i] - mu) * rstd * g[c] + b[c];
    }
}

// ---------------- tiled f32 GEMM with fused epilogue ----------------
// C[M,N] = (residual? residual : 0) + A[M,K] @ B[K,N] + (bias? bias : 0), opt ReLU
// block(16,16); each thread computes 4x4; tile 64x64x16.
#define BM 64
#define BN 64
#define BK 16
__global__ __launch_bounds__(256)
void gemm_f32(const float* __restrict__ A, const float* __restrict__ B,
              const float* __restrict__ bias, const float* __restrict__ residual,
              float* __restrict__ C, int M, int N, int K, int relu)
{
    __shared__ float As[BK][BM + 1];
    __shared__ float Bs[BK][BN + 1];
    int bx = blockIdx.x, by = blockIdx.y;
    int tx = threadIdx.x, ty = threadIdx.y;
    int tid = ty * 16 + tx;
    int row0 = by * BM, col0 = bx * BN;
    float acc[4][4] = {};
    for (int k0 = 0; k0 < K; k0 += BK) {
        for (int i = tid; i < BM * BK; i += 256) {
            int r = i / BK, c = i % BK;
            As[c][r] = A[(size_t)(row0 + r) * K + k0 + c];
        }
        for (int i = tid; i < BK * BN; i += 256) {
            int r = i / BN, c = i % BN;
            Bs[r][c] = B[(size_t)(k0 + r) * N + col0 + c];
        }
        __syncthreads();
        #pragma unroll
        for (int kk = 0; kk < BK; ++kk) {
            float a[4], bb[4];
            #pragma unroll
            for (int i = 0; i < 4; ++i) a[i] = As[kk][ty * 4 + i];
            #pragma unroll
            for (int j = 0; j < 4; ++j) bb[j] = Bs[kk][tx * 4 + j];
            #pragma unroll
            for (int i = 0; i < 4; ++i)
                #pragma unroll
                for (int j = 0; j < 4; ++j)
                    acc[i][j] += a[i] * bb[j];
        }
        __syncthreads();
    }
    #pragma unroll
    for (int i = 0; i < 4; ++i) {
        int r = row0 + ty * 4 + i;
        #pragma unroll
        for (int j = 0; j < 4; ++j) {
            int c = col0 + tx * 4 + j;
            float v = acc[i][j];
            if (bias) v += bias[c];
            if (residual) v += residual[(size_t)r * N + c];
            if (relu) v = fmaxf(v, 0.f);
            C[(size_t)r * N + c] = v;
        }
    }
}

// ---------------- fused causal attention, one (b,h,q) per block ----------------
// qkv layout per row: [3][H][HD] (i*DM + h*HDIM + d)
__global__ __launch_bounds__(256)
void attn_fused_k(const float* __restrict__ qkv, float* __restrict__ out)
{
    int tq = blockIdx.x;
    int h  = blockIdx.y;
    int b  = blockIdx.z;
    int tid = threadIdx.x;
    const float scale = 0.125f; // 1/sqrt(64)

    __shared__ float qs[HDIM];
    __shared__ float sc[TSEQ];
    __shared__ float red[256];

    const float* base = qkv + (size_t)b * TSEQ * 3 * DM;
    const float* qrow = base + (size_t)tq * 3 * DM + h * HDIM; // q block
    if (tid < HDIM) qs[tid] = qrow[tid];
    __syncthreads();

    int nk = tq + 1; // causal: keys 0..tq inclusive
    // scores
    for (int k = tid; k < nk; k += 256) {
        const float* krow = base + (size_t)k * 3 * DM + DM + h * HDIM;
        float s = 0.f;
        #pragma unroll
        for (int d = 0; d < HDIM; ++d) s += qs[d] * krow[d];
        sc[k] = s * scale;
    }
    __syncthreads();
    // max
    float m = -INFINITY;
    for (int k = tid; k < nk; k += 256) m = fmaxf(m, sc[k]);
    red[tid] = m; __syncthreads();
    for (int st = 128; st > 0; st >>= 1) {
        if (tid < st) red[tid] = fmaxf(red[tid], red[tid + st]);
        __syncthreads();
    }
    m = red[0]; __syncthreads();
    // exp + sum
    float sum = 0.f;
    for (int k = tid; k < nk; k += 256) {
        float e = __expf(sc[k] - m);
        sc[k] = e;
        sum += e;
    }
    red[tid] = sum; __syncthreads();
    for (int st = 128; st > 0; st >>= 1) {
        if (tid < st) red[tid] += red[tid + st];
        __syncthreads();
    }
    float inv = 1.f / red[0];
    __syncthreads();
    // PV: thread t handles d = t&63, k-chunk = t>>6 (4 chunks)
    int d = tid & 63, chunk = tid >> 6;
    float o = 0.f;
    for (int k = chunk; k < nk; k += 4) {
        const float* vrow = base + (size_t)k * 3 * DM + 2 * DM + h * HDIM;
        o += sc[k] * vrow[d];
    }
    red[tid] = o; __syncthreads();
    if (tid < 64) {
        float t = red[tid] + red[tid + 64] + red[tid + 128] + red[tid + 192];
        out[((size_t)b * TSEQ + tq) * DM + h * HDIM + d] = t * inv;
    }
}

// ---------------- orchestration ----------------
extern "C" void kernel_launch(void* const* d_in, const int* in_sizes, int n_in,
                              void* d_out, int out_size, void* d_ws, size_t ws_size,
                              hipStream_t stream)
{
    const int*   idx    = (const int*)  d_in[0];
    const float* embed  = (const float*)d_in[1];
    const float* Wqkv   = (const float*)d_in[2];
    const float* Wproj  = (const float*)d_in[3];
    const float* bproj  = (const float*)d_in[4];
    const float* ln1_g  = (const float*)d_in[5];
    const float* ln1_b  = (const float*)d_in[6];
    const float* ln2_g  = (const float*)d_in[7];
    const float* ln2_b  = (const float*)d_in[8];
    const float* W1     = (const float*)d_in[9];
    const float* b1     = (const float*)d_in[10];
    const float* W2     = (const float*)d_in[11];
    const float* b2     = (const float*)d_in[12];
    const float* lnf_g  = (const float*)d_in[13];
    const float* lnf_b  = (const float*)d_in[14];
    const float* Whead  = (const float*)d_in[15];
    float* out = (float*)d_out;

    float* ws = (float*)d_ws;
    float* X    = ws;                         // 2048*1024
    float* T1   = X   + (size_t)NROWS * DM;   // 2048*1024
    float* QKV  = T1  + (size_t)NROWS * DM;   // 2048*3072
    float* ATT  = QKV + (size_t)NROWS * 3 * DM; // 2048*1024
    float* FFH  = ATT + (size_t)NROWS * DM;   // 2048*4096

    dim3 gblk(16, 16);

    // embedding + positional encoding
    embed_pos_k<<<NROWS, 256, 0, stream>>>(idx, embed, X);

    for (int l = 0; l < NLAYER; ++l) {
        const float* wqkv_l  = Wqkv  + (size_t)l * DM * 3 * DM;
        const float* wproj_l = Wproj + (size_t)l * DM * DM;
        const float* bproj_l = bproj + (size_t)l * DM;
        const float* w1_l = W1 + (size_t)l * DM * DFFN;
        const float* b1_l = b1 + (size_t)l * DFFN;
        const float* w2_l = W2 + (size_t)l * DFFN * DM;
        const float* b2_l = b2 + (size_t)l * DM;

        // ln1
        layernorm_k<<<NROWS, 256, 0, stream>>>(X, ln1_g + (size_t)l * DM,
                                               ln1_b + (size_t)l * DM, T1);
        // qkv = ln1 @ Wqkv
        {
            dim3 grid(3 * DM / BN, NROWS / BM);
            gemm_f32<<<grid, gblk, 0, stream>>>(T1, wqkv_l, nullptr, nullptr,
                                                QKV, NROWS, 3 * DM, DM, 0);
        }
        // fused causal attention -> ATT
        {
            dim3 grid(TSEQ, NHEAD, NB);
            attn_fused_k<<<grid, 256, 0, stream>>>(QKV, ATT);
        }
        // x = x + ATT @ Wproj + bproj
        {
            dim3 grid(DM / BN, NROWS / BM);
            gemm_f32<<<grid, gblk, 0, stream>>>(ATT, wproj_l, bproj_l, X,
                                                X, NROWS, DM, DM, 0);
        }
        // ln2
        layernorm_k<<<NROWS, 256, 0, stream>>>(X, ln2_g + (size_t)l * DM,
                                               ln2_b + (size_t)l * DM, T1);
        // ffh = relu(ln2 @ W1 + b1)
        {
            dim3 grid(DFFN / BN, NROWS / BM);
            gemm_f32<<<grid, gblk, 0, stream>>>(T1, w1_l, b1_l, nullptr,
                                                FFH, NROWS, DFFN, DM, 1);
        }
        // x = x + ffh @ W2 + b2
        {
            dim3 grid(DM / BN, NROWS / BM);
            gemm_f32<<<grid, gblk, 0, stream>>>(FFH, w2_l, b2_l, X,
                                                X, NROWS, DM, DFFN, 0);
        }
    }

    // final layernorm
    layernorm_k<<<NROWS, 256, 0, stream>>>(X, lnf_g, lnf_b, T1);
    // logits = lnf(x) @ Whead
    {
        dim3 grid(NVOC / BN, NROWS / BM);
        gemm_f32<<<grid, gblk, 0, stream>>>(T1, Whead, nullptr, nullptr,
                                            out, NROWS, NVOC, DM, 0);
    }
}

// Round 2
// 8684.917 us; speedup vs baseline: 3.4962x; 3.4962x over previous
//
#include <hip/hip_runtime.h>
#include <cstddef>

#define DM    1024
#define TSEQ  1024
#define NB    2
#define NHEAD 16
#define HDIM  64
#define NLAYER 8
#define DFFN  4096
#define NVOC  32000
#define NROWS (NB*TSEQ)

typedef __attribute__((ext_vector_type(8))) short short8;
typedef __attribute__((ext_vector_type(4))) float f32x4;

static __device__ __forceinline__ unsigned short f2bf(float f) {
    union { float f; unsigned int u; } v; v.f = f;
    unsigned int r = v.u + 0x7FFF + ((v.u >> 16) & 1);   // RNE
    return (unsigned short)(r >> 16);
}

// ---------------- embedding + positional encoding (f32 out) ----------------
__global__ __launch_bounds__(256)
void embed_pos_k(const int* __restrict__ idx, const float* __restrict__ embed,
                 float* __restrict__ x)
{
    int row = blockIdx.x;
    int t   = row & (TSEQ - 1);
    int tid = threadIdx.x;
    int token = idx[row];
    const float* er = embed + (size_t)token * DM;
    float* xr = x + (size_t)row * DM;
    const float neg_ln1e4_over_d = -9.210340371976184f / (float)DM;
    for (int i = tid; i < DM; i += 256) {
        int half = i >> 1;
        float div = expf((float)(2 * half) * neg_ln1e4_over_d);
        float ang = (float)t * div;
        float pe = (i & 1) ? cosf(ang) : sinf(ang);
        xr[i] = er[i] + pe;
    }
}

// ---------------- layernorm (f32 in, bf16 out) ----------------
__global__ __launch_bounds__(256)
void layernorm_k(const float* __restrict__ x, const float* __restrict__ g,
                 const float* __restrict__ b, unsigned short* __restrict__ y)
{
    int row = blockIdx.x;
    int tid = threadIdx.x;
    const float* xr = x + (size_t)row * DM;
    unsigned short* yr = y + (size_t)row * DM;
    float vals[4];
    float s = 0.f;
    #pragma unroll
    for (int i = 0; i < 4; ++i) { vals[i] = xr[tid + 256 * i]; s += vals[i]; }
    __shared__ float red[256];
    red[tid] = s; __syncthreads();
    for (int st = 128; st > 0; st >>= 1) {
        if (tid < st) red[tid] += red[tid + st];
        __syncthreads();
    }
    float mu = red[0] * (1.f / DM);
    __syncthreads();
    float v = 0.f;
    #pragma unroll
    for (int i = 0; i < 4; ++i) { float d = vals[i] - mu; v += d * d; }
    red[tid] = v; __syncthreads();
    for (int st = 128; st > 0; st >>= 1) {
        if (tid < st) red[tid] += red[tid + st];
        __syncthreads();
    }
    float rstd = rsqrtf(red[0] * (1.f / DM) + 1e-5f);
    #pragma unroll
    for (int i = 0; i < 4; ++i) {
        int c = tid + 256 * i;
        yr[c] = f2bf((vals[i] - mu) * rstd * g[c] + b[c]);
    }
}

// ---------------- bf16 MFMA GEMM, 128x128 tile, BK=32 ----------------
// A: bf16 [M][K] row-major. B: f32 [K][N] (converted to bf16 in staging).
// C = A@B (+bias)(+residual)(relu?), out f32 or bf16.
template<bool OUT_BF16>
__global__ __launch_bounds__(256)
void gemm_bf16(const unsigned short* __restrict__ A, const float* __restrict__ B,
               const float* __restrict__ bias, const float* __restrict__ residual,
               void* __restrict__ Cout, int M, int N, int K, int relu)
{
    __shared__ unsigned short As[128][40];   // [m][k], pitch 80B (16B aligned)
    __shared__ unsigned short Bs[128][40];   // [n][k] transposed

    const int tid  = threadIdx.x;
    const int lane = tid & 63;
    const int wave = tid >> 6;
    const int wr = wave >> 1, wc = wave & 1;
    const int l16 = lane & 15, g = lane >> 4;
    const int row0 = blockIdx.y * 128, col0 = blockIdx.x * 128;

    f32x4 acc[4][4] = {};

    const int ar  = tid >> 1, acb = (tid & 1) << 4;   // A: row, k-half
    const int bn  = tid >> 1, bkb = (tid & 1) << 4;   // B: col n, k-half

    for (int k0 = 0; k0 < K; k0 += 32) {
        // ---- stage A (bf16 passthrough) ----
        const unsigned short* asrc = A + (size_t)(row0 + ar) * K + k0 + acb;
        short8 av0 = *(const short8*)asrc;
        short8 av1 = *(const short8*)(asrc + 8);
        // ---- stage B (f32 -> bf16, transpose into [n][k]) ----
        const float* bsrc = B + (size_t)(k0 + bkb) * N + col0 + bn;
        unsigned short bt[16];
        #pragma unroll
        for (int j = 0; j < 16; ++j) bt[j] = f2bf(bsrc[(size_t)j * N]);

        *(short8*)&As[ar][acb]     = av0;
        *(short8*)&As[ar][acb + 8] = av1;
        *(short8*)&Bs[bn][bkb]     = *(short8*)&bt[0];
        *(short8*)&Bs[bn][bkb + 8] = *(short8*)&bt[8];
        __syncthreads();

        short8 af[4], bfr[4];
        #pragma unroll
        for (int i = 0; i < 4; ++i)
            af[i] = *(const short8*)&As[wr * 64 + i * 16 + l16][g * 8];
        #pragma unroll
        for (int j = 0; j < 4; ++j)
            bfr[j] = *(const short8*)&Bs[wc * 64 + j * 16 + l16][g * 8];
        #pragma unroll
        for (int i = 0; i < 4; ++i)
            #pragma unroll
            for (int j = 0; j < 4; ++j)
                acc[i][j] = __builtin_amdgcn_mfma_f32_16x16x32_bf16(af[i], bfr[j], acc[i][j], 0, 0, 0);
        __syncthreads();
    }

    // ---- epilogue: C col = lane&15, row = g*4 + reg (verified layout) ----
    #pragma unroll
    for (int i = 0; i < 4; ++i) {
        #pragma unroll
        for (int j = 0; j < 4; ++j) {
            #pragma unroll
            for (int r = 0; r < 4; ++r) {
                int row = row0 + wr * 64 + i * 16 + g * 4 + r;
                int col = col0 + wc * 64 + j * 16 + l16;
                float v = acc[i][j][r];
                if (bias)     v += bias[col];
                if (residual) v += residual[(size_t)row * N + col];
                if (relu)     v = fmaxf(v, 0.f);
                if (OUT_BF16) ((unsigned short*)Cout)[(size_t)row * N + col] = f2bf(v);
                else          ((float*)Cout)[(size_t)row * N + col] = v;
            }
        }
    }
}

// ---------------- fused causal attention (f32 math, bf16 out) ----------------
// qkv row layout: [3][H][HD]; one (b,h,q) per block.
__global__ __launch_bounds__(256)
void attn_fused_k(const float* __restrict__ qkv, unsigned short* __restrict__ out)
{
    int tq = blockIdx.x;
    int h  = blockIdx.y;
    int b  = blockIdx.z;
    int tid = threadIdx.x;

    __shared__ float sc[TSEQ];
    __shared__ float red[256];
    __shared__ float red4[16][17][4];

    const float* base = qkv + (size_t)b * TSEQ * 3 * DM;
    const float* qrow = base + (size_t)tq * 3 * DM + h * HDIM;

    // q in registers (broadcast load)
    float qreg[HDIM];
    #pragma unroll
    for (int d = 0; d < HDIM; d += 4) {
        float4 t4 = *(const float4*)(qrow + d);
        qreg[d] = t4.x; qreg[d+1] = t4.y; qreg[d+2] = t4.z; qreg[d+3] = t4.w;
    }

    int nk = tq + 1;
    // scores
    for (int k = tid; k < nk; k += 256) {
        const float* krow = base + (size_t)k * 3 * DM + DM + h * HDIM;
        float s = 0.f;
        #pragma unroll
        for (int d = 0; d < HDIM; d += 4) {
            float4 kv = *(const float4*)(krow + d);
            s += qreg[d] * kv.x + qreg[d+1] * kv.y + qreg[d+2] * kv.z + qreg[d+3] * kv.w;
        }
        sc[k] = s * 0.125f;
    }
    __syncthreads();
    // max
    float m = -INFINITY;
    for (int k = tid; k < nk; k += 256) m = fmaxf(m, sc[k]);
    red[tid] = m; __syncthreads();
    for (int st = 128; st > 0; st >>= 1) {
        if (tid < st) red[tid] = fmaxf(red[tid], red[tid + st]);
        __syncthreads();
    }
    m = red[0]; __syncthreads();
    // exp + sum
    float sum = 0.f;
    for (int k = tid; k < nk; k += 256) {
        float e = __expf(sc[k] - m);
        sc[k] = e;
        sum += e;
    }
    red[tid] = sum; __syncthreads();
    for (int st = 128; st > 0; st >>= 1) {
        if (tid < st) red[tid] += red[tid + st];
        __syncthreads();
    }
    float inv = 1.f / red[0];
    __syncthreads();

    // PV: 16 d-groups (float4) x 16 k-chunks
    int dgrp = tid & 15, kc = tid >> 4;
    float4 o = make_float4(0.f, 0.f, 0.f, 0.f);
    for (int k = kc; k < nk; k += 16) {
        const float4* vrow = (const float4*)(base + (size_t)k * 3 * DM + 2 * DM + h * HDIM);
        float w = sc[k];
        float4 v = vrow[dgrp];
        o.x += w * v.x; o.y += w * v.y; o.z += w * v.z; o.w += w * v.w;
    }
    red4[kc][dgrp][0] = o.x; red4[kc][dgrp][1] = o.y;
    red4[kc][dgrp][2] = o.z; red4[kc][dgrp][3] = o.w;
    __syncthreads();
    if (tid < 64) {
        int d = tid;
        float s = 0.f;
        #pragma unroll
        for (int c = 0; c < 16; ++c) s += red4[c][d >> 2][d & 3];
        out[((size_t)b * TSEQ + tq) * DM + h * HDIM + d] = f2bf(s * inv);
    }
}

// ---------------- orchestration ----------------
extern "C" void kernel_launch(void* const* d_in, const int* in_sizes, int n_in,
                              void* d_out, int out_size, void* d_ws, size_t ws_size,
                              hipStream_t stream)
{
    const int*   idx    = (const int*)  d_in[0];
    const float* embed  = (const float*)d_in[1];
    const float* Wqkv   = (const float*)d_in[2];
    const float* Wproj  = (const float*)d_in[3];
    const float* bproj  = (const float*)d_in[4];
    const float* ln1_g  = (const float*)d_in[5];
    const float* ln1_b  = (const float*)d_in[6];
    const float* ln2_g  = (const float*)d_in[7];
    const float* ln2_b  = (const float*)d_in[8];
    const float* W1     = (const float*)d_in[9];
    const float* b1     = (const float*)d_in[10];
    const float* W2     = (const float*)d_in[11];
    const float* b2     = (const float*)d_in[12];
    const float* lnf_g  = (const float*)d_in[13];
    const float* lnf_b  = (const float*)d_in[14];
    const float* Whead  = (const float*)d_in[15];
    float* out = (float*)d_out;

    float* ws = (float*)d_ws;
    float*          X   = ws;                                  // f32 2048x1024
    float*          QKV = X + (size_t)NROWS * DM;              // f32 2048x3072
    unsigned short* XN  = (unsigned short*)(QKV + (size_t)NROWS * 3 * DM); // bf16 2048x1024
    unsigned short* ATT = XN + (size_t)NROWS * DM;             // bf16 2048x1024
    unsigned short* FFH = ATT + (size_t)NROWS * DM;            // bf16 2048x4096

    embed_pos_k<<<NROWS, 256, 0, stream>>>(idx, embed, X);

    for (int l = 0; l < NLAYER; ++l) {
        const float* wqkv_l  = Wqkv  + (size_t)l * DM * 3 * DM;
        const float* wproj_l = Wproj + (size_t)l * DM * DM;
        const float* bproj_l = bproj + (size_t)l * DM;
        const float* w1_l = W1 + (size_t)l * DM * DFFN;
        const float* b1_l = b1 + (size_t)l * DFFN;
        const float* w2_l = W2 + (size_t)l * DFFN * DM;
        const float* b2_l = b2 + (size_t)l * DM;

        layernorm_k<<<NROWS, 256, 0, stream>>>(X, ln1_g + (size_t)l * DM,
                                               ln1_b + (size_t)l * DM, XN);
        {   // qkv = ln1(x) @ Wqkv  (f32 out)
            dim3 grid(3 * DM / 128, NROWS / 128);
            gemm_bf16<false><<<grid, 256, 0, stream>>>(XN, wqkv_l, nullptr, nullptr,
                                                       QKV, NROWS, 3 * DM, DM, 0);
        }
        {   // attention -> bf16
            dim3 grid(TSEQ, NHEAD, NB);
            attn_fused_k<<<grid, 256, 0, stream>>>(QKV, ATT);
        }
        {   // x = x + att @ Wproj + bproj  (f32 out, in-place residual)
            dim3 grid(DM / 128, NROWS / 128);
            gemm_bf16<false><<<grid, 256, 0, stream>>>(ATT, wproj_l, bproj_l, X,
                                                       X, NROWS, DM, DM, 0);
        }
        layernorm_k<<<NROWS, 256, 0, stream>>>(X, ln2_g + (size_t)l * DM,
                                               ln2_b + (size_t)l * DM, XN);
        {   // ffh = relu(ln2 @ W1 + b1)  (bf16 out)
            dim3 grid(DFFN / 128, NROWS / 128);
            gemm_bf16<true><<<grid, 256, 0, stream>>>(XN, w1_l, b1_l, nullptr,
                                                      FFH, NROWS, DFFN, DM, 1);
        }
        {   // x = x + ffh @ W2 + b2  (f32 out)
            dim3 grid(DM / 128, NROWS / 128);
            gemm_bf16<false><<<grid, 256, 0, stream>>>(FFH, w2_l, b2_l, X,
                                                       X, NROWS, DM, DFFN, 0);
        }
    }

    layernorm_k<<<NROWS, 256, 0, stream>>>(X, lnf_g, lnf_b, XN);
    {   // logits = lnf(x) @ Whead  (f32 out)
        dim3 grid(NVOC / 128, NROWS / 128);
        gemm_bf16<false><<<grid, 256, 0, stream>>>(XN, Whead, nullptr, nullptr,
                                                   out, NROWS, NVOC, DM, 0);
    }
}

// Round 3
// 4101.398 us; speedup vs baseline: 7.4033x; 2.1176x over previous
//
#include <hip/hip_runtime.h>
#include <cstddef>

#define DM    1024
#define TSEQ  1024
#define NB    2
#define NHEAD 16
#define HDIM  64
#define NLAYER 8
#define DFFN  4096
#define NVOC  32000
#define NROWS (NB*TSEQ)

typedef __attribute__((ext_vector_type(8))) short short8;
typedef __attribute__((ext_vector_type(4))) float f32x4;

static __device__ __forceinline__ unsigned short f2bf(float f) {
    union { float f; unsigned int u; } v; v.f = f;
    unsigned int r = v.u + 0x7FFF + ((v.u >> 16) & 1);   // RNE
    return (unsigned short)(r >> 16);
}

// ---------------- embedding + positional encoding (f32 out) ----------------
__global__ __launch_bounds__(256)
void embed_pos_k(const int* __restrict__ idx, const float* __restrict__ embed,
                 float* __restrict__ x)
{
    int row = blockIdx.x;
    int t   = row & (TSEQ - 1);
    int tid = threadIdx.x;
    int token = idx[row];
    const float* er = embed + (size_t)token * DM;
    float* xr = x + (size_t)row * DM;
    const float neg_ln1e4_over_d = -9.210340371976184f / (float)DM;
    for (int i = tid; i < DM; i += 256) {
        int half = i >> 1;
        float div = expf((float)(2 * half) * neg_ln1e4_over_d);
        float ang = (float)t * div;
        float pe = (i & 1) ? cosf(ang) : sinf(ang);
        xr[i] = er[i] + pe;
    }
}

// ---------------- layernorm (f32 in, bf16 out) ----------------
__global__ __launch_bounds__(256)
void layernorm_k(const float* __restrict__ x, const float* __restrict__ g,
                 const float* __restrict__ b, unsigned short* __restrict__ y)
{
    int row = blockIdx.x;
    int tid = threadIdx.x;
    const float* xr = x + (size_t)row * DM;
    unsigned short* yr = y + (size_t)row * DM;
    float vals[4];
    float s = 0.f;
    #pragma unroll
    for (int i = 0; i < 4; ++i) { vals[i] = xr[tid + 256 * i]; s += vals[i]; }
    __shared__ float red[256];
    red[tid] = s; __syncthreads();
    for (int st = 128; st > 0; st >>= 1) {
        if (tid < st) red[tid] += red[tid + st];
        __syncthreads();
    }
    float mu = red[0] * (1.f / DM);
    __syncthreads();
    float v = 0.f;
    #pragma unroll
    for (int i = 0; i < 4; ++i) { float d = vals[i] - mu; v += d * d; }
    red[tid] = v; __syncthreads();
    for (int st = 128; st > 0; st >>= 1) {
        if (tid < st) red[tid] += red[tid + st];
        __syncthreads();
    }
    float rstd = rsqrtf(red[0] * (1.f / DM) + 1e-5f);
    #pragma unroll
    for (int i = 0; i < 4; ++i) {
        int c = tid + 256 * i;
        yr[c] = f2bf((vals[i] - mu) * rstd * g[c] + b[c]);
    }
}

// ---------------- bf16 MFMA GEMM, 128x128 tile, BK=32 ----------------
template<bool OUT_BF16>
__global__ __launch_bounds__(256)
void gemm_bf16(const unsigned short* __restrict__ A, const float* __restrict__ B,
               const float* __restrict__ bias, const float* __restrict__ residual,
               void* __restrict__ Cout, int M, int N, int K, int relu)
{
    __shared__ unsigned short As[128][40];
    __shared__ unsigned short Bs[128][40];

    const int tid  = threadIdx.x;
    const int lane = tid & 63;
    const int wave = tid >> 6;
    const int wr = wave >> 1, wc = wave & 1;
    const int l16 = lane & 15, g = lane >> 4;
    const int row0 = blockIdx.y * 128, col0 = blockIdx.x * 128;

    f32x4 acc[4][4] = {};

    const int ar  = tid >> 1, acb = (tid & 1) << 4;
    const int bn  = tid >> 1, bkb = (tid & 1) << 4;

    for (int k0 = 0; k0 < K; k0 += 32) {
        const unsigned short* asrc = A + (size_t)(row0 + ar) * K + k0 + acb;
        short8 av0 = *(const short8*)asrc;
        short8 av1 = *(const short8*)(asrc + 8);
        const float* bsrc = B + (size_t)(k0 + bkb) * N + col0 + bn;
        unsigned short bt[16];
        #pragma unroll
        for (int j = 0; j < 16; ++j) bt[j] = f2bf(bsrc[(size_t)j * N]);

        *(short8*)&As[ar][acb]     = av0;
        *(short8*)&As[ar][acb + 8] = av1;
        *(short8*)&Bs[bn][bkb]     = *(short8*)&bt[0];
        *(short8*)&Bs[bn][bkb + 8] = *(short8*)&bt[8];
        __syncthreads();

        short8 af[4], bfr[4];
        #pragma unroll
        for (int i = 0; i < 4; ++i)
            af[i] = *(const short8*)&As[wr * 64 + i * 16 + l16][g * 8];
        #pragma unroll
        for (int j = 0; j < 4; ++j)
            bfr[j] = *(const short8*)&Bs[wc * 64 + j * 16 + l16][g * 8];
        #pragma unroll
        for (int i = 0; i < 4; ++i)
            #pragma unroll
            for (int j = 0; j < 4; ++j)
                acc[i][j] = __builtin_amdgcn_mfma_f32_16x16x32_bf16(af[i], bfr[j], acc[i][j], 0, 0, 0);
        __syncthreads();
    }

    #pragma unroll
    for (int i = 0; i < 4; ++i) {
        #pragma unroll
        for (int j = 0; j < 4; ++j) {
            #pragma unroll
            for (int r = 0; r < 4; ++r) {
                int row = row0 + wr * 64 + i * 16 + g * 4 + r;
                int col = col0 + wc * 64 + j * 16 + l16;
                float v = acc[i][j][r];
                if (bias)     v += bias[col];
                if (residual) v += residual[(size_t)row * N + col];
                if (relu)     v = fmaxf(v, 0.f);
                if (OUT_BF16) ((unsigned short*)Cout)[(size_t)row * N + col] = f2bf(v);
                else          ((float*)Cout)[(size_t)row * N + col] = v;
            }
        }
    }
}

// ---------------- MFMA flash attention ----------------
// qkv: bf16, row layout [3][H][HD]. One block = 64 q-rows of one (b,h).
// 4 waves, each owns 16 q-rows. K/V tiles (64x64) staged in LDS.
__global__ __launch_bounds__(256)
void attn_flash_k(const unsigned short* __restrict__ qkv, unsigned short* __restrict__ out)
{
    __shared__ unsigned short Ks[64][72];   // [kv][d], pitch 144B
    __shared__ unsigned short Vt[64][72];   // [d][kv]
    __shared__ unsigned short Ps[4][16][72];// per-wave P [q][kv]

    const int tid = threadIdx.x;
    const int lane = tid & 63;
    const int w = tid >> 6;
    const int l16 = lane & 15, g = lane >> 4;
    const int q0 = blockIdx.x * 64;
    const int h = blockIdx.y;
    const int b = blockIdx.z;

    const size_t rstr = 3 * DM;  // u16 per token row
    const unsigned short* base = qkv + (size_t)b * TSEQ * rstr + h * HDIM;

    // Q fragments (lane l16 <-> q-row, slots <-> d)
    const int qrow_w = q0 + w * 16 + l16;
    short8 aq0 = *(const short8*)(base + (size_t)qrow_w * rstr + g * 8);
    short8 aq1 = *(const short8*)(base + (size_t)qrow_w * rstr + 32 + g * 8);

    f32x4 acc_o[4] = {};
    float m_r[4] = {-INFINITY, -INFINITY, -INFINITY, -INFINITY};
    float l_r[4] = {};

    const int qmax_w = q0 + w * 16 + 15;
    const int nt = blockIdx.x + 1;

    for (int t = 0; t < nt; ++t) {
        const int kv0 = t * 64;
        // ---- stage K tile [kv][d] ----
        #pragma unroll
        for (int i = 0; i < 2; ++i) {
            int c = tid + 256 * i;
            int row = c >> 3, off = (c & 7) * 8;
            *(short8*)&Ks[row][off] =
                *(const short8*)(base + (size_t)(kv0 + row) * rstr + DM + off);
        }
        // ---- stage V transposed [d][kv] ----
        {
            int kv = tid & 63, dg = tid >> 6;
            const unsigned short* vsrc = base + (size_t)(kv0 + kv) * rstr + 2 * DM + dg * 16;
            short8 v0 = *(const short8*)vsrc;
            short8 v1 = *(const short8*)(vsrc + 8);
            #pragma unroll
            for (int j = 0; j < 8; ++j) Vt[dg * 16 + j][kv] = (unsigned short)v0[j];
            #pragma unroll
            for (int j = 0; j < 8; ++j) Vt[dg * 16 + 8 + j][kv] = (unsigned short)v1[j];
        }
        __syncthreads();

        if (kv0 <= qmax_w) {
            // ---- S = Q K^T (4 k-subtiles of 16) ----
            f32x4 acc_s[4] = {};
            #pragma unroll
            for (int ks = 0; ks < 4; ++ks) {
                short8 bk0 = *(const short8*)&Ks[ks * 16 + l16][g * 8];
                short8 bk1 = *(const short8*)&Ks[ks * 16 + l16][32 + g * 8];
                acc_s[ks] = __builtin_amdgcn_mfma_f32_16x16x32_bf16(aq0, bk0, acc_s[ks], 0, 0, 0);
                acc_s[ks] = __builtin_amdgcn_mfma_f32_16x16x32_bf16(aq1, bk1, acc_s[ks], 0, 0, 0);
            }
            const bool need_mask = (kv0 + 63 > q0 + w * 16);
            float alpha[4];
            #pragma unroll
            for (int r = 0; r < 4; ++r) {
                const int q_abs = q0 + w * 16 + g * 4 + r;
                float s[4];
                #pragma unroll
                for (int ks = 0; ks < 4; ++ks) {
                    s[ks] = acc_s[ks][r] * 0.125f;
                    if (need_mask && (kv0 + ks * 16 + l16 > q_abs)) s[ks] = -INFINITY;
                }
                float pm = fmaxf(fmaxf(s[0], s[1]), fmaxf(s[2], s[3]));
                #pragma unroll
                for (int msk = 1; msk <= 8; msk <<= 1)
                    pm = fmaxf(pm, __shfl_xor(pm, msk));
                float mnew = fmaxf(m_r[r], pm);
                alpha[r] = __expf(m_r[r] - mnew);
                m_r[r] = mnew;
                float p[4], psum = 0.f;
                #pragma unroll
                for (int ks = 0; ks < 4; ++ks) {
                    p[ks] = (s[ks] == -INFINITY) ? 0.f : __expf(s[ks] - mnew);
                    psum += p[ks];
                }
                #pragma unroll
                for (int msk = 1; msk <= 8; msk <<= 1)
                    psum += __shfl_xor(psum, msk);
                l_r[r] = l_r[r] * alpha[r] + psum;
                #pragma unroll
                for (int ks = 0; ks < 4; ++ks)
                    Ps[w][g * 4 + r][ks * 16 + l16] = f2bf(p[ks]);
            }
            // rescale O
            #pragma unroll
            for (int ds = 0; ds < 4; ++ds)
                #pragma unroll
                for (int r = 0; r < 4; ++r)
                    acc_o[ds][r] *= alpha[r];
            // ---- O += P V ---- (P via per-wave LDS relayout; same-wave dep, no barrier)
            short8 ap0 = *(const short8*)&Ps[w][l16][g * 8];
            short8 ap1 = *(const short8*)&Ps[w][l16][32 + g * 8];
            #pragma unroll
            for (int ds = 0; ds < 4; ++ds) {
                short8 bv0 = *(const short8*)&Vt[ds * 16 + l16][g * 8];
                short8 bv1 = *(const short8*)&Vt[ds * 16 + l16][32 + g * 8];
                acc_o[ds] = __builtin_amdgcn_mfma_f32_16x16x32_bf16(ap0, bv0, acc_o[ds], 0, 0, 0);
                acc_o[ds] = __builtin_amdgcn_mfma_f32_16x16x32_bf16(ap1, bv1, acc_o[ds], 0, 0, 0);
            }
        }
        __syncthreads();
    }

    // ---- write O (bf16) ----
    #pragma unroll
    for (int ds = 0; ds < 4; ++ds)
        #pragma unroll
        for (int r = 0; r < 4; ++r) {
            int row = q0 + w * 16 + g * 4 + r;
            out[((size_t)b * TSEQ + row) * DM + h * HDIM + ds * 16 + l16] =
                f2bf(acc_o[ds][r] * (1.f / l_r[r]));
        }
}

// ---------------- orchestration ----------------
extern "C" void kernel_launch(void* const* d_in, const int* in_sizes, int n_in,
                              void* d_out, int out_size, void* d_ws, size_t ws_size,
                              hipStream_t stream)
{
    const int*   idx    = (const int*)  d_in[0];
    const float* embed  = (const float*)d_in[1];
    const float* Wqkv   = (const float*)d_in[2];
    const float* Wproj  = (const float*)d_in[3];
    const float* bproj  = (const float*)d_in[4];
    const float* ln1_g  = (const float*)d_in[5];
    const float* ln1_b  = (const float*)d_in[6];
    const float* ln2_g  = (const float*)d_in[7];
    const float* ln2_b  = (const float*)d_in[8];
    const float* W1     = (const float*)d_in[9];
    const float* b1     = (const float*)d_in[10];
    const float* W2     = (const float*)d_in[11];
    const float* b2     = (const float*)d_in[12];
    const float* lnf_g  = (const float*)d_in[13];
    const float* lnf_b  = (const float*)d_in[14];
    const float* Whead  = (const float*)d_in[15];
    float* out = (float*)d_out;

    float* ws = (float*)d_ws;
    float*          X    = ws;                                   // f32 2048x1024
    unsigned short* QKVb = (unsigned short*)(X + (size_t)NROWS * DM); // bf16 2048x3072
    unsigned short* XN   = QKVb + (size_t)NROWS * 3 * DM;        // bf16 2048x1024
    unsigned short* ATT  = XN + (size_t)NROWS * DM;              // bf16 2048x1024
    unsigned short* FFH  = ATT + (size_t)NROWS * DM;             // bf16 2048x4096

    embed_pos_k<<<NROWS, 256, 0, stream>>>(idx, embed, X);

    for (int l = 0; l < NLAYER; ++l) {
        const float* wqkv_l  = Wqkv  + (size_t)l * DM * 3 * DM;
        const float* wproj_l = Wproj + (size_t)l * DM * DM;
        const float* bproj_l = bproj + (size_t)l * DM;
        const float* w1_l = W1 + (size_t)l * DM * DFFN;
        const float* b1_l = b1 + (size_t)l * DFFN;
        const float* w2_l = W2 + (size_t)l * DFFN * DM;
        const float* b2_l = b2 + (size_t)l * DM;

        layernorm_k<<<NROWS, 256, 0, stream>>>(X, ln1_g + (size_t)l * DM,
                                               ln1_b + (size_t)l * DM, XN);
        {   // qkv = ln1(x) @ Wqkv  (bf16 out)
            dim3 grid(3 * DM / 128, NROWS / 128);
            gemm_bf16<true><<<grid, 256, 0, stream>>>(XN, wqkv_l, nullptr, nullptr,
                                                      QKVb, NROWS, 3 * DM, DM, 0);
        }
        {   // flash attention -> bf16
            dim3 grid(TSEQ / 64, NHEAD, NB);
            attn_flash_k<<<grid, 256, 0, stream>>>(QKVb, ATT);
        }
        {   // x = x + att @ Wproj + bproj  (f32 out)
            dim3 grid(DM / 128, NROWS / 128);
            gemm_bf16<false><<<grid, 256, 0, stream>>>(ATT, wproj_l, bproj_l, X,
                                                       X, NROWS, DM, DM, 0);
        }
        layernorm_k<<<NROWS, 256, 0, stream>>>(X, ln2_g + (size_t)l * DM,
                                               ln2_b + (size_t)l * DM, XN);
        {   // ffh = relu(ln2 @ W1 + b1)  (bf16 out)
            dim3 grid(DFFN / 128, NROWS / 128);
            gemm_bf16<true><<<grid, 256, 0, stream>>>(XN, w1_l, b1_l, nullptr,
                                                      FFH, NROWS, DFFN, DM, 1);
        }
        {   // x = x + ffh @ W2 + b2  (f32 out)
            dim3 grid(DM / 128, NROWS / 128);
            gemm_bf16<false><<<grid, 256, 0, stream>>>(FFH, w2_l, b2_l, X,
                                                       X, NROWS, DM, DFFN, 0);
        }
    }

    layernorm_k<<<NROWS, 256, 0, stream>>>(X, lnf_g, lnf_b, XN);
    {   // logits = lnf(x) @ Whead  (f32 out)
        dim3 grid(NVOC / 128, NROWS / 128);
        gemm_bf16<false><<<grid, 256, 0, stream>>>(XN, Whead, nullptr, nullptr,
                                                   out, NROWS, NVOC, DM, 0);
    }
}

// Round 4
// 2319.221 us; speedup vs baseline: 13.0923x; 1.7684x over previous
//
#include <hip/hip_runtime.h>
#include <cstddef>

#define DM    1024
#define TSEQ  1024
#define NB    2
#define NHEAD 16
#define HDIM  64
#define NLAYER 8
#define DFFN  4096
#define NVOC  32000
#define NROWS (NB*TSEQ)

typedef __attribute__((ext_vector_type(8))) short short8;
typedef __attribute__((ext_vector_type(4))) float f32x4;

static __device__ __forceinline__ unsigned short f2bf(float f) {
    union { float f; unsigned int u; } v; v.f = f;
    unsigned int r = v.u + 0x7FFF + ((v.u >> 16) & 1);   // RNE
    return (unsigned short)(r >> 16);
}

static __device__ __forceinline__ void gload_lds16(const void* g, void* l) {
    __builtin_amdgcn_global_load_lds(
        (const __attribute__((address_space(1))) unsigned int*)g,
        (__attribute__((address_space(3))) unsigned int*)l, 16, 0, 0);
}

// ---------------- embedding + positional encoding (f32 out) ----------------
__global__ __launch_bounds__(256)
void embed_pos_k(const int* __restrict__ idx, const float* __restrict__ embed,
                 float* __restrict__ x)
{
    int row = blockIdx.x;
    int t   = row & (TSEQ - 1);
    int tid = threadIdx.x;
    int token = idx[row];
    const float* er = embed + (size_t)token * DM;
    float* xr = x + (size_t)row * DM;
    const float neg_ln1e4_over_d = -9.210340371976184f / (float)DM;
    for (int i = tid; i < DM; i += 256) {
        int half = i >> 1;
        float div = expf((float)(2 * half) * neg_ln1e4_over_d);
        float ang = (float)t * div;
        float pe = (i & 1) ? cosf(ang) : sinf(ang);
        xr[i] = er[i] + pe;
    }
}

// ---------------- layernorm (f32 in, bf16 out) ----------------
__global__ __launch_bounds__(256)
void layernorm_k(const float* __restrict__ x, const float* __restrict__ g,
                 const float* __restrict__ b, unsigned short* __restrict__ y)
{
    int row = blockIdx.x;
    int tid = threadIdx.x;
    const float* xr = x + (size_t)row * DM;
    unsigned short* yr = y + (size_t)row * DM;
    float vals[4];
    float s = 0.f;
    #pragma unroll
    for (int i = 0; i < 4; ++i) { vals[i] = xr[tid + 256 * i]; s += vals[i]; }
    __shared__ float red[256];
    red[tid] = s; __syncthreads();
    for (int st = 128; st > 0; st >>= 1) {
        if (tid < st) red[tid] += red[tid + st];
        __syncthreads();
    }
    float mu = red[0] * (1.f / DM);
    __syncthreads();
    float v = 0.f;
    #pragma unroll
    for (int i = 0; i < 4; ++i) { float d = vals[i] - mu; v += d * d; }
    red[tid] = v; __syncthreads();
    for (int st = 128; st > 0; st >>= 1) {
        if (tid < st) red[tid] += red[tid + st];
        __syncthreads();
    }
    float rstd = rsqrtf(red[0] * (1.f / DM) + 1e-5f);
    #pragma unroll
    for (int i = 0; i < 4; ++i) {
        int c = tid + 256 * i;
        yr[c] = f2bf((vals[i] - mu) * rstd * g[c] + b[c]);
    }
}

// ---------------- weight convert+transpose: f32 [K][N] -> bf16 [N][K] ----------------
// grid (N/64, K/64, batch), block 256. XOR-swizzled k-groups in LDS.
__global__ __launch_bounds__(256)
void convt_k(const float* __restrict__ src, unsigned short* __restrict__ dst,
             int K, int N)
{
    __shared__ __align__(16) unsigned short T[64][72];
    const int tid = threadIdx.x;
    const int n0 = blockIdx.x * 64, k0 = blockIdx.y * 64;
    const float* s = src + (size_t)blockIdx.z * K * N;
    unsigned short* d = dst + (size_t)blockIdx.z * K * N;
    #pragma unroll
    for (int q = 0; q < 4; ++q) {
        int f4 = tid + q * 256;
        int kk = f4 >> 4, nn = (f4 & 15) * 4;
        float4 v = *(const float4*)(s + (size_t)(k0 + kk) * N + n0 + nn);
        int swz = ((nn >> 2) & 7) << 3;
        T[nn + 0][kk ^ swz] = f2bf(v.x);
        T[nn + 1][kk ^ swz] = f2bf(v.y);
        T[nn + 2][kk ^ swz] = f2bf(v.z);
        T[nn + 3][kk ^ swz] = f2bf(v.w);
    }
    __syncthreads();
    #pragma unroll
    for (int q = 0; q < 2; ++q) {
        int s8 = tid + q * 256;
        int nn = s8 >> 3, kc = (s8 & 7) * 8;
        int swz = ((nn >> 2) & 7) << 3;
        *(short8*)(d + (size_t)(n0 + nn) * K + k0 + kc) =
            *(const short8*)&T[nn][kc ^ swz];
    }
}

// ---------------- bf16 MFMA GEMM (m97 structure) ----------------
// A: bf16 [M][K]; BT: bf16 [N][K]; C = A @ BT^T (+bias)(+residual)(relu?).
// Tile BMx BM, BK=32, global_load_lds staging, linear LDS, XCD swizzle (rows fastest).
template<int BM, bool OUT_BF16>
__global__ __launch_bounds__(256)
void gemm_tn(const unsigned short* __restrict__ A, const unsigned short* __restrict__ BT,
             const float* __restrict__ bias, const float* __restrict__ residual,
             void* __restrict__ Cout, int M, int N, int K, int relu)
{
    constexpr int FR = BM / 32;          // frags per wave dim
    constexpr int RPW = BM / 4;          // staged rows per wave
    constexpr int NI = BM / 64;          // gload insts per operand per wave
    __shared__ __align__(16) unsigned short As[BM][32];
    __shared__ __align__(16) unsigned short Bs[BM][32];

    const int tid = threadIdx.x;
    const int lane = tid & 63;
    const int w = tid >> 6;
    const int wr = w >> 1, wc = w & 1;
    const int l16 = lane & 15, g = lane >> 4;

    // XCD-bijective swizzle, row-blocks fastest (B panel shared by adjacent blocks)
    const int nby = M / BM;
    const int nwg = (N / BM) * nby;
    const int cpx = nwg >> 3;
    const int bid = blockIdx.x;
    const int sbid = (bid & 7) * cpx + (bid >> 3);
    const int row0 = (sbid % nby) * BM;
    const int col0 = (sbid / nby) * BM;

    const int srow = w * RPW + (lane >> 2);
    const int scol = (lane & 3) * 8;

    f32x4 acc[FR][FR] = {};

    for (int k0 = 0; k0 < K; k0 += 32) {
        const unsigned short* ga = A  + (size_t)(row0 + srow) * K + k0 + scol;
        const unsigned short* gb = BT + (size_t)(col0 + srow) * K + k0 + scol;
        #pragma unroll
        for (int i = 0; i < NI; ++i) {
            gload_lds16(ga + (size_t)(i * 16) * K, &As[srow + i * 16][scol]);
            gload_lds16(gb + (size_t)(i * 16) * K, &Bs[srow + i * 16][scol]);
        }
        __syncthreads();

        short8 af[FR], bf[FR];
        #pragma unroll
        for (int i = 0; i < FR; ++i)
            af[i] = *(const short8*)&As[wr * (BM / 2) + i * 16 + l16][g * 8];
        #pragma unroll
        for (int j = 0; j < FR; ++j)
            bf[j] = *(const short8*)&Bs[wc * (BM / 2) + j * 16 + l16][g * 8];
        #pragma unroll
        for (int i = 0; i < FR; ++i)
            #pragma unroll
            for (int j = 0; j < FR; ++j)
                acc[i][j] = __builtin_amdgcn_mfma_f32_16x16x32_bf16(af[i], bf[j], acc[i][j], 0, 0, 0);
        __syncthreads();
    }

    #pragma unroll
    for (int i = 0; i < FR; ++i) {
        #pragma unroll
        for (int j = 0; j < FR; ++j) {
            #pragma unroll
            for (int r = 0; r < 4; ++r) {
                int row = row0 + wr * (BM / 2) + i * 16 + g * 4 + r;
                int col = col0 + wc * (BM / 2) + j * 16 + l16;
                float v = acc[i][j][r];
                if (bias)     v += bias[col];
                if (residual) v += residual[(size_t)row * N + col];
                if (relu)     v = fmaxf(v, 0.f);
                if (OUT_BF16) ((unsigned short*)Cout)[(size_t)row * N + col] = f2bf(v);
                else          ((float*)Cout)[(size_t)row * N + col] = v;
            }
        }
    }
}

// ---------------- MFMA flash attention ----------------
__global__ __launch_bounds__(256)
void attn_flash_k(const unsigned short* __restrict__ qkv, unsigned short* __restrict__ out)
{
    __shared__ unsigned short Ks[64][72];
    __shared__ unsigned short Vt[64][72];
    __shared__ unsigned short Ps[4][16][72];

    const int tid = threadIdx.x;
    const int lane = tid & 63;
    const int w = tid >> 6;
    const int l16 = lane & 15, g = lane >> 4;
    const int q0 = blockIdx.x * 64;
    const int h = blockIdx.y;
    const int b = blockIdx.z;

    const size_t rstr = 3 * DM;
    const unsigned short* base = qkv + (size_t)b * TSEQ * rstr + h * HDIM;

    const int qrow_w = q0 + w * 16 + l16;
    short8 aq0 = *(const short8*)(base + (size_t)qrow_w * rstr + g * 8);
    short8 aq1 = *(const short8*)(base + (size_t)qrow_w * rstr + 32 + g * 8);

    f32x4 acc_o[4] = {};
    float m_r[4] = {-INFINITY, -INFINITY, -INFINITY, -INFINITY};
    float l_r[4] = {};

    const int qmax_w = q0 + w * 16 + 15;
    const int nt = blockIdx.x + 1;

    for (int t = 0; t < nt; ++t) {
        const int kv0 = t * 64;
        #pragma unroll
        for (int i = 0; i < 2; ++i) {
            int c = tid + 256 * i;
            int row = c >> 3, off = (c & 7) * 8;
            *(short8*)&Ks[row][off] =
                *(const short8*)(base + (size_t)(kv0 + row) * rstr + DM + off);
        }
        {
            int kv = tid & 63, dg = tid >> 6;
            const unsigned short* vsrc = base + (size_t)(kv0 + kv) * rstr + 2 * DM + dg * 16;
            short8 v0 = *(const short8*)vsrc;
            short8 v1 = *(const short8*)(vsrc + 8);
            #pragma unroll
            for (int j = 0; j < 8; ++j) Vt[dg * 16 + j][kv] = (unsigned short)v0[j];
            #pragma unroll
            for (int j = 0; j < 8; ++j) Vt[dg * 16 + 8 + j][kv] = (unsigned short)v1[j];
        }
        __syncthreads();

        if (kv0 <= qmax_w) {
            f32x4 acc_s[4] = {};
            #pragma unroll
            for (int ks = 0; ks < 4; ++ks) {
                short8 bk0 = *(const short8*)&Ks[ks * 16 + l16][g * 8];
                short8 bk1 = *(const short8*)&Ks[ks * 16 + l16][32 + g * 8];
                acc_s[ks] = __builtin_amdgcn_mfma_f32_16x16x32_bf16(aq0, bk0, acc_s[ks], 0, 0, 0);
                acc_s[ks] = __builtin_amdgcn_mfma_f32_16x16x32_bf16(aq1, bk1, acc_s[ks], 0, 0, 0);
            }
            const bool need_mask = (kv0 + 63 > q0 + w * 16);
            float alpha[4];
            #pragma unroll
            for (int r = 0; r < 4; ++r) {
                const int q_abs = q0 + w * 16 + g * 4 + r;
                float s[4];
                #pragma unroll
                for (int ks = 0; ks < 4; ++ks) {
                    s[ks] = acc_s[ks][r] * 0.125f;
                    if (need_mask && (kv0 + ks * 16 + l16 > q_abs)) s[ks] = -INFINITY;
                }
                float pm = fmaxf(fmaxf(s[0], s[1]), fmaxf(s[2], s[3]));
                #pragma unroll
                for (int msk = 1; msk <= 8; msk <<= 1)
                    pm = fmaxf(pm, __shfl_xor(pm, msk));
                float mnew = fmaxf(m_r[r], pm);
                alpha[r] = __expf(m_r[r] - mnew);
                m_r[r] = mnew;
                float p[4], psum = 0.f;
                #pragma unroll
                for (int ks = 0; ks < 4; ++ks) {
                    p[ks] = (s[ks] == -INFINITY) ? 0.f : __expf(s[ks] - mnew);
                    psum += p[ks];
                }
                #pragma unroll
                for (int msk = 1; msk <= 8; msk <<= 1)
                    psum += __shfl_xor(psum, msk);
                l_r[r] = l_r[r] * alpha[r] + psum;
                #pragma unroll
                for (int ks = 0; ks < 4; ++ks)
                    Ps[w][g * 4 + r][ks * 16 + l16] = f2bf(p[ks]);
            }
            #pragma unroll
            for (int ds = 0; ds < 4; ++ds)
                #pragma unroll
                for (int r = 0; r < 4; ++r)
                    acc_o[ds][r] *= alpha[r];
            short8 ap0 = *(const short8*)&Ps[w][l16][g * 8];
            short8 ap1 = *(const short8*)&Ps[w][l16][32 + g * 8];
            #pragma unroll
            for (int ds = 0; ds < 4; ++ds) {
                short8 bv0 = *(const short8*)&Vt[ds * 16 + l16][g * 8];
                short8 bv1 = *(const short8*)&Vt[ds * 16 + l16][32 + g * 8];
                acc_o[ds] = __builtin_amdgcn_mfma_f32_16x16x32_bf16(ap0, bv0, acc_o[ds], 0, 0, 0);
                acc_o[ds] = __builtin_amdgcn_mfma_f32_16x16x32_bf16(ap1, bv1, acc_o[ds], 0, 0, 0);
            }
        }
        __syncthreads();
    }

    #pragma unroll
    for (int ds = 0; ds < 4; ++ds)
        #pragma unroll
        for (int r = 0; r < 4; ++r) {
            int row = q0 + w * 16 + g * 4 + r;
            out[((size_t)b * TSEQ + row) * DM + h * HDIM + ds * 16 + l16] =
                f2bf(acc_o[ds][r] * (1.f / l_r[r]));
        }
}

// ---------------- orchestration ----------------
extern "C" void kernel_launch(void* const* d_in, const int* in_sizes, int n_in,
                              void* d_out, int out_size, void* d_ws, size_t ws_size,
                              hipStream_t stream)
{
    const int*   idx    = (const int*)  d_in[0];
    const float* embed  = (const float*)d_in[1];
    const float* Wqkv   = (const float*)d_in[2];
    const float* Wproj  = (const float*)d_in[3];
    const float* bproj  = (const float*)d_in[4];
    const float* ln1_g  = (const float*)d_in[5];
    const float* ln1_b  = (const float*)d_in[6];
    const float* ln2_g  = (const float*)d_in[7];
    const float* ln2_b  = (const float*)d_in[8];
    const float* W1     = (const float*)d_in[9];
    const float* b1     = (const float*)d_in[10];
    const float* W2     = (const float*)d_in[11];
    const float* b2     = (const float*)d_in[12];
    const float* lnf_g  = (const float*)d_in[13];
    const float* lnf_b  = (const float*)d_in[14];
    const float* Whead  = (const float*)d_in[15];
    float* out = (float*)d_out;

    float* X = (float*)d_ws;                                  // f32 2048x1024
    unsigned short* u = (unsigned short*)(X + (size_t)NROWS * DM);
    unsigned short* XN     = u;  u += (size_t)NROWS * DM;          // bf16
    unsigned short* QKVb   = u;  u += (size_t)NROWS * 3 * DM;
    unsigned short* ATT    = u;  u += (size_t)NROWS * DM;
    unsigned short* FFH    = u;  u += (size_t)NROWS * DFFN;
    unsigned short* WqkvT  = u;  u += (size_t)NLAYER * 3 * DM * DM; // [3D][K]
    unsigned short* WprojT = u;  u += (size_t)NLAYER * DM * DM;
    unsigned short* W1T    = u;  u += (size_t)NLAYER * DFFN * DM;
    unsigned short* W2T    = u;  u += (size_t)NLAYER * DM * DFFN;
    unsigned short* WheadT = u;  u += (size_t)NVOC * DM;

    // ---- one-time weight convert+transpose (every call; inputs may change) ----
    convt_k<<<dim3(3 * DM / 64, DM / 64, NLAYER), 256, 0, stream>>>(Wqkv,  WqkvT,  DM,   3 * DM);
    convt_k<<<dim3(DM / 64,     DM / 64, NLAYER), 256, 0, stream>>>(Wproj, WprojT, DM,   DM);
    convt_k<<<dim3(DFFN / 64,   DM / 64, NLAYER), 256, 0, stream>>>(W1,    W1T,    DM,   DFFN);
    convt_k<<<dim3(DM / 64,   DFFN / 64, NLAYER), 256, 0, stream>>>(W2,    W2T,    DFFN, DM);
    convt_k<<<dim3(NVOC / 64,   DM / 64, 1),      256, 0, stream>>>(Whead, WheadT, DM,   NVOC);

    embed_pos_k<<<NROWS, 256, 0, stream>>>(idx, embed, X);

    for (int l = 0; l < NLAYER; ++l) {
        const unsigned short* wqkvT_l  = WqkvT  + (size_t)l * 3 * DM * DM;
        const unsigned short* wprojT_l = WprojT + (size_t)l * DM * DM;
        const unsigned short* w1T_l    = W1T    + (size_t)l * DFFN * DM;
        const unsigned short* w2T_l    = W2T    + (size_t)l * DM * DFFN;
        const float* bproj_l = bproj + (size_t)l * DM;
        const float* b1_l = b1 + (size_t)l * DFFN;
        const float* b2_l = b2 + (size_t)l * DM;

        layernorm_k<<<NROWS, 256, 0, stream>>>(X, ln1_g + (size_t)l * DM,
                                               ln1_b + (size_t)l * DM, XN);
        {   // qkv = ln1(x) @ Wqkv  (bf16 out), 384 blocks
            int nwg = (NROWS / 128) * (3 * DM / 128);
            gemm_tn<128, true><<<nwg, 256, 0, stream>>>(XN, wqkvT_l, nullptr, nullptr,
                                                        QKVb, NROWS, 3 * DM, DM, 0);
        }
        {   // flash attention
            dim3 grid(TSEQ / 64, NHEAD, NB);
            attn_flash_k<<<grid, 256, 0, stream>>>(QKVb, ATT);
        }
        {   // x = x + att @ Wproj + bproj, 64^2 tiles -> 512 blocks
            int nwg = (NROWS / 64) * (DM / 64);
            gemm_tn<64, false><<<nwg, 256, 0, stream>>>(ATT, wprojT_l, bproj_l, X,
                                                        X, NROWS, DM, DM, 0);
        }
        layernorm_k<<<NROWS, 256, 0, stream>>>(X, ln2_g + (size_t)l * DM,
                                               ln2_b + (size_t)l * DM, XN);
        {   // ffh = relu(ln2 @ W1 + b1), 512 blocks
            int nwg = (NROWS / 128) * (DFFN / 128);
            gemm_tn<128, true><<<nwg, 256, 0, stream>>>(XN, w1T_l, b1_l, nullptr,
                                                        FFH, NROWS, DFFN, DM, 1);
        }
        {   // x = x + ffh @ W2 + b2, 64^2 tiles -> 512 blocks
            int nwg = (NROWS / 64) * (DM / 64);
            gemm_tn<64, false><<<nwg, 256, 0, stream>>>(FFH, w2T_l, b2_l, X,
                                                        X, NROWS, DM, DFFN, 0);
        }
    }

    layernorm_k<<<NROWS, 256, 0, stream>>>(X, lnf_g, lnf_b, XN);
    {   // logits = lnf(x) @ Whead, 4000 blocks
        int nwg = (NROWS / 128) * (NVOC / 128);
        gemm_tn<128, false><<<nwg, 256, 0, stream>>>(XN, WheadT, nullptr, nullptr,
                                                     out, NROWS, NVOC, DM, 0);
    }
}

// Round 5
// 2214.257 us; speedup vs baseline: 13.7129x; 1.0474x over previous
//
#include <hip/hip_runtime.h>
#include <cstddef>

#define DM    1024
#define TSEQ  1024
#define NB    2
#define NHEAD 16
#define HDIM  64
#define NLAYER 8
#define DFFN  4096
#define NVOC  32000
#define NROWS (NB*TSEQ)

typedef __attribute__((ext_vector_type(8))) short short8;
typedef __attribute__((ext_vector_type(4))) float f32x4;

static __device__ __forceinline__ unsigned short f2bf(float f) {
    union { float f; unsigned int u; } v; v.f = f;
    unsigned int r = v.u + 0x7FFF + ((v.u >> 16) & 1);   // RNE
    return (unsigned short)(r >> 16);
}

static __device__ __forceinline__ void gload_lds16(const void* g, void* l) {
    __builtin_amdgcn_global_load_lds(
        (const __attribute__((address_space(1))) unsigned int*)g,
        (__attribute__((address_space(3))) unsigned int*)l, 16, 0, 0);
}

// ---------------- embedding + positional encoding (f32 out) ----------------
__global__ __launch_bounds__(256)
void embed_pos_k(const int* __restrict__ idx, const float* __restrict__ embed,
                 float* __restrict__ x)
{
    int row = blockIdx.x;
    int t   = row & (TSEQ - 1);
    int tid = threadIdx.x;
    int token = idx[row];
    const float* er = embed + (size_t)token * DM;
    float* xr = x + (size_t)row * DM;
    const float neg_ln1e4_over_d = -9.210340371976184f / (float)DM;
    for (int i = tid; i < DM; i += 256) {
        int half = i >> 1;
        float div = expf((float)(2 * half) * neg_ln1e4_over_d);
        float ang = (float)t * div;
        float pe = (i & 1) ? cosf(ang) : sinf(ang);
        xr[i] = er[i] + pe;
    }
}

// ---------------- layernorm (f32 in, bf16 out) ----------------
__global__ __launch_bounds__(256)
void layernorm_k(const float* __restrict__ x, const float* __restrict__ g,
                 const float* __restrict__ b, unsigned short* __restrict__ y)
{
    int row = blockIdx.x;
    int tid = threadIdx.x;
    const float* xr = x + (size_t)row * DM;
    unsigned short* yr = y + (size_t)row * DM;
    float vals[4];
    float s = 0.f;
    #pragma unroll
    for (int i = 0; i < 4; ++i) { vals[i] = xr[tid + 256 * i]; s += vals[i]; }
    __shared__ float red[256];
    red[tid] = s; __syncthreads();
    for (int st = 128; st > 0; st >>= 1) {
        if (tid < st) red[tid] += red[tid + st];
        __syncthreads();
    }
    float mu = red[0] * (1.f / DM);
    __syncthreads();
    float v = 0.f;
    #pragma unroll
    for (int i = 0; i < 4; ++i) { float d = vals[i] - mu; v += d * d; }
    red[tid] = v; __syncthreads();
    for (int st = 128; st > 0; st >>= 1) {
        if (tid < st) red[tid] += red[tid + st];
        __syncthreads();
    }
    float rstd = rsqrtf(red[0] * (1.f / DM) + 1e-5f);
    #pragma unroll
    for (int i = 0; i < 4; ++i) {
        int c = tid + 256 * i;
        yr[c] = f2bf((vals[i] - mu) * rstd * g[c] + b[c]);
    }
}

// ---------------- weight convert+transpose: f32 [K][N] -> bf16 [N][K] ----------------
__global__ __launch_bounds__(256)
void convt_k(const float* __restrict__ src, unsigned short* __restrict__ dst,
             int K, int N)
{
    __shared__ __align__(16) unsigned short T[64][72];
    const int tid = threadIdx.x;
    const int n0 = blockIdx.x * 64, k0 = blockIdx.y * 64;
    const float* s = src + (size_t)blockIdx.z * K * N;
    unsigned short* d = dst + (size_t)blockIdx.z * K * N;
    #pragma unroll
    for (int q = 0; q < 4; ++q) {
        int f4 = tid + q * 256;
        int kk = f4 >> 4, nn = (f4 & 15) * 4;
        float4 v = *(const float4*)(s + (size_t)(k0 + kk) * N + n0 + nn);
        int swz = ((nn >> 2) & 7) << 3;
        T[nn + 0][kk ^ swz] = f2bf(v.x);
        T[nn + 1][kk ^ swz] = f2bf(v.y);
        T[nn + 2][kk ^ swz] = f2bf(v.z);
        T[nn + 3][kk ^ swz] = f2bf(v.w);
    }
    __syncthreads();
    #pragma unroll
    for (int q = 0; q < 2; ++q) {
        int s8 = tid + q * 256;
        int nn = s8 >> 3, kc = (s8 & 7) * 8;
        int swz = ((nn >> 2) & 7) << 3;
        *(short8*)(d + (size_t)(n0 + nn) * K + k0 + kc) =
            *(const short8*)&T[nn][kc ^ swz];
    }
}

// ---------------- bf16 MFMA GEMM, double-buffered prefetch ----------------
// A: bf16 [M][K]; BT: bf16 [N][K]; C = A @ BT^T (+bias)(+residual)(relu?).
// T3-min pipeline: stage(t+1) issued before MFMA(t); ONE barrier per K-step.
template<int BM, bool OUT_BF16>
__global__ __launch_bounds__(256)
void gemm_tn(const unsigned short* __restrict__ A, const unsigned short* __restrict__ BT,
             const float* __restrict__ bias, const float* __restrict__ residual,
             void* __restrict__ Cout, int M, int N, int K, int relu)
{
    constexpr int FR = BM / 32;          // frags per wave dim
    constexpr int RPW = BM / 4;          // staged rows per wave
    constexpr int NI = BM / 64;          // gload insts per operand per wave
    __shared__ __align__(16) unsigned short As[2][BM][32];
    __shared__ __align__(16) unsigned short Bs[2][BM][32];

    const int tid = threadIdx.x;
    const int lane = tid & 63;
    const int w = tid >> 6;
    const int wr = w >> 1, wc = w & 1;
    const int l16 = lane & 15, g = lane >> 4;

    // XCD-bijective swizzle, row-blocks fastest (B panel shared by adjacent blocks)
    const int nby = M / BM;
    const int nwg = (N / BM) * nby;
    const int cpx = nwg >> 3;
    const int bid = blockIdx.x;
    const int sbid = (bid & 7) * cpx + (bid >> 3);
    const int row0 = (sbid % nby) * BM;
    const int col0 = (sbid / nby) * BM;

    const int srow = w * RPW + (lane >> 2);
    const int scol = (lane & 3) * 8;

    const unsigned short* ga = A  + (size_t)(row0 + srow) * K + scol;
    const unsigned short* gb = BT + (size_t)(col0 + srow) * K + scol;

    f32x4 acc[FR][FR] = {};

    // prologue: stage tile 0
    #pragma unroll
    for (int i = 0; i < NI; ++i) {
        gload_lds16(ga + (size_t)(i * 16) * K, &As[0][srow + i * 16][scol]);
        gload_lds16(gb + (size_t)(i * 16) * K, &Bs[0][srow + i * 16][scol]);
    }
    __syncthreads();

    int cur = 0;
    for (int k0 = 0; k0 < K; k0 += 32) {
        // issue next tile's stage (async, in flight across MFMA)
        if (k0 + 32 < K) {
            #pragma unroll
            for (int i = 0; i < NI; ++i) {
                gload_lds16(ga + k0 + 32 + (size_t)(i * 16) * K, &As[cur ^ 1][srow + i * 16][scol]);
                gload_lds16(gb + k0 + 32 + (size_t)(i * 16) * K, &Bs[cur ^ 1][srow + i * 16][scol]);
            }
        }
        short8 af[FR], bf[FR];
        #pragma unroll
        for (int i = 0; i < FR; ++i)
            af[i] = *(const short8*)&As[cur][wr * (BM / 2) + i * 16 + l16][g * 8];
        #pragma unroll
        for (int j = 0; j < FR; ++j)
            bf[j] = *(const short8*)&Bs[cur][wc * (BM / 2) + j * 16 + l16][g * 8];
        #pragma unroll
        for (int i = 0; i < FR; ++i)
            #pragma unroll
            for (int j = 0; j < FR; ++j)
                acc[i][j] = __builtin_amdgcn_mfma_f32_16x16x32_bf16(af[i], bf[j], acc[i][j], 0, 0, 0);
        __syncthreads();   // drains next-tile stages (vmcnt) + this tile's ds_reads (lgkm)
        cur ^= 1;
    }

    #pragma unroll
    for (int i = 0; i < FR; ++i) {
        #pragma unroll
        for (int j = 0; j < FR; ++j) {
            #pragma unroll
            for (int r = 0; r < 4; ++r) {
                int row = row0 + wr * (BM / 2) + i * 16 + g * 4 + r;
                int col = col0 + wc * (BM / 2) + j * 16 + l16;
                float v = acc[i][j][r];
                if (bias)     v += bias[col];
                if (residual) v += residual[(size_t)row * N + col];
                if (relu)     v = fmaxf(v, 0.f);
                if (OUT_BF16) ((unsigned short*)Cout)[(size_t)row * N + col] = f2bf(v);
                else          ((float*)Cout)[(size_t)row * N + col] = v;
            }
        }
    }
}

// ---------------- MFMA flash attention (heavy-blocks-first) ----------------
__global__ __launch_bounds__(256)
void attn_flash_k(const unsigned short* __restrict__ qkv, unsigned short* __restrict__ out)
{
    __shared__ unsigned short Ks[64][72];
    __shared__ unsigned short Vt[64][72];
    __shared__ unsigned short Ps[4][16][72];

    const int tid = threadIdx.x;
    const int lane = tid & 63;
    const int w = tid >> 6;
    const int l16 = lane & 15, g = lane >> 4;
    // heavy-first: largest q-block launches first -> better round packing
    const int qb = gridDim.x - 1 - blockIdx.x;
    const int q0 = qb * 64;
    const int h = blockIdx.y;
    const int b = blockIdx.z;

    const size_t rstr = 3 * DM;
    const unsigned short* base = qkv + (size_t)b * TSEQ * rstr + h * HDIM;

    const int qrow_w = q0 + w * 16 + l16;
    short8 aq0 = *(const short8*)(base + (size_t)qrow_w * rstr + g * 8);
    short8 aq1 = *(const short8*)(base + (size_t)qrow_w * rstr + 32 + g * 8);

    f32x4 acc_o[4] = {};
    float m_r[4] = {-INFINITY, -INFINITY, -INFINITY, -INFINITY};
    float l_r[4] = {};

    const int qmax_w = q0 + w * 16 + 15;
    const int nt = qb + 1;

    for (int t = 0; t < nt; ++t) {
        const int kv0 = t * 64;
        #pragma unroll
        for (int i = 0; i < 2; ++i) {
            int c = tid + 256 * i;
            int row = c >> 3, off = (c & 7) * 8;
            *(short8*)&Ks[row][off] =
                *(const short8*)(base + (size_t)(kv0 + row) * rstr + DM + off);
        }
        {
            int kv = tid & 63, dg = tid >> 6;
            const unsigned short* vsrc = base + (size_t)(kv0 + kv) * rstr + 2 * DM + dg * 16;
            short8 v0 = *(const short8*)vsrc;
            short8 v1 = *(const short8*)(vsrc + 8);
            #pragma unroll
            for (int j = 0; j < 8; ++j) Vt[dg * 16 + j][kv] = (unsigned short)v0[j];
            #pragma unroll
            for (int j = 0; j < 8; ++j) Vt[dg * 16 + 8 + j][kv] = (unsigned short)v1[j];
        }
        __syncthreads();

        if (kv0 <= qmax_w) {
            f32x4 acc_s[4] = {};
            #pragma unroll
            for (int ks = 0; ks < 4; ++ks) {
                short8 bk0 = *(const short8*)&Ks[ks * 16 + l16][g * 8];
                short8 bk1 = *(const short8*)&Ks[ks * 16 + l16][32 + g * 8];
                acc_s[ks] = __builtin_amdgcn_mfma_f32_16x16x32_bf16(aq0, bk0, acc_s[ks], 0, 0, 0);
                acc_s[ks] = __builtin_amdgcn_mfma_f32_16x16x32_bf16(aq1, bk1, acc_s[ks], 0, 0, 0);
            }
            const bool need_mask = (kv0 + 63 > q0 + w * 16);
            float alpha[4];
            #pragma unroll
            for (int r = 0; r < 4; ++r) {
                const int q_abs = q0 + w * 16 + g * 4 + r;
                float s[4];
                #pragma unroll
                for (int ks = 0; ks < 4; ++ks) {
                    s[ks] = acc_s[ks][r] * 0.125f;
                    if (need_mask && (kv0 + ks * 16 + l16 > q_abs)) s[ks] = -INFINITY;
                }
                float pm = fmaxf(fmaxf(s[0], s[1]), fmaxf(s[2], s[3]));
                #pragma unroll
                for (int msk = 1; msk <= 8; msk <<= 1)
                    pm = fmaxf(pm, __shfl_xor(pm, msk));
                float mnew = fmaxf(m_r[r], pm);
                alpha[r] = __expf(m_r[r] - mnew);
                m_r[r] = mnew;
                float p[4], psum = 0.f;
                #pragma unroll
                for (int ks = 0; ks < 4; ++ks) {
                    p[ks] = (s[ks] == -INFINITY) ? 0.f : __expf(s[ks] - mnew);
                    psum += p[ks];
                }
                #pragma unroll
                for (int msk = 1; msk <= 8; msk <<= 1)
                    psum += __shfl_xor(psum, msk);
                l_r[r] = l_r[r] * alpha[r] + psum;
                #pragma unroll
                for (int ks = 0; ks < 4; ++ks)
                    Ps[w][g * 4 + r][ks * 16 + l16] = f2bf(p[ks]);
            }
            #pragma unroll
            for (int ds = 0; ds < 4; ++ds)
                #pragma unroll
                for (int r = 0; r < 4; ++r)
                    acc_o[ds][r] *= alpha[r];
            short8 ap0 = *(const short8*)&Ps[w][l16][g * 8];
            short8 ap1 = *(const short8*)&Ps[w][l16][32 + g * 8];
            #pragma unroll
            for (int ds = 0; ds < 4; ++ds) {
                short8 bv0 = *(const short8*)&Vt[ds * 16 + l16][g * 8];
                short8 bv1 = *(const short8*)&Vt[ds * 16 + l16][32 + g * 8];
                acc_o[ds] = __builtin_amdgcn_mfma_f32_16x16x32_bf16(ap0, bv0, acc_o[ds], 0, 0, 0);
                acc_o[ds] = __builtin_amdgcn_mfma_f32_16x16x32_bf16(ap1, bv1, acc_o[ds], 0, 0, 0);
            }
        }
        __syncthreads();
    }

    #pragma unroll
    for (int ds = 0; ds < 4; ++ds)
        #pragma unroll
        for (int r = 0; r < 4; ++r) {
            int row = q0 + w * 16 + g * 4 + r;
            out[((size_t)b * TSEQ + row) * DM + h * HDIM + ds * 16 + l16] =
                f2bf(acc_o[ds][r] * (1.f / l_r[r]));
        }
}

// ---------------- orchestration ----------------
extern "C" void kernel_launch(void* const* d_in, const int* in_sizes, int n_in,
                              void* d_out, int out_size, void* d_ws, size_t ws_size,
                              hipStream_t stream)
{
    const int*   idx    = (const int*)  d_in[0];
    const float* embed  = (const float*)d_in[1];
    const float* Wqkv   = (const float*)d_in[2];
    const float* Wproj  = (const float*)d_in[3];
    const float* bproj  = (const float*)d_in[4];
    const float* ln1_g  = (const float*)d_in[5];
    const float* ln1_b  = (const float*)d_in[6];
    const float* ln2_g  = (const float*)d_in[7];
    const float* ln2_b  = (const float*)d_in[8];
    const float* W1     = (const float*)d_in[9];
    const float* b1     = (const float*)d_in[10];
    const float* W2     = (const float*)d_in[11];
    const float* b2     = (const float*)d_in[12];
    const float* lnf_g  = (const float*)d_in[13];
    const float* lnf_b  = (const float*)d_in[14];
    const float* Whead  = (const float*)d_in[15];
    float* out = (float*)d_out;

    float* X = (float*)d_ws;                                  // f32 2048x1024
    unsigned short* u = (unsigned short*)(X + (size_t)NROWS * DM);
    unsigned short* XN     = u;  u += (size_t)NROWS * DM;          // bf16
    unsigned short* QKVb   = u;  u += (size_t)NROWS * 3 * DM;
    unsigned short* ATT    = u;  u += (size_t)NROWS * DM;
    unsigned short* FFH    = u;  u += (size_t)NROWS * DFFN;
    unsigned short* WqkvT  = u;  u += (size_t)NLAYER * 3 * DM * DM; // [3D][K]
    unsigned short* WprojT = u;  u += (size_t)NLAYER * DM * DM;
    unsigned short* W1T    = u;  u += (size_t)NLAYER * DFFN * DM;
    unsigned short* W2T    = u;  u += (size_t)NLAYER * DM * DFFN;
    unsigned short* WheadT = u;  u += (size_t)NVOC * DM;

    // ---- one-time weight convert+transpose ----
    convt_k<<<dim3(3 * DM / 64, DM / 64, NLAYER), 256, 0, stream>>>(Wqkv,  WqkvT,  DM,   3 * DM);
    convt_k<<<dim3(DM / 64,     DM / 64, NLAYER), 256, 0, stream>>>(Wproj, WprojT, DM,   DM);
    convt_k<<<dim3(DFFN / 64,   DM / 64, NLAYER), 256, 0, stream>>>(W1,    W1T,    DM,   DFFN);
    convt_k<<<dim3(DM / 64,   DFFN / 64, NLAYER), 256, 0, stream>>>(W2,    W2T,    DFFN, DM);
    convt_k<<<dim3(NVOC / 64,   DM / 64, 1),      256, 0, stream>>>(Whead, WheadT, DM,   NVOC);

    embed_pos_k<<<NROWS, 256, 0, stream>>>(idx, embed, X);

    for (int l = 0; l < NLAYER; ++l) {
        const unsigned short* wqkvT_l  = WqkvT  + (size_t)l * 3 * DM * DM;
        const unsigned short* wprojT_l = WprojT + (size_t)l * DM * DM;
        const unsigned short* w1T_l    = W1T    + (size_t)l * DFFN * DM;
        const unsigned short* w2T_l    = W2T    + (size_t)l * DM * DFFN;
        const float* bproj_l = bproj + (size_t)l * DM;
        const float* b1_l = b1 + (size_t)l * DFFN;
        const float* b2_l = b2 + (size_t)l * DM;

        layernorm_k<<<NROWS, 256, 0, stream>>>(X, ln1_g + (size_t)l * DM,
                                               ln1_b + (size_t)l * DM, XN);
        {   // qkv = ln1(x) @ Wqkv  (bf16 out)
            int nwg = (NROWS / 128) * (3 * DM / 128);
            gemm_tn<128, true><<<nwg, 256, 0, stream>>>(XN, wqkvT_l, nullptr, nullptr,
                                                        QKVb, NROWS, 3 * DM, DM, 0);
        }
        {   // flash attention
            dim3 grid(TSEQ / 64, NHEAD, NB);
            attn_flash_k<<<grid, 256, 0, stream>>>(QKVb, ATT);
        }
        {   // x = x + att @ Wproj + bproj
            int nwg = (NROWS / 64) * (DM / 64);
            gemm_tn<64, false><<<nwg, 256, 0, stream>>>(ATT, wprojT_l, bproj_l, X,
                                                        X, NROWS, DM, DM, 0);
        }
        layernorm_k<<<NROWS, 256, 0, stream>>>(X, ln2_g + (size_t)l * DM,
                                               ln2_b + (size_t)l * DM, XN);
        {   // ffh = relu(ln2 @ W1 + b1)
            int nwg = (NROWS / 128) * (DFFN / 128);
            gemm_tn<128, true><<<nwg, 256, 0, stream>>>(XN, w1T_l, b1_l, nullptr,
                                                        FFH, NROWS, DFFN, DM, 1);
        }
        {   // x = x + ffh @ W2 + b2
            int nwg = (NROWS / 64) * (DM / 64);
            gemm_tn<64, false><<<nwg, 256, 0, stream>>>(FFH, w2T_l, b2_l, X,
                                                        X, NROWS, DM, DFFN, 0);
        }
    }

    layernorm_k<<<NROWS, 256, 0, stream>>>(X, lnf_g, lnf_b, XN);
    {   // logits = lnf(x) @ Whead
        int nwg = (NROWS / 128) * (NVOC / 128);
        gemm_tn<128, false><<<nwg, 256, 0, stream>>>(XN, WheadT, nullptr, nullptr,
                                                     out, NROWS, NVOC, DM, 0);
    }
}

// Round 6
// 1905.410 us; speedup vs baseline: 15.9356x; 1.1621x over previous
//
#include <hip/hip_runtime.h>
#include <cstddef>

#define DM    1024
#define TSEQ  1024
#define NB    2
#define NHEAD 16
#define HDIM  64
#define NLAYER 8
#define DFFN  4096
#define NVOC  32000
#define NROWS (NB*TSEQ)

typedef __attribute__((ext_vector_type(8))) short short8;
typedef __attribute__((ext_vector_type(4))) float f32x4;

static __device__ __forceinline__ unsigned short f2bf(float f) {
    union { float f; unsigned int u; } v; v.f = f;
    unsigned int r = v.u + 0x7FFF + ((v.u >> 16) & 1);   // RNE
    return (unsigned short)(r >> 16);
}

static __device__ __forceinline__ void gload_lds16(const void* g, void* l) {
    __builtin_amdgcn_global_load_lds(
        (const __attribute__((address_space(1))) unsigned int*)g,
        (__attribute__((address_space(3))) unsigned int*)l, 16, 0, 0);
}

// ---------------- embedding + positional encoding (f32 out) ----------------
__global__ __launch_bounds__(256)
void embed_pos_k(const int* __restrict__ idx, const float* __restrict__ embed,
                 float* __restrict__ x)
{
    int row = blockIdx.x;
    int t   = row & (TSEQ - 1);
    int tid = threadIdx.x;
    int token = idx[row];
    const float* er = embed + (size_t)token * DM;
    float* xr = x + (size_t)row * DM;
    const float neg_ln1e4_over_d = -9.210340371976184f / (float)DM;
    for (int i = tid; i < DM; i += 256) {
        int half = i >> 1;
        float div = expf((float)(2 * half) * neg_ln1e4_over_d);
        float ang = (float)t * div;
        float pe = (i & 1) ? cosf(ang) : sinf(ang);
        xr[i] = er[i] + pe;
    }
}

// ---------------- layernorm (f32 in, bf16 out) ----------------
__global__ __launch_bounds__(256)
void layernorm_k(const float* __restrict__ x, const float* __restrict__ g,
                 const float* __restrict__ b, unsigned short* __restrict__ y)
{
    int row = blockIdx.x;
    int tid = threadIdx.x;
    const float* xr = x + (size_t)row * DM;
    unsigned short* yr = y + (size_t)row * DM;
    float vals[4];
    float s = 0.f;
    #pragma unroll
    for (int i = 0; i < 4; ++i) { vals[i] = xr[tid + 256 * i]; s += vals[i]; }
    __shared__ float red[256];
    red[tid] = s; __syncthreads();
    for (int st = 128; st > 0; st >>= 1) {
        if (tid < st) red[tid] += red[tid + st];
        __syncthreads();
    }
    float mu = red[0] * (1.f / DM);
    __syncthreads();
    float v = 0.f;
    #pragma unroll
    for (int i = 0; i < 4; ++i) { float d = vals[i] - mu; v += d * d; }
    red[tid] = v; __syncthreads();
    for (int st = 128; st > 0; st >>= 1) {
        if (tid < st) red[tid] += red[tid + st];
        __syncthreads();
    }
    float rstd = rsqrtf(red[0] * (1.f / DM) + 1e-5f);
    #pragma unroll
    for (int i = 0; i < 4; ++i) {
        int c = tid + 256 * i;
        yr[c] = f2bf((vals[i] - mu) * rstd * g[c] + b[c]);
    }
}

// ---------------- weight convert+transpose: f32 [K][N] -> bf16 [N][K] ----------------
__global__ __launch_bounds__(256)
void convt_k(const float* __restrict__ src, unsigned short* __restrict__ dst,
             int K, int N)
{
    __shared__ __align__(16) unsigned short T[64][72];
    const int tid = threadIdx.x;
    const int n0 = blockIdx.x * 64, k0 = blockIdx.y * 64;
    const float* s = src + (size_t)blockIdx.z * K * N;
    unsigned short* d = dst + (size_t)blockIdx.z * K * N;
    #pragma unroll
    for (int q = 0; q < 4; ++q) {
        int f4 = tid + q * 256;
        int kk = f4 >> 4, nn = (f4 & 15) * 4;
        float4 v = *(const float4*)(s + (size_t)(k0 + kk) * N + n0 + nn);
        int swz = ((nn >> 2) & 7) << 3;
        T[nn + 0][kk ^ swz] = f2bf(v.x);
        T[nn + 1][kk ^ swz] = f2bf(v.y);
        T[nn + 2][kk ^ swz] = f2bf(v.z);
        T[nn + 3][kk ^ swz] = f2bf(v.w);
    }
    __syncthreads();
    #pragma unroll
    for (int q = 0; q < 2; ++q) {
        int s8 = tid + q * 256;
        int nn = s8 >> 3, kc = (s8 & 7) * 8;
        int swz = ((nn >> 2) & 7) << 3;
        *(short8*)(d + (size_t)(n0 + nn) * K + k0 + kc) =
            *(const short8*)&T[nn][kc ^ swz];
    }
}

// ---------------- bf16 MFMA GEMM, double-buffered, optional split-K ----------------
// A: bf16 [M][KS]; BT: bf16 [N][KS]. Loops k over [blockIdx.y*K, +K).
// Split-K (blockIdx.y = split): Cout(float) += split*M*N, bias/residual must be null.
template<int BM, bool OUT_BF16>
__global__ __launch_bounds__(256)
void gemm_tn(const unsigned short* __restrict__ A, const unsigned short* __restrict__ BT,
             const float* __restrict__ bias, const float* __restrict__ residual,
             void* __restrict__ Cout, int M, int N, int K, int KS, int relu)
{
    constexpr int FR = BM / 32;
    constexpr int RPW = BM / 4;
    constexpr int NI = BM / 64;
    __shared__ __align__(16) unsigned short As[2][BM][32];
    __shared__ __align__(16) unsigned short Bs[2][BM][32];

    const int tid = threadIdx.x;
    const int lane = tid & 63;
    const int w = tid >> 6;
    const int wr = w >> 1, wc = w & 1;
    const int l16 = lane & 15, g = lane >> 4;

    const int nby = M / BM;
    const int nwg = (N / BM) * nby;
    const int cpx = nwg >> 3;
    const int bid = blockIdx.x;
    const int sbid = (bid & 7) * cpx + (bid >> 3);
    const int row0 = (sbid % nby) * BM;
    const int col0 = (sbid / nby) * BM;

    const int srow = w * RPW + (lane >> 2);
    const int scol = (lane & 3) * 8;

    const unsigned short* ga = A  + (size_t)(row0 + srow) * KS + (size_t)blockIdx.y * K + scol;
    const unsigned short* gb = BT + (size_t)(col0 + srow) * KS + (size_t)blockIdx.y * K + scol;

    f32x4 acc[FR][FR] = {};

    #pragma unroll
    for (int i = 0; i < NI; ++i) {
        gload_lds16(ga + (size_t)(i * 16) * KS, &As[0][srow + i * 16][scol]);
        gload_lds16(gb + (size_t)(i * 16) * KS, &Bs[0][srow + i * 16][scol]);
    }
    __syncthreads();

    int cur = 0;
    for (int k0 = 0; k0 < K; k0 += 32) {
        if (k0 + 32 < K) {
            #pragma unroll
            for (int i = 0; i < NI; ++i) {
                gload_lds16(ga + k0 + 32 + (size_t)(i * 16) * KS, &As[cur ^ 1][srow + i * 16][scol]);
                gload_lds16(gb + k0 + 32 + (size_t)(i * 16) * KS, &Bs[cur ^ 1][srow + i * 16][scol]);
            }
        }
        short8 af[FR], bf[FR];
        #pragma unroll
        for (int i = 0; i < FR; ++i)
            af[i] = *(const short8*)&As[cur][wr * (BM / 2) + i * 16 + l16][g * 8];
        #pragma unroll
        for (int j = 0; j < FR; ++j)
            bf[j] = *(const short8*)&Bs[cur][wc * (BM / 2) + j * 16 + l16][g * 8];
        #pragma unroll
        for (int i = 0; i < FR; ++i)
            #pragma unroll
            for (int j = 0; j < FR; ++j)
                acc[i][j] = __builtin_amdgcn_mfma_f32_16x16x32_bf16(af[i], bf[j], acc[i][j], 0, 0, 0);
        __syncthreads();
        cur ^= 1;
    }

    float* Cf = (float*)Cout + (size_t)blockIdx.y * M * N;
    #pragma unroll
    for (int i = 0; i < FR; ++i) {
        #pragma unroll
        for (int j = 0; j < FR; ++j) {
            #pragma unroll
            for (int r = 0; r < 4; ++r) {
                int row = row0 + wr * (BM / 2) + i * 16 + g * 4 + r;
                int col = col0 + wc * (BM / 2) + j * 16 + l16;
                float v = acc[i][j][r];
                if (bias)     v += bias[col];
                if (residual) v += residual[(size_t)row * N + col];
                if (relu)     v = fmaxf(v, 0.f);
                if (OUT_BF16) ((unsigned short*)Cout)[(size_t)row * N + col] = f2bf(v);
                else          Cf[(size_t)row * N + col] = v;
            }
        }
    }
}

// ---------------- split-K reduce: X = Xres + sum(P_s) + bias ----------------
__global__ __launch_bounds__(256)
void reduce_sk(const float* __restrict__ P, int nsplit, const float* __restrict__ bias,
               const float* __restrict__ Xres, float* __restrict__ X, int Ncols)
{
    const size_t i4 = (size_t)blockIdx.x * 256 + threadIdx.x;   // float4 index
    const int col4 = (int)(i4 & (Ncols / 4 - 1)) * 4;
    float4 v = *(const float4*)(Xres + i4 * 4);
    float4 bb = *(const float4*)(bias + col4);
    v.x += bb.x; v.y += bb.y; v.z += bb.z; v.w += bb.w;
    const size_t tot4 = (size_t)NROWS * Ncols / 4;
    for (int s = 0; s < nsplit; ++s) {
        float4 p = *(const float4*)(P + (s * tot4 + i4) * 4);
        v.x += p.x; v.y += p.y; v.z += p.z; v.w += p.w;
    }
    *(float4*)(X + i4 * 4) = v;
}

// ---------------- MFMA flash attention (paired q-tiles + async reg-stage) ----------------
// blockIdx.x = pid (0..7): handles q-tiles qb=pid and qb=15-pid -> constant 17 tile-rounds.
__global__ __launch_bounds__(256)
void attn_flash_k(const unsigned short* __restrict__ qkv, unsigned short* __restrict__ out)
{
    __shared__ unsigned short Ks[64][72];
    __shared__ unsigned short Vt[64][72];
    __shared__ unsigned short Ps[4][16][72];

    const int tid = threadIdx.x;
    const int lane = tid & 63;
    const int w = tid >> 6;
    const int l16 = lane & 15, g = lane >> 4;
    const int h = blockIdx.y;
    const int b = blockIdx.z;

    const size_t rstr = 3 * DM;
    const unsigned short* base = qkv + (size_t)b * TSEQ * rstr + h * HDIM;

    const int krow0 = tid >> 3, kcol = (tid & 7) * 8;   // K stage coords
    const int vkv = tid & 63, vdg = tid >> 6;           // V stage coords

    short8 kreg0, kreg1, vreg0, vreg1;

    #pragma unroll
    for (int pass = 0; pass < 2; ++pass) {
        const int qb = pass ? (15 - (int)blockIdx.x) : (int)blockIdx.x;
        const int q0 = qb * 64;
        const int nt = qb + 1;

        const int qrow_w = q0 + w * 16 + l16;
        short8 aq0 = *(const short8*)(base + (size_t)qrow_w * rstr + g * 8);
        short8 aq1 = *(const short8*)(base + (size_t)qrow_w * rstr + 32 + g * 8);

        f32x4 acc_o[4] = {};
        float m_r[4] = {-INFINITY, -INFINITY, -INFINITY, -INFINITY};
        float l_r[4] = {};

        // prologue: load tile 0 into regs
        {
            const unsigned short* kb = base + DM;
            kreg0 = *(const short8*)(kb + (size_t)krow0 * rstr + kcol);
            kreg1 = *(const short8*)(kb + (size_t)(32 + krow0) * rstr + kcol);
            const unsigned short* vsrc = base + (size_t)vkv * rstr + 2 * DM + vdg * 16;
            vreg0 = *(const short8*)vsrc;
            vreg1 = *(const short8*)(vsrc + 8);
        }

        for (int t = 0; t < nt; ++t) {
            // commit regs -> LDS
            *(short8*)&Ks[krow0][kcol] = kreg0;
            *(short8*)&Ks[32 + krow0][kcol] = kreg1;
            #pragma unroll
            for (int j = 0; j < 8; ++j) Vt[vdg * 16 + j][vkv] = (unsigned short)vreg0[j];
            #pragma unroll
            for (int j = 0; j < 8; ++j) Vt[vdg * 16 + 8 + j][vkv] = (unsigned short)vreg1[j];
            __syncthreads();

            // async: issue next tile's loads (in flight across compute)
            if (t + 1 < nt) {
                const int kv0 = (t + 1) * 64;
                const unsigned short* kb = base + (size_t)kv0 * rstr + DM;
                kreg0 = *(const short8*)(kb + (size_t)krow0 * rstr + kcol);
                kreg1 = *(const short8*)(kb + (size_t)(32 + krow0) * rstr + kcol);
                const unsigned short* vsrc = base + (size_t)(kv0 + vkv) * rstr + 2 * DM + vdg * 16;
                vreg0 = *(const short8*)vsrc;
                vreg1 = *(const short8*)(vsrc + 8);
            }

            const int kv0 = t * 64;
            // ---- S = Q K^T ----
            f32x4 acc_s[4] = {};
            #pragma unroll
            for (int ks = 0; ks < 4; ++ks) {
                short8 bk0 = *(const short8*)&Ks[ks * 16 + l16][g * 8];
                short8 bk1 = *(const short8*)&Ks[ks * 16 + l16][32 + g * 8];
                acc_s[ks] = __builtin_amdgcn_mfma_f32_16x16x32_bf16(aq0, bk0, acc_s[ks], 0, 0, 0);
                acc_s[ks] = __builtin_amdgcn_mfma_f32_16x16x32_bf16(aq1, bk1, acc_s[ks], 0, 0, 0);
            }
            const bool need_mask = (kv0 + 63 > q0 + w * 16);
            float alpha[4];
            #pragma unroll
            for (int r = 0; r < 4; ++r) {
                const int q_abs = q0 + w * 16 + g * 4 + r;
                float s[4];
                #pragma unroll
                for (int ks = 0; ks < 4; ++ks) {
                    s[ks] = acc_s[ks][r] * 0.125f;
                    if (need_mask && (kv0 + ks * 16 + l16 > q_abs)) s[ks] = -INFINITY;
                }
                float pm = fmaxf(fmaxf(s[0], s[1]), fmaxf(s[2], s[3]));
                #pragma unroll
                for (int msk = 1; msk <= 8; msk <<= 1)
                    pm = fmaxf(pm, __shfl_xor(pm, msk));
                float mnew = fmaxf(m_r[r], pm);
                alpha[r] = __expf(m_r[r] - mnew);
                m_r[r] = mnew;
                float p[4], psum = 0.f;
                #pragma unroll
                for (int ks = 0; ks < 4; ++ks) {
                    p[ks] = (s[ks] == -INFINITY) ? 0.f : __expf(s[ks] - mnew);
                    psum += p[ks];
                }
                #pragma unroll
                for (int msk = 1; msk <= 8; msk <<= 1)
                    psum += __shfl_xor(psum, msk);
                l_r[r] = l_r[r] * alpha[r] + psum;
                #pragma unroll
                for (int ks = 0; ks < 4; ++ks)
                    Ps[w][g * 4 + r][ks * 16 + l16] = f2bf(p[ks]);
            }
            #pragma unroll
            for (int ds = 0; ds < 4; ++ds)
                #pragma unroll
                for (int r = 0; r < 4; ++r)
                    acc_o[ds][r] *= alpha[r];
            short8 ap0 = *(const short8*)&Ps[w][l16][g * 8];
            short8 ap1 = *(const short8*)&Ps[w][l16][32 + g * 8];
            #pragma unroll
            for (int ds = 0; ds < 4; ++ds) {
                short8 bv0 = *(const short8*)&Vt[ds * 16 + l16][g * 8];
                short8 bv1 = *(const short8*)&Vt[ds * 16 + l16][32 + g * 8];
                acc_o[ds] = __builtin_amdgcn_mfma_f32_16x16x32_bf16(ap0, bv0, acc_o[ds], 0, 0, 0);
                acc_o[ds] = __builtin_amdgcn_mfma_f32_16x16x32_bf16(ap1, bv1, acc_o[ds], 0, 0, 0);
            }
            __syncthreads();
        }

        #pragma unroll
        for (int ds = 0; ds < 4; ++ds)
            #pragma unroll
            for (int r = 0; r < 4; ++r) {
                int row = q0 + w * 16 + g * 4 + r;
                out[((size_t)b * TSEQ + row) * DM + h * HDIM + ds * 16 + l16] =
                    f2bf(acc_o[ds][r] * (1.f / l_r[r]));
            }
    }
}

// ---------------- orchestration ----------------
extern "C" void kernel_launch(void* const* d_in, const int* in_sizes, int n_in,
                              void* d_out, int out_size, void* d_ws, size_t ws_size,
                              hipStream_t stream)
{
    const int*   idx    = (const int*)  d_in[0];
    const float* embed  = (const float*)d_in[1];
    const float* Wqkv   = (const float*)d_in[2];
    const float* Wproj  = (const float*)d_in[3];
    const float* bproj  = (const float*)d_in[4];
    const float* ln1_g  = (const float*)d_in[5];
    const float* ln1_b  = (const float*)d_in[6];
    const float* ln2_g  = (const float*)d_in[7];
    const float* ln2_b  = (const float*)d_in[8];
    const float* W1     = (const float*)d_in[9];
    const float* b1     = (const float*)d_in[10];
    const float* W2     = (const float*)d_in[11];
    const float* b2     = (const float*)d_in[12];
    const float* lnf_g  = (const float*)d_in[13];
    const float* lnf_b  = (const float*)d_in[14];
    const float* Whead  = (const float*)d_in[15];
    float* out = (float*)d_out;

    float* X = (float*)d_ws;                                       // f32 2048x1024
    float* PK = X + (size_t)NROWS * DM;                            // f32 partials 4x 2048x1024
    unsigned short* u = (unsigned short*)(PK + (size_t)4 * NROWS * DM);
    unsigned short* XN     = u;  u += (size_t)NROWS * DM;
    unsigned short* QKVb   = u;  u += (size_t)NROWS * 3 * DM;
    unsigned short* ATT    = u;  u += (size_t)NROWS * DM;
    unsigned short* FFH    = u;  u += (size_t)NROWS * DFFN;
    unsigned short* WqkvT  = u;  u += (size_t)NLAYER * 3 * DM * DM;
    unsigned short* WprojT = u;  u += (size_t)NLAYER * DM * DM;
    unsigned short* W1T    = u;  u += (size_t)NLAYER * DFFN * DM;
    unsigned short* W2T    = u;  u += (size_t)NLAYER * DM * DFFN;
    unsigned short* WheadT = u;  u += (size_t)NVOC * DM;

    convt_k<<<dim3(3 * DM / 64, DM / 64, NLAYER), 256, 0, stream>>>(Wqkv,  WqkvT,  DM,   3 * DM);
    convt_k<<<dim3(DM / 64,     DM / 64, NLAYER), 256, 0, stream>>>(Wproj, WprojT, DM,   DM);
    convt_k<<<dim3(DFFN / 64,   DM / 64, NLAYER), 256, 0, stream>>>(W1,    W1T,    DM,   DFFN);
    convt_k<<<dim3(DM / 64,   DFFN / 64, NLAYER), 256, 0, stream>>>(W2,    W2T,    DFFN, DM);
    convt_k<<<dim3(NVOC / 64,   DM / 64, 1),      256, 0, stream>>>(Whead, WheadT, DM,   NVOC);

    embed_pos_k<<<NROWS, 256, 0, stream>>>(idx, embed, X);

    const int nred = (NROWS * DM / 4) / 256;   // reduce_sk grid

    for (int l = 0; l < NLAYER; ++l) {
        const unsigned short* wqkvT_l  = WqkvT  + (size_t)l * 3 * DM * DM;
        const unsigned short* wprojT_l = WprojT + (size_t)l * DM * DM;
        const unsigned short* w1T_l    = W1T    + (size_t)l * DFFN * DM;
        const unsigned short* w2T_l    = W2T    + (size_t)l * DM * DFFN;
        const float* bproj_l = bproj + (size_t)l * DM;
        const float* b1_l = b1 + (size_t)l * DFFN;
        const float* b2_l = b2 + (size_t)l * DM;

        layernorm_k<<<NROWS, 256, 0, stream>>>(X, ln1_g + (size_t)l * DM,
                                               ln1_b + (size_t)l * DM, XN);
        {   // qkv = ln1(x) @ Wqkv  (bf16 out)
            int nwg = (NROWS / 128) * (3 * DM / 128);
            gemm_tn<128, true><<<nwg, 256, 0, stream>>>(XN, wqkvT_l, nullptr, nullptr,
                                                        QKVb, NROWS, 3 * DM, DM, DM, 0);
        }
        {   // flash attention (paired q-tiles)
            dim3 grid(TSEQ / 128, NHEAD, NB);
            attn_flash_k<<<grid, 256, 0, stream>>>(QKVb, ATT);
        }
        {   // proj: split-K=2 (K=512 each) -> partials, then reduce with residual+bias
            dim3 grid((NROWS / 128) * (DM / 128), 2);
            gemm_tn<128, false><<<grid, 256, 0, stream>>>(ATT, wprojT_l, nullptr, nullptr,
                                                          PK, NROWS, DM, 512, DM, 0);
            reduce_sk<<<nred, 256, 0, stream>>>(PK, 2, bproj_l, X, X, DM);
        }
        layernorm_k<<<NROWS, 256, 0, stream>>>(X, ln2_g + (size_t)l * DM,
                                               ln2_b + (size_t)l * DM, XN);
        {   // ffh = relu(ln2 @ W1 + b1)
            int nwg = (NROWS / 128) * (DFFN / 128);
            gemm_tn<128, true><<<nwg, 256, 0, stream>>>(XN, w1T_l, b1_l, nullptr,
                                                        FFH, NROWS, DFFN, DM, DM, 1);
        }
        {   // ffn2: split-K=4 (K=1024 each) -> partials, then reduce with residual+bias
            dim3 grid((NROWS / 128) * (DM / 128), 4);
            gemm_tn<128, false><<<grid, 256, 0, stream>>>(FFH, w2T_l, nullptr, nullptr,
                                                          PK, NROWS, DM, 1024, DFFN, 0);
            reduce_sk<<<nred, 256, 0, stream>>>(PK, 4, b2_l, X, X, DM);
        }
    }

    layernorm_k<<<NROWS, 256, 0, stream>>>(X, lnf_g, lnf_b, XN);
    {   // logits = lnf(x) @ Whead
        int nwg = (NROWS / 128) * (NVOC / 128);
        gemm_tn<128, false><<<nwg, 256, 0, stream>>>(XN, WheadT, nullptr, nullptr,
                                                     out, NROWS, NVOC, DM, DM, 0);
    }
}

// Round 7
// 1846.345 us; speedup vs baseline: 16.4454x; 1.0320x over previous
//
#include <hip/hip_runtime.h>
#include <cstddef>

#define DM    1024
#define TSEQ  1024
#define NB    2
#define NHEAD 16
#define HDIM  64
#define NLAYER 8
#define DFFN  4096
#define NVOC  32000
#define NROWS (NB*TSEQ)

typedef __attribute__((ext_vector_type(8))) short short8;
typedef __attribute__((ext_vector_type(4))) float f32x4;

static __device__ __forceinline__ unsigned short f2bf(float f) {
    union { float f; unsigned int u; } v; v.f = f;
    unsigned int r = v.u + 0x7FFF + ((v.u >> 16) & 1);   // RNE
    return (unsigned short)(r >> 16);
}

static __device__ __forceinline__ void gload_lds16(const void* g, void* l) {
    __builtin_amdgcn_global_load_lds(
        (const __attribute__((address_space(1))) unsigned int*)g,
        (__attribute__((address_space(3))) unsigned int*)l, 16, 0, 0);
}

// ---------------- embedding + positional encoding (f32 out) ----------------
__global__ __launch_bounds__(256)
void embed_pos_k(const int* __restrict__ idx, const float* __restrict__ embed,
                 float* __restrict__ x)
{
    int row = blockIdx.x;
    int t   = row & (TSEQ - 1);
    int tid = threadIdx.x;
    int token = idx[row];
    const float* er = embed + (size_t)token * DM;
    float* xr = x + (size_t)row * DM;
    const float neg_ln1e4_over_d = -9.210340371976184f / (float)DM;
    for (int i = tid; i < DM; i += 256) {
        int half = i >> 1;
        float div = expf((float)(2 * half) * neg_ln1e4_over_d);
        float ang = (float)t * div;
        float pe = (i & 1) ? cosf(ang) : sinf(ang);
        xr[i] = er[i] + pe;
    }
}

// ---------------- layernorm (f32 in, bf16 out) ----------------
__global__ __launch_bounds__(256)
void layernorm_k(const float* __restrict__ x, const float* __restrict__ g,
                 const float* __restrict__ b, unsigned short* __restrict__ y)
{
    int row = blockIdx.x;
    int tid = threadIdx.x;
    const float* xr = x + (size_t)row * DM;
    unsigned short* yr = y + (size_t)row * DM;
    float vals[4];
    float s = 0.f;
    #pragma unroll
    for (int i = 0; i < 4; ++i) { vals[i] = xr[tid + 256 * i]; s += vals[i]; }
    __shared__ float red[256];
    red[tid] = s; __syncthreads();
    for (int st = 128; st > 0; st >>= 1) {
        if (tid < st) red[tid] += red[tid + st];
        __syncthreads();
    }
    float mu = red[0] * (1.f / DM);
    __syncthreads();
    float v = 0.f;
    #pragma unroll
    for (int i = 0; i < 4; ++i) { float d = vals[i] - mu; v += d * d; }
    red[tid] = v; __syncthreads();
    for (int st = 128; st > 0; st >>= 1) {
        if (tid < st) red[tid] += red[tid + st];
        __syncthreads();
    }
    float rstd = rsqrtf(red[0] * (1.f / DM) + 1e-5f);
    #pragma unroll
    for (int i = 0; i < 4; ++i) {
        int c = tid + 256 * i;
        yr[c] = f2bf((vals[i] - mu) * rstd * g[c] + b[c]);
    }
}

// ---------------- fused split-K reduce + residual + bias + layernorm ----------------
// x_new = Xres + sum_s P[s] + bias;  X <- x_new;  XN <- LN(x_new, g, b)  (bf16)
// One row per block; each thread owns one float4 (DM/4 == 256).
__global__ __launch_bounds__(256)
void reduce_ln_k(const float* __restrict__ P, int nsplit, const float* __restrict__ bias,
                 float* __restrict__ X, const float* __restrict__ g,
                 const float* __restrict__ b, unsigned short* __restrict__ XN)
{
    const int row = blockIdx.x;
    const int tid = threadIdx.x;
    const size_t off4 = (size_t)row * 256 + tid;
    const size_t tot4 = (size_t)NROWS * 256;

    float4 v = *((const float4*)X + off4);
    float4 bb = *((const float4*)bias + tid);
    v.x += bb.x; v.y += bb.y; v.z += bb.z; v.w += bb.w;
    for (int s = 0; s < nsplit; ++s) {
        float4 p = *((const float4*)P + s * tot4 + off4);
        v.x += p.x; v.y += p.y; v.z += p.z; v.w += p.w;
    }
    *((float4*)X + off4) = v;

    __shared__ float red[256];
    red[tid] = v.x + v.y + v.z + v.w;
    __syncthreads();
    for (int st = 128; st > 0; st >>= 1) {
        if (tid < st) red[tid] += red[tid + st];
        __syncthreads();
    }
    float mu = red[0] * (1.f / DM);
    __syncthreads();
    float4 d = make_float4(v.x - mu, v.y - mu, v.z - mu, v.w - mu);
    red[tid] = d.x * d.x + d.y * d.y + d.z * d.z + d.w * d.w;
    __syncthreads();
    for (int st = 128; st > 0; st >>= 1) {
        if (tid < st) red[tid] += red[tid + st];
        __syncthreads();
    }
    float rstd = rsqrtf(red[0] * (1.f / DM) + 1e-5f);
    float4 gg = *((const float4*)g + tid);
    float4 bbn = *((const float4*)b + tid);
    unsigned short o[4];
    o[0] = f2bf(d.x * rstd * gg.x + bbn.x);
    o[1] = f2bf(d.y * rstd * gg.y + bbn.y);
    o[2] = f2bf(d.z * rstd * gg.z + bbn.z);
    o[3] = f2bf(d.w * rstd * gg.w + bbn.w);
    *(ushort4*)(XN + (size_t)row * DM + tid * 4) = *(ushort4*)o;
}

// ---------------- weight convert+transpose: f32 [K][N] -> bf16 [N][K] ----------------
__global__ __launch_bounds__(256)
void convt_k(const float* __restrict__ src, unsigned short* __restrict__ dst,
             int K, int N)
{
    __shared__ __align__(16) unsigned short T[64][72];
    const int tid = threadIdx.x;
    const int n0 = blockIdx.x * 64, k0 = blockIdx.y * 64;
    const float* s = src + (size_t)blockIdx.z * K * N;
    unsigned short* d = dst + (size_t)blockIdx.z * K * N;
    #pragma unroll
    for (int q = 0; q < 4; ++q) {
        int f4 = tid + q * 256;
        int kk = f4 >> 4, nn = (f4 & 15) * 4;
        float4 v = *(const float4*)(s + (size_t)(k0 + kk) * N + n0 + nn);
        int swz = ((nn >> 2) & 7) << 3;
        T[nn + 0][kk ^ swz] = f2bf(v.x);
        T[nn + 1][kk ^ swz] = f2bf(v.y);
        T[nn + 2][kk ^ swz] = f2bf(v.z);
        T[nn + 3][kk ^ swz] = f2bf(v.w);
    }
    __syncthreads();
    #pragma unroll
    for (int q = 0; q < 2; ++q) {
        int s8 = tid + q * 256;
        int nn = s8 >> 3, kc = (s8 & 7) * 8;
        int swz = ((nn >> 2) & 7) << 3;
        *(short8*)(d + (size_t)(n0 + nn) * K + k0 + kc) =
            *(const short8*)&T[nn][kc ^ swz];
    }
}

// ---------------- bf16 MFMA GEMM, dbuf + bank-conflict-free LDS swizzle ----------------
// LDS layout: chunk c (8 bf16) of row r stored at slot c ^ ((r>>1)&3).
// gload_lds writes linearly (lane*16), so the GLOBAL source is pre-permuted:
// lane fetches chunk (lane&3)^((lane>>3)&3) of its row. Read: slot g^((l16>>1)&3).
template<int BM, bool OUT_BF16>
__global__ __launch_bounds__(256)
void gemm_tn(const unsigned short* __restrict__ A, const unsigned short* __restrict__ BT,
             const float* __restrict__ bias, const float* __restrict__ residual,
             void* __restrict__ Cout, int M, int N, int K, int KS, int relu)
{
    constexpr int FR = BM / 32;
    constexpr int RPW = BM / 4;
    constexpr int NI = BM / 64;
    __shared__ __align__(16) unsigned short As[2][BM][32];
    __shared__ __align__(16) unsigned short Bs[2][BM][32];

    const int tid = threadIdx.x;
    const int lane = tid & 63;
    const int w = tid >> 6;
    const int wr = w >> 1, wc = w & 1;
    const int l16 = lane & 15, g = lane >> 4;

    const int nby = M / BM;
    const int nwg = (N / BM) * nby;
    const int cpx = nwg >> 3;
    const int bid = blockIdx.x;
    const int sbid = (bid & 7) * cpx + (bid >> 3);
    const int row0 = (sbid % nby) * BM;
    const int col0 = (sbid / nby) * BM;

    const int srow = w * RPW + (lane >> 2);
    // swizzled source chunk for this lane (see header comment)
    const int scol = (((lane & 3) ^ ((lane >> 3) & 3)) << 3);
    // swizzled read slot offset (elements)
    const int rslot = ((g ^ ((l16 >> 1) & 3)) << 3);

    const unsigned short* ga = A  + (size_t)(row0 + srow) * KS + (size_t)blockIdx.y * K + scol;
    const unsigned short* gb = BT + (size_t)(col0 + srow) * KS + (size_t)blockIdx.y * K + scol;

    f32x4 acc[FR][FR] = {};

    #pragma unroll
    for (int i = 0; i < NI; ++i) {
        gload_lds16(ga + (size_t)(i * 16) * KS, &As[0][srow + i * 16][(lane & 3) << 3]);
        gload_lds16(gb + (size_t)(i * 16) * KS, &Bs[0][srow + i * 16][(lane & 3) << 3]);
    }
    __syncthreads();

    int cur = 0;
    for (int k0 = 0; k0 < K; k0 += 32) {
        if (k0 + 32 < K) {
            #pragma unroll
            for (int i = 0; i < NI; ++i) {
                gload_lds16(ga + k0 + 32 + (size_t)(i * 16) * KS, &As[cur ^ 1][srow + i * 16][(lane & 3) << 3]);
                gload_lds16(gb + k0 + 32 + (size_t)(i * 16) * KS, &Bs[cur ^ 1][srow + i * 16][(lane & 3) << 3]);
            }
        }
        short8 af[FR], bf[FR];
        #pragma unroll
        for (int i = 0; i < FR; ++i)
            af[i] = *(const short8*)&As[cur][wr * (BM / 2) + i * 16 + l16][rslot];
        #pragma unroll
        for (int j = 0; j < FR; ++j)
            bf[j] = *(const short8*)&Bs[cur][wc * (BM / 2) + j * 16 + l16][rslot];
        #pragma unroll
        for (int i = 0; i < FR; ++i)
            #pragma unroll
            for (int j = 0; j < FR; ++j)
                acc[i][j] = __builtin_amdgcn_mfma_f32_16x16x32_bf16(af[i], bf[j], acc[i][j], 0, 0, 0);
        __syncthreads();
        cur ^= 1;
    }

    float* Cf = (float*)Cout + (size_t)blockIdx.y * M * N;
    #pragma unroll
    for (int i = 0; i < FR; ++i) {
        #pragma unroll
        for (int j = 0; j < FR; ++j) {
            #pragma unroll
            for (int r = 0; r < 4; ++r) {
                int row = row0 + wr * (BM / 2) + i * 16 + g * 4 + r;
                int col = col0 + wc * (BM / 2) + j * 16 + l16;
                float v = acc[i][j][r];
                if (bias)     v += bias[col];
                if (residual) v += residual[(size_t)row * N + col];
                if (relu)     v = fmaxf(v, 0.f);
                if (OUT_BF16) ((unsigned short*)Cout)[(size_t)row * N + col] = f2bf(v);
                else          Cf[(size_t)row * N + col] = v;
            }
        }
    }
}

// ---------------- MFMA flash attention (paired q-tiles + async reg-stage) ----------------
__global__ __launch_bounds__(256)
void attn_flash_k(const unsigned short* __restrict__ qkv, unsigned short* __restrict__ out)
{
    __shared__ unsigned short Ks[64][72];
    __shared__ unsigned short Vt[64][72];
    __shared__ unsigned short Ps[4][16][72];

    const int tid = threadIdx.x;
    const int lane = tid & 63;
    const int w = tid >> 6;
    const int l16 = lane & 15, g = lane >> 4;
    const int h = blockIdx.y;
    const int b = blockIdx.z;

    const size_t rstr = 3 * DM;
    const unsigned short* base = qkv + (size_t)b * TSEQ * rstr + h * HDIM;

    const int krow0 = tid >> 3, kcol = (tid & 7) * 8;
    const int vkv = tid & 63, vdg = tid >> 6;

    short8 kreg0, kreg1, vreg0, vreg1;

    #pragma unroll
    for (int pass = 0; pass < 2; ++pass) {
        const int qb = pass ? (15 - (int)blockIdx.x) : (int)blockIdx.x;
        const int q0 = qb * 64;
        const int nt = qb + 1;

        const int qrow_w = q0 + w * 16 + l16;
        short8 aq0 = *(const short8*)(base + (size_t)qrow_w * rstr + g * 8);
        short8 aq1 = *(const short8*)(base + (size_t)qrow_w * rstr + 32 + g * 8);

        f32x4 acc_o[4] = {};
        float m_r[4] = {-INFINITY, -INFINITY, -INFINITY, -INFINITY};
        float l_r[4] = {};

        {
            const unsigned short* kb = base + DM;
            kreg0 = *(const short8*)(kb + (size_t)krow0 * rstr + kcol);
            kreg1 = *(const short8*)(kb + (size_t)(32 + krow0) * rstr + kcol);
            const unsigned short* vsrc = base + (size_t)vkv * rstr + 2 * DM + vdg * 16;
            vreg0 = *(const short8*)vsrc;
            vreg1 = *(const short8*)(vsrc + 8);
        }

        for (int t = 0; t < nt; ++t) {
            *(short8*)&Ks[krow0][kcol] = kreg0;
            *(short8*)&Ks[32 + krow0][kcol] = kreg1;
            #pragma unroll
            for (int j = 0; j < 8; ++j) Vt[vdg * 16 + j][vkv] = (unsigned short)vreg0[j];
            #pragma unroll
            for (int j = 0; j < 8; ++j) Vt[vdg * 16 + 8 + j][vkv] = (unsigned short)vreg1[j];
            __syncthreads();

            if (t + 1 < nt) {
                const int kv0n = (t + 1) * 64;
                const unsigned short* kb = base + (size_t)kv0n * rstr + DM;
                kreg0 = *(const short8*)(kb + (size_t)krow0 * rstr + kcol);
                kreg1 = *(const short8*)(kb + (size_t)(32 + krow0) * rstr + kcol);
                const unsigned short* vsrc = base + (size_t)(kv0n + vkv) * rstr + 2 * DM + vdg * 16;
                vreg0 = *(const short8*)vsrc;
                vreg1 = *(const short8*)(vsrc + 8);
            }

            const int kv0 = t * 64;
            f32x4 acc_s[4] = {};
            #pragma unroll
            for (int ks = 0; ks < 4; ++ks) {
                short8 bk0 = *(const short8*)&Ks[ks * 16 + l16][g * 8];
                short8 bk1 = *(const short8*)&Ks[ks * 16 + l16][32 + g * 8];
                acc_s[ks] = __builtin_amdgcn_mfma_f32_16x16x32_bf16(aq0, bk0, acc_s[ks], 0, 0, 0);
                acc_s[ks] = __builtin_amdgcn_mfma_f32_16x16x32_bf16(aq1, bk1, acc_s[ks], 0, 0, 0);
            }
            const bool need_mask = (kv0 + 63 > q0 + w * 16);
            float alpha[4];
            #pragma unroll
            for (int r = 0; r < 4; ++r) {
                const int q_abs = q0 + w * 16 + g * 4 + r;
                float s[4];
                #pragma unroll
                for (int ks = 0; ks < 4; ++ks) {
                    s[ks] = acc_s[ks][r] * 0.125f;
                    if (need_mask && (kv0 + ks * 16 + l16 > q_abs)) s[ks] = -INFINITY;
                }
                float pm = fmaxf(fmaxf(s[0], s[1]), fmaxf(s[2], s[3]));
                #pragma unroll
                for (int msk = 1; msk <= 8; msk <<= 1)
                    pm = fmaxf(pm, __shfl_xor(pm, msk));
                float mnew = fmaxf(m_r[r], pm);
                alpha[r] = __expf(m_r[r] - mnew);
                m_r[r] = mnew;
                float p[4], psum = 0.f;
                #pragma unroll
                for (int ks = 0; ks < 4; ++ks) {
                    p[ks] = (s[ks] == -INFINITY) ? 0.f : __expf(s[ks] - mnew);
                    psum += p[ks];
                }
                #pragma unroll
                for (int msk = 1; msk <= 8; msk <<= 1)
                    psum += __shfl_xor(psum, msk);
                l_r[r] = l_r[r] * alpha[r] + psum;
                #pragma unroll
                for (int ks = 0; ks < 4; ++ks)
                    Ps[w][g * 4 + r][ks * 16 + l16] = f2bf(p[ks]);
            }
            #pragma unroll
            for (int ds = 0; ds < 4; ++ds)
                #pragma unroll
                for (int r = 0; r < 4; ++r)
                    acc_o[ds][r] *= alpha[r];
            short8 ap0 = *(const short8*)&Ps[w][l16][g * 8];
            short8 ap1 = *(const short8*)&Ps[w][l16][32 + g * 8];
            #pragma unroll
            for (int ds = 0; ds < 4; ++ds) {
                short8 bv0 = *(const short8*)&Vt[ds * 16 + l16][g * 8];
                short8 bv1 = *(const short8*)&Vt[ds * 16 + l16][32 + g * 8];
                acc_o[ds] = __builtin_amdgcn_mfma_f32_16x16x32_bf16(ap0, bv0, acc_o[ds], 0, 0, 0);
                acc_o[ds] = __builtin_amdgcn_mfma_f32_16x16x32_bf16(ap1, bv1, acc_o[ds], 0, 0, 0);
            }
            __syncthreads();
        }

        #pragma unroll
        for (int ds = 0; ds < 4; ++ds)
            #pragma unroll
            for (int r = 0; r < 4; ++r) {
                int row = q0 + w * 16 + g * 4 + r;
                out[((size_t)b * TSEQ + row) * DM + h * HDIM + ds * 16 + l16] =
                    f2bf(acc_o[ds][r] * (1.f / l_r[r]));
            }
    }
}

// ---------------- orchestration ----------------
extern "C" void kernel_launch(void* const* d_in, const int* in_sizes, int n_in,
                              void* d_out, int out_size, void* d_ws, size_t ws_size,
                              hipStream_t stream)
{
    const int*   idx    = (const int*)  d_in[0];
    const float* embed  = (const float*)d_in[1];
    const float* Wqkv   = (const float*)d_in[2];
    const float* Wproj  = (const float*)d_in[3];
    const float* bproj  = (const float*)d_in[4];
    const float* ln1_g  = (const float*)d_in[5];
    const float* ln1_b  = (const float*)d_in[6];
    const float* ln2_g  = (const float*)d_in[7];
    const float* ln2_b  = (const float*)d_in[8];
    const float* W1     = (const float*)d_in[9];
    const float* b1     = (const float*)d_in[10];
    const float* W2     = (const float*)d_in[11];
    const float* b2     = (const float*)d_in[12];
    const float* lnf_g  = (const float*)d_in[13];
    const float* lnf_b  = (const float*)d_in[14];
    const float* Whead  = (const float*)d_in[15];
    float* out = (float*)d_out;

    float* X = (float*)d_ws;                                       // f32 2048x1024
    float* PK = X + (size_t)NROWS * DM;                            // f32 partials 4x 2048x1024
    unsigned short* u = (unsigned short*)(PK + (size_t)4 * NROWS * DM);
    unsigned short* XN     = u;  u += (size_t)NROWS * DM;
    unsigned short* QKVb   = u;  u += (size_t)NROWS * 3 * DM;
    unsigned short* ATT    = u;  u += (size_t)NROWS * DM;
    unsigned short* FFH    = u;  u += (size_t)NROWS * DFFN;
    unsigned short* WqkvT  = u;  u += (size_t)NLAYER * 3 * DM * DM;
    unsigned short* WprojT = u;  u += (size_t)NLAYER * DM * DM;
    unsigned short* W1T    = u;  u += (size_t)NLAYER * DFFN * DM;
    unsigned short* W2T    = u;  u += (size_t)NLAYER * DM * DFFN;
    unsigned short* WheadT = u;  u += (size_t)NVOC * DM;

    convt_k<<<dim3(3 * DM / 64, DM / 64, NLAYER), 256, 0, stream>>>(Wqkv,  WqkvT,  DM,   3 * DM);
    convt_k<<<dim3(DM / 64,     DM / 64, NLAYER), 256, 0, stream>>>(Wproj, WprojT, DM,   DM);
    convt_k<<<dim3(DFFN / 64,   DM / 64, NLAYER), 256, 0, stream>>>(W1,    W1T,    DM,   DFFN);
    convt_k<<<dim3(DM / 64,   DFFN / 64, NLAYER), 256, 0, stream>>>(W2,    W2T,    DFFN, DM);
    convt_k<<<dim3(NVOC / 64,   DM / 64, 1),      256, 0, stream>>>(Whead, WheadT, DM,   NVOC);

    embed_pos_k<<<NROWS, 256, 0, stream>>>(idx, embed, X);
    layernorm_k<<<NROWS, 256, 0, stream>>>(X, ln1_g, ln1_b, XN);   // layer-0 ln1

    for (int l = 0; l < NLAYER; ++l) {
        const unsigned short* wqkvT_l  = WqkvT  + (size_t)l * 3 * DM * DM;
        const unsigned short* wprojT_l = WprojT + (size_t)l * DM * DM;
        const unsigned short* w1T_l    = W1T    + (size_t)l * DFFN * DM;
        const unsigned short* w2T_l    = W2T    + (size_t)l * DM * DFFN;
        const float* bproj_l = bproj + (size_t)l * DM;
        const float* b1_l = b1 + (size_t)l * DFFN;
        const float* b2_l = b2 + (size_t)l * DM;

        {   // qkv = ln1(x) @ Wqkv  (bf16 out)
            int nwg = (NROWS / 128) * (3 * DM / 128);
            gemm_tn<128, true><<<nwg, 256, 0, stream>>>(XN, wqkvT_l, nullptr, nullptr,
                                                        QKVb, NROWS, 3 * DM, DM, DM, 0);
        }
        {   // flash attention (paired q-tiles)
            dim3 grid(TSEQ / 128, NHEAD, NB);
            attn_flash_k<<<grid, 256, 0, stream>>>(QKVb, ATT);
        }
        {   // proj: split-K=2 -> partials; fused reduce + residual + bias + ln2
            dim3 grid((NROWS / 128) * (DM / 128), 2);
            gemm_tn<128, false><<<grid, 256, 0, stream>>>(ATT, wprojT_l, nullptr, nullptr,
                                                          PK, NROWS, DM, 512, DM, 0);
            reduce_ln_k<<<NROWS, 256, 0, stream>>>(PK, 2, bproj_l, X,
                                                   ln2_g + (size_t)l * DM,
                                                   ln2_b + (size_t)l * DM, XN);
        }
        {   // ffh = relu(ln2 @ W1 + b1)
            int nwg = (NROWS / 128) * (DFFN / 128);
            gemm_tn<128, true><<<nwg, 256, 0, stream>>>(XN, w1T_l, b1_l, nullptr,
                                                        FFH, NROWS, DFFN, DM, DM, 1);
        }
        {   // ffn2: split-K=4 -> partials; fused reduce + residual + bias + ln1[l+1]/lnf
            dim3 grid((NROWS / 128) * (DM / 128), 4);
            gemm_tn<128, false><<<grid, 256, 0, stream>>>(FFH, w2T_l, nullptr, nullptr,
                                                          PK, NROWS, DM, 1024, DFFN, 0);
            const float* ng = (l + 1 < NLAYER) ? ln1_g + (size_t)(l + 1) * DM : lnf_g;
            const float* nb = (l + 1 < NLAYER) ? ln1_b + (size_t)(l + 1) * DM : lnf_b;
            reduce_ln_k<<<NROWS, 256, 0, stream>>>(PK, 4, b2_l, X, ng, nb, XN);
        }
    }

    {   // logits = lnf(x) @ Whead
        int nwg = (NROWS / 128) * (NVOC / 128);
        gemm_tn<128, false><<<nwg, 256, 0, stream>>>(XN, WheadT, nullptr, nullptr,
                                                     out, NROWS, NVOC, DM, DM, 0);
    }
}

// Round 8
// 1819.004 us; speedup vs baseline: 16.6926x; 1.0150x over previous
//
#include <hip/hip_runtime.h>
#include <cstddef>

#define DM    1024
#define TSEQ  1024
#define NB    2
#define NHEAD 16
#define HDIM  64
#define NLAYER 8
#define DFFN  4096
#define NVOC  32000
#define NROWS (NB*TSEQ)

typedef __attribute__((ext_vector_type(8))) short short8;
typedef __attribute__((ext_vector_type(4))) float f32x4;

static __device__ __forceinline__ unsigned short f2bf(float f) {
    union { float f; unsigned int u; } v; v.f = f;
    unsigned int r = v.u + 0x7FFF + ((v.u >> 16) & 1);   // RNE
    return (unsigned short)(r >> 16);
}

static __device__ __forceinline__ void gload_lds16(const void* g, void* l) {
    __builtin_amdgcn_global_load_lds(
        (const __attribute__((address_space(1))) unsigned int*)g,
        (__attribute__((address_space(3))) unsigned int*)l, 16, 0, 0);
}

// ---------------- embedding + positional encoding (f32 out) ----------------
__global__ __launch_bounds__(256)
void embed_pos_k(const int* __restrict__ idx, const float* __restrict__ embed,
                 float* __restrict__ x)
{
    int row = blockIdx.x;
    int t   = row & (TSEQ - 1);
    int tid = threadIdx.x;
    int token = idx[row];
    const float* er = embed + (size_t)token * DM;
    float* xr = x + (size_t)row * DM;
    const float neg_ln1e4_over_d = -9.210340371976184f / (float)DM;
    for (int i = tid; i < DM; i += 256) {
        int half = i >> 1;
        float div = expf((float)(2 * half) * neg_ln1e4_over_d);
        float ang = (float)t * div;
        float pe = (i & 1) ? cosf(ang) : sinf(ang);
        xr[i] = er[i] + pe;
    }
}

// ---------------- layernorm (f32 in, bf16 out) ----------------
__global__ __launch_bounds__(256)
void layernorm_k(const float* __restrict__ x, const float* __restrict__ g,
                 const float* __restrict__ b, unsigned short* __restrict__ y)
{
    int row = blockIdx.x;
    int tid = threadIdx.x;
    const float* xr = x + (size_t)row * DM;
    unsigned short* yr = y + (size_t)row * DM;
    float vals[4];
    float s = 0.f;
    #pragma unroll
    for (int i = 0; i < 4; ++i) { vals[i] = xr[tid + 256 * i]; s += vals[i]; }
    __shared__ float red[256];
    red[tid] = s; __syncthreads();
    for (int st = 128; st > 0; st >>= 1) {
        if (tid < st) red[tid] += red[tid + st];
        __syncthreads();
    }
    float mu = red[0] * (1.f / DM);
    __syncthreads();
    float v = 0.f;
    #pragma unroll
    for (int i = 0; i < 4; ++i) { float d = vals[i] - mu; v += d * d; }
    red[tid] = v; __syncthreads();
    for (int st = 128; st > 0; st >>= 1) {
        if (tid < st) red[tid] += red[tid + st];
        __syncthreads();
    }
    float rstd = rsqrtf(red[0] * (1.f / DM) + 1e-5f);
    #pragma unroll
    for (int i = 0; i < 4; ++i) {
        int c = tid + 256 * i;
        yr[c] = f2bf((vals[i] - mu) * rstd * g[c] + b[c]);
    }
}

// ---------------- fused split-K reduce + residual + bias + layernorm ----------------
__global__ __launch_bounds__(256)
void reduce_ln_k(const float* __restrict__ P, int nsplit, const float* __restrict__ bias,
                 float* __restrict__ X, const float* __restrict__ g,
                 const float* __restrict__ b, unsigned short* __restrict__ XN)
{
    const int row = blockIdx.x;
    const int tid = threadIdx.x;
    const size_t off4 = (size_t)row * 256 + tid;
    const size_t tot4 = (size_t)NROWS * 256;

    float4 v = *((const float4*)X + off4);
    float4 bb = *((const float4*)bias + tid);
    v.x += bb.x; v.y += bb.y; v.z += bb.z; v.w += bb.w;
    for (int s = 0; s < nsplit; ++s) {
        float4 p = *((const float4*)P + s * tot4 + off4);
        v.x += p.x; v.y += p.y; v.z += p.z; v.w += p.w;
    }
    *((float4*)X + off4) = v;

    __shared__ float red[256];
    red[tid] = v.x + v.y + v.z + v.w;
    __syncthreads();
    for (int st = 128; st > 0; st >>= 1) {
        if (tid < st) red[tid] += red[tid + st];
        __syncthreads();
    }
    float mu = red[0] * (1.f / DM);
    __syncthreads();
    float4 d = make_float4(v.x - mu, v.y - mu, v.z - mu, v.w - mu);
    red[tid] = d.x * d.x + d.y * d.y + d.z * d.z + d.w * d.w;
    __syncthreads();
    for (int st = 128; st > 0; st >>= 1) {
        if (tid < st) red[tid] += red[tid + st];
        __syncthreads();
    }
    float rstd = rsqrtf(red[0] * (1.f / DM) + 1e-5f);
    float4 gg = *((const float4*)g + tid);
    float4 bbn = *((const float4*)b + tid);
    unsigned short o[4];
    o[0] = f2bf(d.x * rstd * gg.x + bbn.x);
    o[1] = f2bf(d.y * rstd * gg.y + bbn.y);
    o[2] = f2bf(d.z * rstd * gg.z + bbn.z);
    o[3] = f2bf(d.w * rstd * gg.w + bbn.w);
    *(ushort4*)(XN + (size_t)row * DM + tid * 4) = *(ushort4*)o;
}

// ---------------- weight convert+transpose: f32 [K][N] -> bf16 [N][K] ----------------
__global__ __launch_bounds__(256)
void convt_k(const float* __restrict__ src, unsigned short* __restrict__ dst,
             int K, int N)
{
    __shared__ __align__(16) unsigned short T[64][72];
    const int tid = threadIdx.x;
    const int n0 = blockIdx.x * 64, k0 = blockIdx.y * 64;
    const float* s = src + (size_t)blockIdx.z * K * N;
    unsigned short* d = dst + (size_t)blockIdx.z * K * N;
    #pragma unroll
    for (int q = 0; q < 4; ++q) {
        int f4 = tid + q * 256;
        int kk = f4 >> 4, nn = (f4 & 15) * 4;
        float4 v = *(const float4*)(s + (size_t)(k0 + kk) * N + n0 + nn);
        int swz = ((nn >> 2) & 7) << 3;
        T[nn + 0][kk ^ swz] = f2bf(v.x);
        T[nn + 1][kk ^ swz] = f2bf(v.y);
        T[nn + 2][kk ^ swz] = f2bf(v.z);
        T[nn + 3][kk ^ swz] = f2bf(v.w);
    }
    __syncthreads();
    #pragma unroll
    for (int q = 0; q < 2; ++q) {
        int s8 = tid + q * 256;
        int nn = s8 >> 3, kc = (s8 & 7) * 8;
        int swz = ((nn >> 2) & 7) << 3;
        *(short8*)(d + (size_t)(n0 + nn) * K + k0 + kc) =
            *(const short8*)&T[nn][kc ^ swz];
    }
}

// ---------------- 256x128 deep-pipelined MFMA GEMM (counted vmcnt, ring-3) ----------------
// A: bf16 [M][K] (M%256==0), BT: bf16 [N][K] (N%128==0), K%64==0.
// 512 threads = 8 waves (4 row-groups x 2 col-groups), per-wave 64x64 output.
// LDS: 3 tile banks (A 32KB + B 16KB each) = 144KB; stage(t+2) while reading t,
// t+1 landing in the third bank -> a bank is never read & written concurrently.
// XOR chunk swizzle (16B granularity): phys chunk c at row r holds logical c^(r&7);
// staging pre-permutes the GLOBAL source (gload_lds writes linearly), reads XOR back.
template<bool OUT_BF16>
__global__ __launch_bounds__(512)
void gemm256(const unsigned short* __restrict__ A, const unsigned short* __restrict__ BT,
             const float* __restrict__ bias, void* __restrict__ Cout,
             int M, int N, int K, int relu)
{
    __shared__ __align__(16) unsigned short AS[3][256][64];   // 96 KB
    __shared__ __align__(16) unsigned short BS[3][128][64];   // 48 KB

    const int tid  = threadIdx.x;
    const int lane = tid & 63;
    const int w    = tid >> 6;
    const int wm = w >> 1, wn = w & 1;
    const int l16 = lane & 15, g = lane >> 4;

    // XCD swizzle, row-tiles fastest (row-tiles share the B panel)
    const int nby = M / 256;
    const int nwg = nby * (N / 128);
    const int cpx = nwg >> 3;
    const int bid = (int)blockIdx.x;
    const int sbid = (bid & 7) * cpx + (bid >> 3);
    const int row0 = (sbid % nby) * 256;
    const int col0 = (sbid / nby) * 128;

    // staging coords: row srow (0..63) per instruction-slab, swizzled k-chunk
    const int srow = tid >> 3;
    const int schunk = ((tid & 7) ^ (srow & 7)) << 3;
    const unsigned short* ga = A  + (size_t)(row0 + srow) * K + schunk;
    const unsigned short* gb = BT + (size_t)(col0 + srow) * K + schunk;
    const int NT = K >> 6;

    f32x4 acc[4][4] = {};

    // prologue: stage tiles 0 and 1 into banks 0,1 (12 loads outstanding)
    #pragma unroll
    for (int t = 0; t < 2; ++t) {
        #pragma unroll
        for (int i = 0; i < 4; ++i)
            gload_lds16(ga + t * 64 + (size_t)(i * 64) * K,
                        (unsigned short*)AS[t] + i * 4096 + tid * 8);
        #pragma unroll
        for (int i = 0; i < 2; ++i)
            gload_lds16(gb + t * 64 + (size_t)(i * 64) * K,
                        (unsigned short*)BS[t] + i * 4096 + tid * 8);
    }
    asm volatile("s_waitcnt vmcnt(6)" ::: "memory");   // tile 0 landed; tile 1 in flight
    __builtin_amdgcn_s_barrier();

    for (int t = 0; t < NT; ++t) {
        const int rs = t % 3;
        // issue stage of tile t+2 into the bank freed after tile t-1
        if (t + 2 < NT) {
            const int ss = (t + 2) % 3;
            #pragma unroll
            for (int i = 0; i < 4; ++i)
                gload_lds16(ga + (t + 2) * 64 + (size_t)(i * 64) * K,
                            (unsigned short*)AS[ss] + i * 4096 + tid * 8);
            #pragma unroll
            for (int i = 0; i < 2; ++i)
                gload_lds16(gb + (t + 2) * 64 + (size_t)(i * 64) * K,
                            (unsigned short*)BS[ss] + i * 4096 + tid * 8);
        }
        // two k-steps of 32; frags read via XOR-swizzled chunks (conflict-free)
        #pragma unroll
        for (int s = 0; s < 2; ++s) {
            short8 af[4], bf[4];
            #pragma unroll
            for (int i = 0; i < 4; ++i) {
                const int ar = wm * 64 + i * 16 + l16;
                af[i] = *(const short8*)&AS[rs][ar][((((s << 2) | g) ^ (l16 & 7)) << 3)];
            }
            #pragma unroll
            for (int j = 0; j < 4; ++j) {
                const int br = wn * 64 + j * 16 + l16;
                bf[j] = *(const short8*)&BS[rs][br][((((s << 2) | g) ^ (l16 & 7)) << 3)];
            }
            __builtin_amdgcn_s_setprio(1);
            #pragma unroll
            for (int i = 0; i < 4; ++i)
                #pragma unroll
                for (int j = 0; j < 4; ++j)
                    acc[i][j] = __builtin_amdgcn_mfma_f32_16x16x32_bf16(af[i], bf[j], acc[i][j], 0, 0, 0);
            __builtin_amdgcn_s_setprio(0);
        }
        // counted wait: tile t+1's 6 loads landed; tile t+2's 6 may stay in flight
        if (t + 2 < NT) { asm volatile("s_waitcnt vmcnt(6)" ::: "memory"); }
        else            { asm volatile("s_waitcnt vmcnt(0)" ::: "memory"); }
        __builtin_amdgcn_s_barrier();
    }

    #pragma unroll
    for (int i = 0; i < 4; ++i) {
        #pragma unroll
        for (int j = 0; j < 4; ++j) {
            #pragma unroll
            for (int r = 0; r < 4; ++r) {
                int row = row0 + wm * 64 + i * 16 + g * 4 + r;
                int col = col0 + wn * 64 + j * 16 + l16;
                float v = acc[i][j][r];
                if (bias) v += bias[col];
                if (relu) v = fmaxf(v, 0.f);
                if (OUT_BF16) ((unsigned short*)Cout)[(size_t)row * N + col] = f2bf(v);
                else          ((float*)Cout)[(size_t)row * N + col] = v;
            }
        }
    }
}

// ---------------- bf16 MFMA GEMM 128^2 (dbuf, swizzled) — used for split-K ----------------
template<int BM, bool OUT_BF16>
__global__ __launch_bounds__(256)
void gemm_tn(const unsigned short* __restrict__ A, const unsigned short* __restrict__ BT,
             const float* __restrict__ bias, const float* __restrict__ residual,
             void* __restrict__ Cout, int M, int N, int K, int KS, int relu)
{
    constexpr int FR = BM / 32;
    constexpr int RPW = BM / 4;
    constexpr int NI = BM / 64;
    __shared__ __align__(16) unsigned short As[2][BM][32];
    __shared__ __align__(16) unsigned short Bs[2][BM][32];

    const int tid = threadIdx.x;
    const int lane = tid & 63;
    const int w = tid >> 6;
    const int wr = w >> 1, wc = w & 1;
    const int l16 = lane & 15, g = lane >> 4;

    const int nby = M / BM;
    const int nwg = (N / BM) * nby;
    const int cpx = nwg >> 3;
    const int bid = blockIdx.x;
    const int sbid = (bid & 7) * cpx + (bid >> 3);
    const int row0 = (sbid % nby) * BM;
    const int col0 = (sbid / nby) * BM;

    const int srow = w * RPW + (lane >> 2);
    const int scol = (((lane & 3) ^ ((lane >> 3) & 3)) << 3);
    const int rslot = ((g ^ ((l16 >> 1) & 3)) << 3);

    const unsigned short* ga = A  + (size_t)(row0 + srow) * KS + (size_t)blockIdx.y * K + scol;
    const unsigned short* gb = BT + (size_t)(col0 + srow) * KS + (size_t)blockIdx.y * K + scol;

    f32x4 acc[FR][FR] = {};

    #pragma unroll
    for (int i = 0; i < NI; ++i) {
        gload_lds16(ga + (size_t)(i * 16) * KS, &As[0][srow + i * 16][(lane & 3) << 3]);
        gload_lds16(gb + (size_t)(i * 16) * KS, &Bs[0][srow + i * 16][(lane & 3) << 3]);
    }
    __syncthreads();

    int cur = 0;
    for (int k0 = 0; k0 < K; k0 += 32) {
        if (k0 + 32 < K) {
            #pragma unroll
            for (int i = 0; i < NI; ++i) {
                gload_lds16(ga + k0 + 32 + (size_t)(i * 16) * KS, &As[cur ^ 1][srow + i * 16][(lane & 3) << 3]);
                gload_lds16(gb + k0 + 32 + (size_t)(i * 16) * KS, &Bs[cur ^ 1][srow + i * 16][(lane & 3) << 3]);
            }
        }
        short8 af[FR], bf[FR];
        #pragma unroll
        for (int i = 0; i < FR; ++i)
            af[i] = *(const short8*)&As[cur][wr * (BM / 2) + i * 16 + l16][rslot];
        #pragma unroll
        for (int j = 0; j < FR; ++j)
            bf[j] = *(const short8*)&Bs[cur][wc * (BM / 2) + j * 16 + l16][rslot];
        #pragma unroll
        for (int i = 0; i < FR; ++i)
            #pragma unroll
            for (int j = 0; j < FR; ++j)
                acc[i][j] = __builtin_amdgcn_mfma_f32_16x16x32_bf16(af[i], bf[j], acc[i][j], 0, 0, 0);
        __syncthreads();
        cur ^= 1;
    }

    float* Cf = (float*)Cout + (size_t)blockIdx.y * M * N;
    #pragma unroll
    for (int i = 0; i < FR; ++i) {
        #pragma unroll
        for (int j = 0; j < FR; ++j) {
            #pragma unroll
            for (int r = 0; r < 4; ++r) {
                int row = row0 + wr * (BM / 2) + i * 16 + g * 4 + r;
                int col = col0 + wc * (BM / 2) + j * 16 + l16;
                float v = acc[i][j][r];
                if (bias)     v += bias[col];
                if (residual) v += residual[(size_t)row * N + col];
                if (relu)     v = fmaxf(v, 0.f);
                if (OUT_BF16) ((unsigned short*)Cout)[(size_t)row * N + col] = f2bf(v);
                else          Cf[(size_t)row * N + col] = v;
            }
        }
    }
}

// ---------------- MFMA flash attention (paired q-tiles + async reg-stage) ----------------
__global__ __launch_bounds__(256)
void attn_flash_k(const unsigned short* __restrict__ qkv, unsigned short* __restrict__ out)
{
    __shared__ unsigned short Ks[64][72];
    __shared__ unsigned short Vt[64][72];
    __shared__ unsigned short Ps[4][16][72];

    const int tid = threadIdx.x;
    const int lane = tid & 63;
    const int w = tid >> 6;
    const int l16 = lane & 15, g = lane >> 4;
    const int h = blockIdx.y;
    const int b = blockIdx.z;

    const size_t rstr = 3 * DM;
    const unsigned short* base = qkv + (size_t)b * TSEQ * rstr + h * HDIM;

    const int krow0 = tid >> 3, kcol = (tid & 7) * 8;
    const int vkv = tid & 63, vdg = tid >> 6;

    short8 kreg0, kreg1, vreg0, vreg1;

    #pragma unroll
    for (int pass = 0; pass < 2; ++pass) {
        const int qb = pass ? (15 - (int)blockIdx.x) : (int)blockIdx.x;
        const int q0 = qb * 64;
        const int nt = qb + 1;

        const int qrow_w = q0 + w * 16 + l16;
        short8 aq0 = *(const short8*)(base + (size_t)qrow_w * rstr + g * 8);
        short8 aq1 = *(const short8*)(base + (size_t)qrow_w * rstr + 32 + g * 8);

        f32x4 acc_o[4] = {};
        float m_r[4] = {-INFINITY, -INFINITY, -INFINITY, -INFINITY};
        float l_r[4] = {};

        {
            const unsigned short* kb = base + DM;
            kreg0 = *(const short8*)(kb + (size_t)krow0 * rstr + kcol);
            kreg1 = *(const short8*)(kb + (size_t)(32 + krow0) * rstr + kcol);
            const unsigned short* vsrc = base + (size_t)vkv * rstr + 2 * DM + vdg * 16;
            vreg0 = *(const short8*)vsrc;
            vreg1 = *(const short8*)(vsrc + 8);
        }

        for (int t = 0; t < nt; ++t) {
            *(short8*)&Ks[krow0][kcol] = kreg0;
            *(short8*)&Ks[32 + krow0][kcol] = kreg1;
            #pragma unroll
            for (int j = 0; j < 8; ++j) Vt[vdg * 16 + j][vkv] = (unsigned short)vreg0[j];
            #pragma unroll
            for (int j = 0; j < 8; ++j) Vt[vdg * 16 + 8 + j][vkv] = (unsigned short)vreg1[j];
            __syncthreads();

            if (t + 1 < nt) {
                const int kv0n = (t + 1) * 64;
                const unsigned short* kb = base + (size_t)kv0n * rstr + DM;
                kreg0 = *(const short8*)(kb + (size_t)krow0 * rstr + kcol);
                kreg1 = *(const short8*)(kb + (size_t)(32 + krow0) * rstr + kcol);
                const unsigned short* vsrc = base + (size_t)(kv0n + vkv) * rstr + 2 * DM + vdg * 16;
                vreg0 = *(const short8*)vsrc;
                vreg1 = *(const short8*)(vsrc + 8);
            }

            const int kv0 = t * 64;
            f32x4 acc_s[4] = {};
            #pragma unroll
            for (int ks = 0; ks < 4; ++ks) {
                short8 bk0 = *(const short8*)&Ks[ks * 16 + l16][g * 8];
                short8 bk1 = *(const short8*)&Ks[ks * 16 + l16][32 + g * 8];
                acc_s[ks] = __builtin_amdgcn_mfma_f32_16x16x32_bf16(aq0, bk0, acc_s[ks], 0, 0, 0);
                acc_s[ks] = __builtin_amdgcn_mfma_f32_16x16x32_bf16(aq1, bk1, acc_s[ks], 0, 0, 0);
            }
            const bool need_mask = (kv0 + 63 > q0 + w * 16);
            float alpha[4];
            #pragma unroll
            for (int r = 0; r < 4; ++r) {
                const int q_abs = q0 + w * 16 + g * 4 + r;
                float s[4];
                #pragma unroll
                for (int ks = 0; ks < 4; ++ks) {
                    s[ks] = acc_s[ks][r] * 0.125f;
                    if (need_mask && (kv0 + ks * 16 + l16 > q_abs)) s[ks] = -INFINITY;
                }
                float pm = fmaxf(fmaxf(s[0], s[1]), fmaxf(s[2], s[3]));
                #pragma unroll
                for (int msk = 1; msk <= 8; msk <<= 1)
                    pm = fmaxf(pm, __shfl_xor(pm, msk));
                float mnew = fmaxf(m_r[r], pm);
                alpha[r] = __expf(m_r[r] - mnew);
                m_r[r] = mnew;
                float p[4], psum = 0.f;
                #pragma unroll
                for (int ks = 0; ks < 4; ++ks) {
                    p[ks] = (s[ks] == -INFINITY) ? 0.f : __expf(s[ks] - mnew);
                    psum += p[ks];
                }
                #pragma unroll
                for (int msk = 1; msk <= 8; msk <<= 1)
                    psum += __shfl_xor(psum, msk);
                l_r[r] = l_r[r] * alpha[r] + psum;
                #pragma unroll
                for (int ks = 0; ks < 4; ++ks)
                    Ps[w][g * 4 + r][ks * 16 + l16] = f2bf(p[ks]);
            }
            #pragma unroll
            for (int ds = 0; ds < 4; ++ds)
                #pragma unroll
                for (int r = 0; r < 4; ++r)
                    acc_o[ds][r] *= alpha[r];
            short8 ap0 = *(const short8*)&Ps[w][l16][g * 8];
            short8 ap1 = *(const short8*)&Ps[w][l16][32 + g * 8];
            #pragma unroll
            for (int ds = 0; ds < 4; ++ds) {
                short8 bv0 = *(const short8*)&Vt[ds * 16 + l16][g * 8];
                short8 bv1 = *(const short8*)&Vt[ds * 16 + l16][32 + g * 8];
                acc_o[ds] = __builtin_amdgcn_mfma_f32_16x16x32_bf16(ap0, bv0, acc_o[ds], 0, 0, 0);
                acc_o[ds] = __builtin_amdgcn_mfma_f32_16x16x32_bf16(ap1, bv1, acc_o[ds], 0, 0, 0);
            }
            __syncthreads();
        }

        #pragma unroll
        for (int ds = 0; ds < 4; ++ds)
            #pragma unroll
            for (int r = 0; r < 4; ++r) {
                int row = q0 + w * 16 + g * 4 + r;
                out[((size_t)b * TSEQ + row) * DM + h * HDIM + ds * 16 + l16] =
                    f2bf(acc_o[ds][r] * (1.f / l_r[r]));
            }
    }
}

// ---------------- orchestration ----------------
extern "C" void kernel_launch(void* const* d_in, const int* in_sizes, int n_in,
                              void* d_out, int out_size, void* d_ws, size_t ws_size,
                              hipStream_t stream)
{
    const int*   idx    = (const int*)  d_in[0];
    const float* embed  = (const float*)d_in[1];
    const float* Wqkv   = (const float*)d_in[2];
    const float* Wproj  = (const float*)d_in[3];
    const float* bproj  = (const float*)d_in[4];
    const float* ln1_g  = (const float*)d_in[5];
    const float* ln1_b  = (const float*)d_in[6];
    const float* ln2_g  = (const float*)d_in[7];
    const float* ln2_b  = (const float*)d_in[8];
    const float* W1     = (const float*)d_in[9];
    const float* b1     = (const float*)d_in[10];
    const float* W2     = (const float*)d_in[11];
    const float* b2     = (const float*)d_in[12];
    const float* lnf_g  = (const float*)d_in[13];
    const float* lnf_b  = (const float*)d_in[14];
    const float* Whead  = (const float*)d_in[15];
    float* out = (float*)d_out;

    float* X = (float*)d_ws;
    float* PK = X + (size_t)NROWS * DM;
    unsigned short* u = (unsigned short*)(PK + (size_t)4 * NROWS * DM);
    unsigned short* XN     = u;  u += (size_t)NROWS * DM;
    unsigned short* QKVb   = u;  u += (size_t)NROWS * 3 * DM;
    unsigned short* ATT    = u;  u += (size_t)NROWS * DM;
    unsigned short* FFH    = u;  u += (size_t)NROWS * DFFN;
    unsigned short* WqkvT  = u;  u += (size_t)NLAYER * 3 * DM * DM;
    unsigned short* WprojT = u;  u += (size_t)NLAYER * DM * DM;
    unsigned short* W1T    = u;  u += (size_t)NLAYER * DFFN * DM;
    unsigned short* W2T    = u;  u += (size_t)NLAYER * DM * DFFN;
    unsigned short* WheadT = u;  u += (size_t)NVOC * DM;

    convt_k<<<dim3(3 * DM / 64, DM / 64, NLAYER), 256, 0, stream>>>(Wqkv,  WqkvT,  DM,   3 * DM);
    convt_k<<<dim3(DM / 64,     DM / 64, NLAYER), 256, 0, stream>>>(Wproj, WprojT, DM,   DM);
    convt_k<<<dim3(DFFN / 64,   DM / 64, NLAYER), 256, 0, stream>>>(W1,    W1T,    DM,   DFFN);
    convt_k<<<dim3(DM / 64,   DFFN / 64, NLAYER), 256, 0, stream>>>(W2,    W2T,    DFFN, DM);
    convt_k<<<dim3(NVOC / 64,   DM / 64, 1),      256, 0, stream>>>(Whead, WheadT, DM,   NVOC);

    embed_pos_k<<<NROWS, 256, 0, stream>>>(idx, embed, X);
    layernorm_k<<<NROWS, 256, 0, stream>>>(X, ln1_g, ln1_b, XN);   // layer-0 ln1

    for (int l = 0; l < NLAYER; ++l) {
        const unsigned short* wqkvT_l  = WqkvT  + (size_t)l * 3 * DM * DM;
        const unsigned short* wprojT_l = WprojT + (size_t)l * DM * DM;
        const unsigned short* w1T_l    = W1T    + (size_t)l * DFFN * DM;
        const unsigned short* w2T_l    = W2T    + (size_t)l * DM * DFFN;
        const float* bproj_l = bproj + (size_t)l * DM;
        const float* b1_l = b1 + (size_t)l * DFFN;
        const float* b2_l = b2 + (size_t)l * DM;

        {   // qkv = ln1(x) @ Wqkv  (bf16 out), 256x128 pipeline: 192 blocks
            int nwg = (NROWS / 256) * (3 * DM / 128);
            gemm256<true><<<nwg, 512, 0, stream>>>(XN, wqkvT_l, nullptr,
                                                   QKVb, NROWS, 3 * DM, DM, 0);
        }
        {   // flash attention (paired q-tiles)
            dim3 grid(TSEQ / 128, NHEAD, NB);
            attn_flash_k<<<grid, 256, 0, stream>>>(QKVb, ATT);
        }
        {   // proj: split-K=2 -> partials; fused reduce + residual + bias + ln2
            dim3 grid((NROWS / 128) * (DM / 128), 2);
            gemm_tn<128, false><<<grid, 256, 0, stream>>>(ATT, wprojT_l, nullptr, nullptr,
                                                          PK, NROWS, DM, 512, DM, 0);
            reduce_ln_k<<<NROWS, 256, 0, stream>>>(PK, 2, bproj_l, X,
                                                   ln2_g + (size_t)l * DM,
                                                   ln2_b + (size_t)l * DM, XN);
        }
        {   // ffh = relu(ln2 @ W1 + b1): 256 blocks (full machine, 1 round)
            int nwg = (NROWS / 256) * (DFFN / 128);
            gemm256<true><<<nwg, 512, 0, stream>>>(XN, w1T_l, b1_l,
                                                   FFH, NROWS, DFFN, DM, 1);
        }
        {   // ffn2: split-K=4 -> partials; fused reduce + residual + bias + ln1[l+1]/lnf
            dim3 grid((NROWS / 128) * (DM / 128), 4);
            gemm_tn<128, false><<<grid, 256, 0, stream>>>(FFH, w2T_l, nullptr, nullptr,
                                                          PK, NROWS, DM, 1024, DFFN, 0);
            const float* ng = (l + 1 < NLAYER) ? ln1_g + (size_t)(l + 1) * DM : lnf_g;
            const float* nb = (l + 1 < NLAYER) ? ln1_b + (size_t)(l + 1) * DM : lnf_b;
            reduce_ln_k<<<NROWS, 256, 0, stream>>>(PK, 4, b2_l, X, ng, nb, XN);
        }
    }

    {   // logits = lnf(x) @ Whead: 2000 blocks
        int nwg = (NROWS / 256) * (NVOC / 128);
        gemm256<false><<<nwg, 512, 0, stream>>>(XN, WheadT, nullptr,
                                                out, NROWS, NVOC, DM, 0);
    }
}

// Round 9
// 1807.272 us; speedup vs baseline: 16.8009x; 1.0065x over previous
//
#include <hip/hip_runtime.h>
#include <cstddef>

#define DM    1024
#define TSEQ  1024
#define NB    2
#define NHEAD 16
#define HDIM  64
#define NLAYER 8
#define DFFN  4096
#define NVOC  32000
#define NROWS (NB*TSEQ)

typedef __attribute__((ext_vector_type(8))) short short8;
typedef __attribute__((ext_vector_type(4))) float f32x4;

static __device__ __forceinline__ unsigned short f2bf(float f) {
    union { float f; unsigned int u; } v; v.f = f;
    unsigned int r = v.u + 0x7FFF + ((v.u >> 16) & 1);   // RNE
    return (unsigned short)(r >> 16);
}

static __device__ __forceinline__ void gload_lds16(const void* g, void* l) {
    __builtin_amdgcn_global_load_lds(
        (const __attribute__((address_space(1))) unsigned int*)g,
        (__attribute__((address_space(3))) unsigned int*)l, 16, 0, 0);
}

// ---------------- embedding + positional encoding (f32 out) ----------------
__global__ __launch_bounds__(256)
void embed_pos_k(const int* __restrict__ idx, const float* __restrict__ embed,
                 float* __restrict__ x)
{
    int row = blockIdx.x;
    int t   = row & (TSEQ - 1);
    int tid = threadIdx.x;
    int token = idx[row];
    const float* er = embed + (size_t)token * DM;
    float* xr = x + (size_t)row * DM;
    const float neg_ln1e4_over_d = -9.210340371976184f / (float)DM;
    for (int i = tid; i < DM; i += 256) {
        int half = i >> 1;
        float div = expf((float)(2 * half) * neg_ln1e4_over_d);
        float ang = (float)t * div;
        float pe = (i & 1) ? cosf(ang) : sinf(ang);
        xr[i] = er[i] + pe;
    }
}

// ---------------- layernorm (f32 in, bf16 out) ----------------
__global__ __launch_bounds__(256)
void layernorm_k(const float* __restrict__ x, const float* __restrict__ g,
                 const float* __restrict__ b, unsigned short* __restrict__ y)
{
    int row = blockIdx.x;
    int tid = threadIdx.x;
    const float* xr = x + (size_t)row * DM;
    unsigned short* yr = y + (size_t)row * DM;
    float vals[4];
    float s = 0.f;
    #pragma unroll
    for (int i = 0; i < 4; ++i) { vals[i] = xr[tid + 256 * i]; s += vals[i]; }
    __shared__ float red[256];
    red[tid] = s; __syncthreads();
    for (int st = 128; st > 0; st >>= 1) {
        if (tid < st) red[tid] += red[tid + st];
        __syncthreads();
    }
    float mu = red[0] * (1.f / DM);
    __syncthreads();
    float v = 0.f;
    #pragma unroll
    for (int i = 0; i < 4; ++i) { float d = vals[i] - mu; v += d * d; }
    red[tid] = v; __syncthreads();
    for (int st = 128; st > 0; st >>= 1) {
        if (tid < st) red[tid] += red[tid + st];
        __syncthreads();
    }
    float rstd = rsqrtf(red[0] * (1.f / DM) + 1e-5f);
    #pragma unroll
    for (int i = 0; i < 4; ++i) {
        int c = tid + 256 * i;
        yr[c] = f2bf((vals[i] - mu) * rstd * g[c] + b[c]);
    }
}

// ---------------- fused split-K reduce + residual + bias + layernorm ----------------
__global__ __launch_bounds__(256)
void reduce_ln_k(const float* __restrict__ P, int nsplit, const float* __restrict__ bias,
                 float* __restrict__ X, const float* __restrict__ g,
                 const float* __restrict__ b, unsigned short* __restrict__ XN)
{
    const int row = blockIdx.x;
    const int tid = threadIdx.x;
    const size_t off4 = (size_t)row * 256 + tid;
    const size_t tot4 = (size_t)NROWS * 256;

    float4 v = *((const float4*)X + off4);
    float4 bb = *((const float4*)bias + tid);
    v.x += bb.x; v.y += bb.y; v.z += bb.z; v.w += bb.w;
    for (int s = 0; s < nsplit; ++s) {
        float4 p = *((const float4*)P + s * tot4 + off4);
        v.x += p.x; v.y += p.y; v.z += p.z; v.w += p.w;
    }
    *((float4*)X + off4) = v;

    __shared__ float red[256];
    red[tid] = v.x + v.y + v.z + v.w;
    __syncthreads();
    for (int st = 128; st > 0; st >>= 1) {
        if (tid < st) red[tid] += red[tid + st];
        __syncthreads();
    }
    float mu = red[0] * (1.f / DM);
    __syncthreads();
    float4 d = make_float4(v.x - mu, v.y - mu, v.z - mu, v.w - mu);
    red[tid] = d.x * d.x + d.y * d.y + d.z * d.z + d.w * d.w;
    __syncthreads();
    for (int st = 128; st > 0; st >>= 1) {
        if (tid < st) red[tid] += red[tid + st];
        __syncthreads();
    }
    float rstd = rsqrtf(red[0] * (1.f / DM) + 1e-5f);
    float4 gg = *((const float4*)g + tid);
    float4 bbn = *((const float4*)b + tid);
    unsigned short o[4];
    o[0] = f2bf(d.x * rstd * gg.x + bbn.x);
    o[1] = f2bf(d.y * rstd * gg.y + bbn.y);
    o[2] = f2bf(d.z * rstd * gg.z + bbn.z);
    o[3] = f2bf(d.w * rstd * gg.w + bbn.w);
    *(ushort4*)(XN + (size_t)row * DM + tid * 4) = *(ushort4*)o;
}

// ---------------- weight convert+transpose: f32 [K][N] -> bf16 [N][K] ----------------
__global__ __launch_bounds__(256)
void convt_k(const float* __restrict__ src, unsigned short* __restrict__ dst,
             int K, int N)
{
    __shared__ __align__(16) unsigned short T[64][72];
    const int tid = threadIdx.x;
    const int n0 = blockIdx.x * 64, k0 = blockIdx.y * 64;
    const float* s = src + (size_t)blockIdx.z * K * N;
    unsigned short* d = dst + (size_t)blockIdx.z * K * N;
    #pragma unroll
    for (int q = 0; q < 4; ++q) {
        int f4 = tid + q * 256;
        int kk = f4 >> 4, nn = (f4 & 15) * 4;
        float4 v = *(const float4*)(s + (size_t)(k0 + kk) * N + n0 + nn);
        int swz = ((nn >> 2) & 7) << 3;
        T[nn + 0][kk ^ swz] = f2bf(v.x);
        T[nn + 1][kk ^ swz] = f2bf(v.y);
        T[nn + 2][kk ^ swz] = f2bf(v.z);
        T[nn + 3][kk ^ swz] = f2bf(v.w);
    }
    __syncthreads();
    #pragma unroll
    for (int q = 0; q < 2; ++q) {
        int s8 = tid + q * 256;
        int nn = s8 >> 3, kc = (s8 & 7) * 8;
        int swz = ((nn >> 2) & 7) << 3;
        *(short8*)(d + (size_t)(n0 + nn) * K + k0 + kc) =
            *(const short8*)&T[nn][kc ^ swz];
    }
}

// ---------------- 256x128 4-phase deep-pipelined MFMA GEMM ----------------
// A: bf16 [M][K] (M%256==0), BT: bf16 [N][K] (N%128==0), K%64==0.
// 512 threads = 8 waves (4 row x 2 col), per-wave 64x64 output.
// Ring-3 LDS (144KB), counted vmcnt(6) at tile boundary, 4 fine phases per
// tile: {ds_read next frags | issue 1-2 stage gloads | setprio+8 MFMA | barrier}.
// Alternating register sets (aE/aO per phase, b0/b1 per k-half) - no copies.
// XOR chunk swizzle: phys chunk c at row r holds logical c^(r&7).
template<bool OUT_BF16>
__global__ __launch_bounds__(512)
void gemm256(const unsigned short* __restrict__ A, const unsigned short* __restrict__ BT,
             const float* __restrict__ bias, void* __restrict__ Cout,
             int M, int N, int K, int relu)
{
    __shared__ __align__(16) unsigned short AS[3][256][64];   // 96 KB
    __shared__ __align__(16) unsigned short BS[3][128][64];   // 48 KB

    const int tid  = threadIdx.x;
    const int lane = tid & 63;
    const int w    = tid >> 6;
    const int wm = w >> 1, wn = w & 1;
    const int l16 = lane & 15, g = lane >> 4;

    const int nby = M / 256;
    const int nwg = nby * (N / 128);
    const int cpx = nwg >> 3;
    const int bid = (int)blockIdx.x;
    const int sbid = (bid & 7) * cpx + (bid >> 3);
    const int row0 = (sbid % nby) * 256;
    const int col0 = (sbid / nby) * 128;

    const int srow = tid >> 3;
    const int schunk = ((tid & 7) ^ (srow & 7)) << 3;
    const unsigned short* ga = A  + (size_t)(row0 + srow) * K + schunk;
    const unsigned short* gb = BT + (size_t)(col0 + srow) * K + schunk;
    const int NT = K >> 6;

    // fragment read coordinates
    const int ch0 = ((g ^ (l16 & 7)) << 3);            // k-half 0 chunk (bytes/2)
    const int ch1 = (((4 | g) ^ (l16 & 7)) << 3);      // k-half 1 chunk
    const int ar0 = wm * 64 + 0  + l16;
    const int ar1 = wm * 64 + 16 + l16;
    const int ar2 = wm * 64 + 32 + l16;
    const int ar3 = wm * 64 + 48 + l16;
    const int br0 = wn * 64 + 0  + l16;
    const int br1 = wn * 64 + 16 + l16;
    const int br2 = wn * 64 + 32 + l16;
    const int br3 = wn * 64 + 48 + l16;

    f32x4 acc[4][4] = {};

    // prologue: stage tiles 0 and 1 into banks 0,1
    #pragma unroll
    for (int t = 0; t < 2; ++t) {
        #pragma unroll
        for (int i = 0; i < 4; ++i)
            gload_lds16(ga + t * 64 + (size_t)(i * 64) * K,
                        (unsigned short*)AS[t] + i * 4096 + tid * 8);
        #pragma unroll
        for (int i = 0; i < 2; ++i)
            gload_lds16(gb + t * 64 + (size_t)(i * 64) * K,
                        (unsigned short*)BS[t] + i * 4096 + tid * 8);
    }
    asm volatile("s_waitcnt vmcnt(6)" ::: "memory");   // tile 0 landed
    __builtin_amdgcn_s_barrier();

    // initial fragments: tile 0, k-half 0
    short8 aE0 = *(const short8*)&AS[0][ar0][ch0];
    short8 aE1 = *(const short8*)&AS[0][ar1][ch0];
    short8 aO0, aO1;
    short8 b0f[4], b1f[4];
    b0f[0] = *(const short8*)&BS[0][br0][ch0];
    b0f[1] = *(const short8*)&BS[0][br1][ch0];
    b0f[2] = *(const short8*)&BS[0][br2][ch0];
    b0f[3] = *(const short8*)&BS[0][br3][ch0];

    for (int t = 0; t < NT; ++t) {
        const int rs = t % 3;
        const int ss = (t + 2) % 3;
        const bool pf = (t + 2 < NT);
        const unsigned short* gat = ga + (t + 2) * 64;
        const unsigned short* gbt = gb + (t + 2) * 64;

        // ---- PHASE 0: mfma rows 0,1 (k-half 0); read A rows 2,3 (kh0); stage A slabs 0,1
        aO0 = *(const short8*)&AS[rs][ar2][ch0];
        aO1 = *(const short8*)&AS[rs][ar3][ch0];
        if (pf) {
            gload_lds16(gat,                      (unsigned short*)AS[ss] + 0 * 4096 + tid * 8);
            gload_lds16(gat + (size_t)64 * K,     (unsigned short*)AS[ss] + 1 * 4096 + tid * 8);
        }
        __builtin_amdgcn_s_setprio(1);
        #pragma unroll
        for (int j = 0; j < 4; ++j)
            acc[0][j] = __builtin_amdgcn_mfma_f32_16x16x32_bf16(aE0, b0f[j], acc[0][j], 0, 0, 0);
        #pragma unroll
        for (int j = 0; j < 4; ++j)
            acc[1][j] = __builtin_amdgcn_mfma_f32_16x16x32_bf16(aE1, b0f[j], acc[1][j], 0, 0, 0);
        __builtin_amdgcn_s_setprio(0);
        __builtin_amdgcn_s_barrier();

        // ---- PHASE 1: mfma rows 2,3 (kh0); read A rows 0,1 + B (kh1); stage A slabs 2,3
        aE0 = *(const short8*)&AS[rs][ar0][ch1];
        aE1 = *(const short8*)&AS[rs][ar1][ch1];
        b1f[0] = *(const short8*)&BS[rs][br0][ch1];
        b1f[1] = *(const short8*)&BS[rs][br1][ch1];
        b1f[2] = *(const short8*)&BS[rs][br2][ch1];
        b1f[3] = *(const short8*)&BS[rs][br3][ch1];
        if (pf) {
            gload_lds16(gat + (size_t)128 * K,    (unsigned short*)AS[ss] + 2 * 4096 + tid * 8);
            gload_lds16(gat + (size_t)192 * K,    (unsigned short*)AS[ss] + 3 * 4096 + tid * 8);
        }
        __builtin_amdgcn_s_setprio(1);
        #pragma unroll
        for (int j = 0; j < 4; ++j)
            acc[2][j] = __builtin_amdgcn_mfma_f32_16x16x32_bf16(aO0, b0f[j], acc[2][j], 0, 0, 0);
        #pragma unroll
        for (int j = 0; j < 4; ++j)
            acc[3][j] = __builtin_amdgcn_mfma_f32_16x16x32_bf16(aO1, b0f[j], acc[3][j], 0, 0, 0);
        __builtin_amdgcn_s_setprio(0);
        __builtin_amdgcn_s_barrier();

        // ---- PHASE 2: mfma rows 0,1 (kh1); read A rows 2,3 (kh1); stage B slab 0
        aO0 = *(const short8*)&AS[rs][ar2][ch1];
        aO1 = *(const short8*)&AS[rs][ar3][ch1];
        if (pf)
            gload_lds16(gbt,                      (unsigned short*)BS[ss] + 0 * 4096 + tid * 8);
        __builtin_amdgcn_s_setprio(1);
        #pragma unroll
        for (int j = 0; j < 4; ++j)
            acc[0][j] = __builtin_amdgcn_mfma_f32_16x16x32_bf16(aE0, b1f[j], acc[0][j], 0, 0, 0);
        #pragma unroll
        for (int j = 0; j < 4; ++j)
            acc[1][j] = __builtin_amdgcn_mfma_f32_16x16x32_bf16(aE1, b1f[j], acc[1][j], 0, 0, 0);
        __builtin_amdgcn_s_setprio(0);
        __builtin_amdgcn_s_barrier();

        // ---- PHASE 3: mfma rows 2,3 (kh1); stage B slab 1; boundary wait; preload t+1
        if (pf)
            gload_lds16(gbt + (size_t)64 * K,     (unsigned short*)BS[ss] + 1 * 4096 + tid * 8);
        __builtin_amdgcn_s_setprio(1);
        #pragma unroll
        for (int j = 0; j < 4; ++j)
            acc[2][j] = __builtin_amdgcn_mfma_f32_16x16x32_bf16(aO0, b1f[j], acc[2][j], 0, 0, 0);
        #pragma unroll
        for (int j = 0; j < 4; ++j)
            acc[3][j] = __builtin_amdgcn_mfma_f32_16x16x32_bf16(aO1, b1f[j], acc[3][j], 0, 0, 0);
        __builtin_amdgcn_s_setprio(0);
        if (pf) { asm volatile("s_waitcnt vmcnt(6)" ::: "memory"); }
        else    { asm volatile("s_waitcnt vmcnt(0)" ::: "memory"); }
        __builtin_amdgcn_s_barrier();

        if (t + 1 < NT) {
            const int rs2 = (t + 1) % 3;
            aE0 = *(const short8*)&AS[rs2][ar0][ch0];
            aE1 = *(const short8*)&AS[rs2][ar1][ch0];
            b0f[0] = *(const short8*)&BS[rs2][br0][ch0];
            b0f[1] = *(const short8*)&BS[rs2][br1][ch0];
            b0f[2] = *(const short8*)&BS[rs2][br2][ch0];
            b0f[3] = *(const short8*)&BS[rs2][br3][ch0];
        }
    }

    #pragma unroll
    for (int i = 0; i < 4; ++i) {
        #pragma unroll
        for (int j = 0; j < 4; ++j) {
            #pragma unroll
            for (int r = 0; r < 4; ++r) {
                int row = row0 + wm * 64 + i * 16 + g * 4 + r;
                int col = col0 + wn * 64 + j * 16 + l16;
                float v = acc[i][j][r];
                if (bias) v += bias[col];
                if (relu) v = fmaxf(v, 0.f);
                if (OUT_BF16) ((unsigned short*)Cout)[(size_t)row * N + col] = f2bf(v);
                else          ((float*)Cout)[(size_t)row * N + col] = v;
            }
        }
    }
}

// ---------------- bf16 MFMA GEMM 128^2 (dbuf, swizzled) — used for split-K ----------------
template<int BM, bool OUT_BF16>
__global__ __launch_bounds__(256)
void gemm_tn(const unsigned short* __restrict__ A, const unsigned short* __restrict__ BT,
             const float* __restrict__ bias, const float* __restrict__ residual,
             void* __restrict__ Cout, int M, int N, int K, int KS, int relu)
{
    constexpr int FR = BM / 32;
    constexpr int RPW = BM / 4;
    constexpr int NI = BM / 64;
    __shared__ __align__(16) unsigned short As[2][BM][32];
    __shared__ __align__(16) unsigned short Bs[2][BM][32];

    const int tid = threadIdx.x;
    const int lane = tid & 63;
    const int w = tid >> 6;
    const int wr = w >> 1, wc = w & 1;
    const int l16 = lane & 15, g = lane >> 4;

    const int nby = M / BM;
    const int nwg = (N / BM) * nby;
    const int cpx = nwg >> 3;
    const int bid = blockIdx.x;
    const int sbid = (bid & 7) * cpx + (bid >> 3);
    const int row0 = (sbid % nby) * BM;
    const int col0 = (sbid / nby) * BM;

    const int srow = w * RPW + (lane >> 2);
    const int scol = (((lane & 3) ^ ((lane >> 3) & 3)) << 3);
    const int rslot = ((g ^ ((l16 >> 1) & 3)) << 3);

    const unsigned short* ga = A  + (size_t)(row0 + srow) * KS + (size_t)blockIdx.y * K + scol;
    const unsigned short* gb = BT + (size_t)(col0 + srow) * KS + (size_t)blockIdx.y * K + scol;

    f32x4 acc[FR][FR] = {};

    #pragma unroll
    for (int i = 0; i < NI; ++i) {
        gload_lds16(ga + (size_t)(i * 16) * KS, &As[0][srow + i * 16][(lane & 3) << 3]);
        gload_lds16(gb + (size_t)(i * 16) * KS, &Bs[0][srow + i * 16][(lane & 3) << 3]);
    }
    __syncthreads();

    int cur = 0;
    for (int k0 = 0; k0 < K; k0 += 32) {
        if (k0 + 32 < K) {
            #pragma unroll
            for (int i = 0; i < NI; ++i) {
                gload_lds16(ga + k0 + 32 + (size_t)(i * 16) * KS, &As[cur ^ 1][srow + i * 16][(lane & 3) << 3]);
                gload_lds16(gb + k0 + 32 + (size_t)(i * 16) * KS, &Bs[cur ^ 1][srow + i * 16][(lane & 3) << 3]);
            }
        }
        short8 af[FR], bf[FR];
        #pragma unroll
        for (int i = 0; i < FR; ++i)
            af[i] = *(const short8*)&As[cur][wr * (BM / 2) + i * 16 + l16][rslot];
        #pragma unroll
        for (int j = 0; j < FR; ++j)
            bf[j] = *(const short8*)&Bs[cur][wc * (BM / 2) + j * 16 + l16][rslot];
        #pragma unroll
        for (int i = 0; i < FR; ++i)
            #pragma unroll
            for (int j = 0; j < FR; ++j)
                acc[i][j] = __builtin_amdgcn_mfma_f32_16x16x32_bf16(af[i], bf[j], acc[i][j], 0, 0, 0);
        __syncthreads();
        cur ^= 1;
    }

    float* Cf = (float*)Cout + (size_t)blockIdx.y * M * N;
    #pragma unroll
    for (int i = 0; i < FR; ++i) {
        #pragma unroll
        for (int j = 0; j < FR; ++j) {
            #pragma unroll
            for (int r = 0; r < 4; ++r) {
                int row = row0 + wr * (BM / 2) + i * 16 + g * 4 + r;
                int col = col0 + wc * (BM / 2) + j * 16 + l16;
                float v = acc[i][j][r];
                if (bias)     v += bias[col];
                if (residual) v += residual[(size_t)row * N + col];
                if (relu)     v = fmaxf(v, 0.f);
                if (OUT_BF16) ((unsigned short*)Cout)[(size_t)row * N + col] = f2bf(v);
                else          Cf[(size_t)row * N + col] = v;
            }
        }
    }
}

// ---------------- MFMA flash attention (paired q-tiles + async reg-stage) ----------------
__global__ __launch_bounds__(256)
void attn_flash_k(const unsigned short* __restrict__ qkv, unsigned short* __restrict__ out)
{
    __shared__ unsigned short Ks[64][72];
    __shared__ unsigned short Vt[64][72];
    __shared__ unsigned short Ps[4][16][72];

    const int tid = threadIdx.x;
    const int lane = tid & 63;
    const int w = tid >> 6;
    const int l16 = lane & 15, g = lane >> 4;
    const int h = blockIdx.y;
    const int b = blockIdx.z;

    const size_t rstr = 3 * DM;
    const unsigned short* base = qkv + (size_t)b * TSEQ * rstr + h * HDIM;

    const int krow0 = tid >> 3, kcol = (tid & 7) * 8;
    const int vkv = tid & 63, vdg = tid >> 6;

    short8 kreg0, kreg1, vreg0, vreg1;

    #pragma unroll
    for (int pass = 0; pass < 2; ++pass) {
        const int qb = pass ? (15 - (int)blockIdx.x) : (int)blockIdx.x;
        const int q0 = qb * 64;
        const int nt = qb + 1;

        const int qrow_w = q0 + w * 16 + l16;
        short8 aq0 = *(const short8*)(base + (size_t)qrow_w * rstr + g * 8);
        short8 aq1 = *(const short8*)(base + (size_t)qrow_w * rstr + 32 + g * 8);

        f32x4 acc_o[4] = {};
        float m_r[4] = {-INFINITY, -INFINITY, -INFINITY, -INFINITY};
        float l_r[4] = {};

        {
            const unsigned short* kb = base + DM;
            kreg0 = *(const short8*)(kb + (size_t)krow0 * rstr + kcol);
            kreg1 = *(const short8*)(kb + (size_t)(32 + krow0) * rstr + kcol);
            const unsigned short* vsrc = base + (size_t)vkv * rstr + 2 * DM + vdg * 16;
            vreg0 = *(const short8*)vsrc;
            vreg1 = *(const short8*)(vsrc + 8);
        }

        for (int t = 0; t < nt; ++t) {
            *(short8*)&Ks[krow0][kcol] = kreg0;
            *(short8*)&Ks[32 + krow0][kcol] = kreg1;
            #pragma unroll
            for (int j = 0; j < 8; ++j) Vt[vdg * 16 + j][vkv] = (unsigned short)vreg0[j];
            #pragma unroll
            for (int j = 0; j < 8; ++j) Vt[vdg * 16 + 8 + j][vkv] = (unsigned short)vreg1[j];
            __syncthreads();

            if (t + 1 < nt) {
                const int kv0n = (t + 1) * 64;
                const unsigned short* kb = base + (size_t)kv0n * rstr + DM;
                kreg0 = *(const short8*)(kb + (size_t)krow0 * rstr + kcol);
                kreg1 = *(const short8*)(kb + (size_t)(32 + krow0) * rstr + kcol);
                const unsigned short* vsrc = base + (size_t)(kv0n + vkv) * rstr + 2 * DM + vdg * 16;
                vreg0 = *(const short8*)vsrc;
                vreg1 = *(const short8*)(vsrc + 8);
            }

            const int kv0 = t * 64;
            f32x4 acc_s[4] = {};
            #pragma unroll
            for (int ks = 0; ks < 4; ++ks) {
                short8 bk0 = *(const short8*)&Ks[ks * 16 + l16][g * 8];
                short8 bk1 = *(const short8*)&Ks[ks * 16 + l16][32 + g * 8];
                acc_s[ks] = __builtin_amdgcn_mfma_f32_16x16x32_bf16(aq0, bk0, acc_s[ks], 0, 0, 0);
                acc_s[ks] = __builtin_amdgcn_mfma_f32_16x16x32_bf16(aq1, bk1, acc_s[ks], 0, 0, 0);
            }
            const bool need_mask = (kv0 + 63 > q0 + w * 16);
            float alpha[4];
            #pragma unroll
            for (int r = 0; r < 4; ++r) {
                const int q_abs = q0 + w * 16 + g * 4 + r;
                float s[4];
                #pragma unroll
                for (int ks = 0; ks < 4; ++ks) {
                    s[ks] = acc_s[ks][r] * 0.125f;
                    if (need_mask && (kv0 + ks * 16 + l16 > q_abs)) s[ks] = -INFINITY;
                }
                float pm = fmaxf(fmaxf(s[0], s[1]), fmaxf(s[2], s[3]));
                #pragma unroll
                for (int msk = 1; msk <= 8; msk <<= 1)
                    pm = fmaxf(pm, __shfl_xor(pm, msk));
                float mnew = fmaxf(m_r[r], pm);
                alpha[r] = __expf(m_r[r] - mnew);
                m_r[r] = mnew;
                float p[4], psum = 0.f;
                #pragma unroll
                for (int ks = 0; ks < 4; ++ks) {
                    p[ks] = (s[ks] == -INFINITY) ? 0.f : __expf(s[ks] - mnew);
                    psum += p[ks];
                }
                #pragma unroll
                for (int msk = 1; msk <= 8; msk <<= 1)
                    psum += __shfl_xor(psum, msk);
                l_r[r] = l_r[r] * alpha[r] + psum;
                #pragma unroll
                for (int ks = 0; ks < 4; ++ks)
                    Ps[w][g * 4 + r][ks * 16 + l16] = f2bf(p[ks]);
            }
            #pragma unroll
            for (int ds = 0; ds < 4; ++ds)
                #pragma unroll
                for (int r = 0; r < 4; ++r)
                    acc_o[ds][r] *= alpha[r];
            short8 ap0 = *(const short8*)&Ps[w][l16][g * 8];
            short8 ap1 = *(const short8*)&Ps[w][l16][32 + g * 8];
            #pragma unroll
            for (int ds = 0; ds < 4; ++ds) {
                short8 bv0 = *(const short8*)&Vt[ds * 16 + l16][g * 8];
                short8 bv1 = *(const short8*)&Vt[ds * 16 + l16][32 + g * 8];
                acc_o[ds] = __builtin_amdgcn_mfma_f32_16x16x32_bf16(ap0, bv0, acc_o[ds], 0, 0, 0);
                acc_o[ds] = __builtin_amdgcn_mfma_f32_16x16x32_bf16(ap1, bv1, acc_o[ds], 0, 0, 0);
            }
            __syncthreads();
        }

        #pragma unroll
        for (int ds = 0; ds < 4; ++ds)
            #pragma unroll
            for (int r = 0; r < 4; ++r) {
                int row = q0 + w * 16 + g * 4 + r;
                out[((size_t)b * TSEQ + row) * DM + h * HDIM + ds * 16 + l16] =
                    f2bf(acc_o[ds][r] * (1.f / l_r[r]));
            }
    }
}

// ---------------- orchestration ----------------
extern "C" void kernel_launch(void* const* d_in, const int* in_sizes, int n_in,
                              void* d_out, int out_size, void* d_ws, size_t ws_size,
                              hipStream_t stream)
{
    const int*   idx    = (const int*)  d_in[0];
    const float* embed  = (const float*)d_in[1];
    const float* Wqkv   = (const float*)d_in[2];
    const float* Wproj  = (const float*)d_in[3];
    const float* bproj  = (const float*)d_in[4];
    const float* ln1_g  = (const float*)d_in[5];
    const float* ln1_b  = (const float*)d_in[6];
    const float* ln2_g  = (const float*)d_in[7];
    const float* ln2_b  = (const float*)d_in[8];
    const float* W1     = (const float*)d_in[9];
    const float* b1     = (const float*)d_in[10];
    const float* W2     = (const float*)d_in[11];
    const float* b2     = (const float*)d_in[12];
    const float* lnf_g  = (const float*)d_in[13];
    const float* lnf_b  = (const float*)d_in[14];
    const float* Whead  = (const float*)d_in[15];
    float* out = (float*)d_out;

    float* X = (float*)d_ws;
    float* PK = X + (size_t)NROWS * DM;
    unsigned short* u = (unsigned short*)(PK + (size_t)4 * NROWS * DM);
    unsigned short* XN     = u;  u += (size_t)NROWS * DM;
    unsigned short* QKVb   = u;  u += (size_t)NROWS * 3 * DM;
    unsigned short* ATT    = u;  u += (size_t)NROWS * DM;
    unsigned short* FFH    = u;  u += (size_t)NROWS * DFFN;
    unsigned short* WqkvT  = u;  u += (size_t)NLAYER * 3 * DM * DM;
    unsigned short* WprojT = u;  u += (size_t)NLAYER * DM * DM;
    unsigned short* W1T    = u;  u += (size_t)NLAYER * DFFN * DM;
    unsigned short* W2T    = u;  u += (size_t)NLAYER * DM * DFFN;
    unsigned short* WheadT = u;  u += (size_t)NVOC * DM;

    convt_k<<<dim3(3 * DM / 64, DM / 64, NLAYER), 256, 0, stream>>>(Wqkv,  WqkvT,  DM,   3 * DM);
    convt_k<<<dim3(DM / 64,     DM / 64, NLAYER), 256, 0, stream>>>(Wproj, WprojT, DM,   DM);
    convt_k<<<dim3(DFFN / 64,   DM / 64, NLAYER), 256, 0, stream>>>(W1,    W1T,    DM,   DFFN);
    convt_k<<<dim3(DM / 64,   DFFN / 64, NLAYER), 256, 0, stream>>>(W2,    W2T,    DFFN, DM);
    convt_k<<<dim3(NVOC / 64,   DM / 64, 1),      256, 0, stream>>>(Whead, WheadT, DM,   NVOC);

    embed_pos_k<<<NROWS, 256, 0, stream>>>(idx, embed, X);
    layernorm_k<<<NROWS, 256, 0, stream>>>(X, ln1_g, ln1_b, XN);   // layer-0 ln1

    for (int l = 0; l < NLAYER; ++l) {
        const unsigned short* wqkvT_l  = WqkvT  + (size_t)l * 3 * DM * DM;
        const unsigned short* wprojT_l = WprojT + (size_t)l * DM * DM;
        const unsigned short* w1T_l    = W1T    + (size_t)l * DFFN * DM;
        const unsigned short* w2T_l    = W2T    + (size_t)l * DM * DFFN;
        const float* bproj_l = bproj + (size_t)l * DM;
        const float* b1_l = b1 + (size_t)l * DFFN;
        const float* b2_l = b2 + (size_t)l * DM;

        {   // qkv = ln1(x) @ Wqkv  (bf16 out), 192 blocks
            int nwg = (NROWS / 256) * (3 * DM / 128);
            gemm256<true><<<nwg, 512, 0, stream>>>(XN, wqkvT_l, nullptr,
                                                   QKVb, NROWS, 3 * DM, DM, 0);
        }
        {   // flash attention (paired q-tiles)
            dim3 grid(TSEQ / 128, NHEAD, NB);
            attn_flash_k<<<grid, 256, 0, stream>>>(QKVb, ATT);
        }
        {   // proj: split-K=2 -> partials; fused reduce + residual + bias + ln2
            dim3 grid((NROWS / 128) * (DM / 128), 2);
            gemm_tn<128, false><<<grid, 256, 0, stream>>>(ATT, wprojT_l, nullptr, nullptr,
                                                          PK, NROWS, DM, 512, DM, 0);
            reduce_ln_k<<<NROWS, 256, 0, stream>>>(PK, 2, bproj_l, X,
                                                   ln2_g + (size_t)l * DM,
                                                   ln2_b + (size_t)l * DM, XN);
        }
        {   // ffh = relu(ln2 @ W1 + b1): 256 blocks
            int nwg = (NROWS / 256) * (DFFN / 128);
            gemm256<true><<<nwg, 512, 0, stream>>>(XN, w1T_l, b1_l,
                                                   FFH, NROWS, DFFN, DM, 1);
        }
        {   // ffn2: split-K=4 -> partials; fused reduce + residual + bias + ln1[l+1]/lnf
            dim3 grid((NROWS / 128) * (DM / 128), 4);
            gemm_tn<128, false><<<grid, 256, 0, stream>>>(FFH, w2T_l, nullptr, nullptr,
                                                          PK, NROWS, DM, 1024, DFFN, 0);
            const float* ng = (l + 1 < NLAYER) ? ln1_g + (size_t)(l + 1) * DM : lnf_g;
            const float* nb = (l + 1 < NLAYER) ? ln1_b + (size_t)(l + 1) * DM : lnf_b;
            reduce_ln_k<<<NROWS, 256, 0, stream>>>(PK, 4, b2_l, X, ng, nb, XN);
        }
    }

    {   // logits = lnf(x) @ Whead: 2000 blocks
        int nwg = (NROWS / 256) * (NVOC / 128);
        gemm256<false><<<nwg, 512, 0, stream>>>(XN, WheadT, nullptr,
                                                out, NROWS, NVOC, DM, 0);
    }
}

// Round 10
// 1736.191 us; speedup vs baseline: 17.4888x; 1.0409x over previous
//
#include <hip/hip_runtime.h>
#include <cstddef>

#define DM    1024
#define TSEQ  1024
#define NB    2
#define NHEAD 16
#define HDIM  64
#define NLAYER 8
#define DFFN  4096
#define NVOC  32000
#define NROWS (NB*TSEQ)

typedef __attribute__((ext_vector_type(8))) short short8;
typedef __attribute__((ext_vector_type(4))) float f32x4;

static __device__ __forceinline__ unsigned short f2bf(float f) {
    union { float f; unsigned int u; } v; v.f = f;
    unsigned int r = v.u + 0x7FFF + ((v.u >> 16) & 1);   // RNE
    return (unsigned short)(r >> 16);
}

static __device__ __forceinline__ void gload_lds16(const void* g, void* l) {
    __builtin_amdgcn_global_load_lds(
        (const __attribute__((address_space(1))) unsigned int*)g,
        (__attribute__((address_space(3))) unsigned int*)l, 16, 0, 0);
}

// ---------------- embedding + positional encoding (f32 out) ----------------
__global__ __launch_bounds__(256)
void embed_pos_k(const int* __restrict__ idx, const float* __restrict__ embed,
                 float* __restrict__ x)
{
    int row = blockIdx.x;
    int t   = row & (TSEQ - 1);
    int tid = threadIdx.x;
    int token = idx[row];
    const float* er = embed + (size_t)token * DM;
    float* xr = x + (size_t)row * DM;
    const float neg_ln1e4_over_d = -9.210340371976184f / (float)DM;
    for (int i = tid; i < DM; i += 256) {
        int half = i >> 1;
        float div = expf((float)(2 * half) * neg_ln1e4_over_d);
        float ang = (float)t * div;
        float pe = (i & 1) ? cosf(ang) : sinf(ang);
        xr[i] = er[i] + pe;
    }
}

// ---------------- layernorm (f32 in, bf16 out) ----------------
__global__ __launch_bounds__(256)
void layernorm_k(const float* __restrict__ x, const float* __restrict__ g,
                 const float* __restrict__ b, unsigned short* __restrict__ y)
{
    int row = blockIdx.x;
    int tid = threadIdx.x;
    const float* xr = x + (size_t)row * DM;
    unsigned short* yr = y + (size_t)row * DM;
    float vals[4];
    float s = 0.f;
    #pragma unroll
    for (int i = 0; i < 4; ++i) { vals[i] = xr[tid + 256 * i]; s += vals[i]; }
    __shared__ float red[256];
    red[tid] = s; __syncthreads();
    for (int st = 128; st > 0; st >>= 1) {
        if (tid < st) red[tid] += red[tid + st];
        __syncthreads();
    }
    float mu = red[0] * (1.f / DM);
    __syncthreads();
    float v = 0.f;
    #pragma unroll
    for (int i = 0; i < 4; ++i) { float d = vals[i] - mu; v += d * d; }
    red[tid] = v; __syncthreads();
    for (int st = 128; st > 0; st >>= 1) {
        if (tid < st) red[tid] += red[tid + st];
        __syncthreads();
    }
    float rstd = rsqrtf(red[0] * (1.f / DM) + 1e-5f);
    #pragma unroll
    for (int i = 0; i < 4; ++i) {
        int c = tid + 256 * i;
        yr[c] = f2bf((vals[i] - mu) * rstd * g[c] + b[c]);
    }
}

// ---------------- fused split-K reduce + residual + bias + layernorm ----------------
__global__ __launch_bounds__(256)
void reduce_ln_k(const float* __restrict__ P, int nsplit, const float* __restrict__ bias,
                 float* __restrict__ X, const float* __restrict__ g,
                 const float* __restrict__ b, unsigned short* __restrict__ XN)
{
    const int row = blockIdx.x;
    const int tid = threadIdx.x;
    const size_t off4 = (size_t)row * 256 + tid;
    const size_t tot4 = (size_t)NROWS * 256;

    float4 v = *((const float4*)X + off4);
    float4 bb = *((const float4*)bias + tid);
    v.x += bb.x; v.y += bb.y; v.z += bb.z; v.w += bb.w;
    for (int s = 0; s < nsplit; ++s) {
        float4 p = *((const float4*)P + s * tot4 + off4);
        v.x += p.x; v.y += p.y; v.z += p.z; v.w += p.w;
    }
    *((float4*)X + off4) = v;

    __shared__ float red[256];
    red[tid] = v.x + v.y + v.z + v.w;
    __syncthreads();
    for (int st = 128; st > 0; st >>= 1) {
        if (tid < st) red[tid] += red[tid + st];
        __syncthreads();
    }
    float mu = red[0] * (1.f / DM);
    __syncthreads();
    float4 d = make_float4(v.x - mu, v.y - mu, v.z - mu, v.w - mu);
    red[tid] = d.x * d.x + d.y * d.y + d.z * d.z + d.w * d.w;
    __syncthreads();
    for (int st = 128; st > 0; st >>= 1) {
        if (tid < st) red[tid] += red[tid + st];
        __syncthreads();
    }
    float rstd = rsqrtf(red[0] * (1.f / DM) + 1e-5f);
    float4 gg = *((const float4*)g + tid);
    float4 bbn = *((const float4*)b + tid);
    unsigned short o[4];
    o[0] = f2bf(d.x * rstd * gg.x + bbn.x);
    o[1] = f2bf(d.y * rstd * gg.y + bbn.y);
    o[2] = f2bf(d.z * rstd * gg.z + bbn.z);
    o[3] = f2bf(d.w * rstd * gg.w + bbn.w);
    *(ushort4*)(XN + (size_t)row * DM + tid * 4) = *(ushort4*)o;
}

// ---------------- weight convert+transpose: f32 [K][N] -> bf16 [N][K] ----------------
__global__ __launch_bounds__(256)
void convt_k(const float* __restrict__ src, unsigned short* __restrict__ dst,
             int K, int N)
{
    __shared__ __align__(16) unsigned short T[64][72];
    const int tid = threadIdx.x;
    const int n0 = blockIdx.x * 64, k0 = blockIdx.y * 64;
    const float* s = src + (size_t)blockIdx.z * K * N;
    unsigned short* d = dst + (size_t)blockIdx.z * K * N;
    #pragma unroll
    for (int q = 0; q < 4; ++q) {
        int f4 = tid + q * 256;
        int kk = f4 >> 4, nn = (f4 & 15) * 4;
        float4 v = *(const float4*)(s + (size_t)(k0 + kk) * N + n0 + nn);
        int swz = ((nn >> 2) & 7) << 3;
        T[nn + 0][kk ^ swz] = f2bf(v.x);
        T[nn + 1][kk ^ swz] = f2bf(v.y);
        T[nn + 2][kk ^ swz] = f2bf(v.z);
        T[nn + 3][kk ^ swz] = f2bf(v.w);
    }
    __syncthreads();
    #pragma unroll
    for (int q = 0; q < 2; ++q) {
        int s8 = tid + q * 256;
        int nn = s8 >> 3, kc = (s8 & 7) * 8;
        int swz = ((nn >> 2) & 7) << 3;
        *(short8*)(d + (size_t)(n0 + nn) * K + k0 + kc) =
            *(const short8*)&T[nn][kc ^ swz];
    }
}

// ---------------- bf16 MFMA GEMM 128^2: ring-3 LDS + counted vmcnt ----------------
// A: bf16 [M][KS]; BT: bf16 [N][KS]; k in [blockIdx.y*K, +K).
// One raw s_barrier per K-step; stage(t+1) issued BEFORE the barrier into
// buf((t+1)%3); vmcnt(4) leaves the fresh 4 loads in flight a full iteration
// (never drains to 0 mid-loop). Race-free: reads of buf((t+1)%3) happened at
// iter t-2 and were consumed by MFMA before BAR(t-1) < any iter-t write.
// XOR involution swizzle (verified conflict-free, R7: BANK_CONFLICT=0).
template<int BM, bool OUT_BF16>
__global__ __launch_bounds__(256)
void gemm_tn(const unsigned short* __restrict__ A, const unsigned short* __restrict__ BT,
             const float* __restrict__ bias, const float* __restrict__ residual,
             void* __restrict__ Cout, int M, int N, int K, int KS, int relu)
{
    constexpr int FR = BM / 32;
    constexpr int RPW = BM / 4;
    constexpr int NI = BM / 64;
    __shared__ __align__(16) unsigned short As[3][BM][32];
    __shared__ __align__(16) unsigned short Bs[3][BM][32];

    const int tid = threadIdx.x;
    const int lane = tid & 63;
    const int w = tid >> 6;
    const int wr = w >> 1, wc = w & 1;
    const int l16 = lane & 15, g = lane >> 4;

    const int nby = M / BM;
    const int nwg = (N / BM) * nby;
    const int cpx = nwg >> 3;
    const int bid = blockIdx.x;
    const int sbid = (bid & 7) * cpx + (bid >> 3);
    const int row0 = (sbid % nby) * BM;
    const int col0 = (sbid / nby) * BM;

    const int srow = w * RPW + (lane >> 2);
    const int scol = (((lane & 3) ^ ((lane >> 3) & 3)) << 3);   // pre-permuted global chunk
    const int rslot = ((g ^ ((l16 >> 1) & 3)) << 3);            // swizzled read slot
    const int ldst = (lane & 3) << 3;                            // linear LDS dest chunk

    const unsigned short* ga = A  + (size_t)(row0 + srow) * KS + (size_t)blockIdx.y * K + scol;
    const unsigned short* gb = BT + (size_t)(col0 + srow) * KS + (size_t)blockIdx.y * K + scol;

    f32x4 acc[FR][FR] = {};
    const int NT = K >> 5;

    // prologue: stage tile 0 into buf 0
    #pragma unroll
    for (int i = 0; i < NI; ++i) {
        gload_lds16(ga + (size_t)(i * 16) * KS, &As[0][srow + i * 16][ldst]);
        gload_lds16(gb + (size_t)(i * 16) * KS, &Bs[0][srow + i * 16][ldst]);
    }

    for (int t = 0; t < NT; ++t) {
        const int rb = t % 3;
        // stage tile t+1 into buf (t+1)%3 (issued before the barrier; counted wait)
        if (t + 1 < NT) {
            const int wb2 = (t + 1) % 3;
            const int ko = (t + 1) * 32;
            #pragma unroll
            for (int i = 0; i < NI; ++i) {
                gload_lds16(ga + ko + (size_t)(i * 16) * KS, &As[wb2][srow + i * 16][ldst]);
                gload_lds16(gb + ko + (size_t)(i * 16) * KS, &Bs[wb2][srow + i * 16][ldst]);
            }
            asm volatile("s_waitcnt vmcnt(4)" ::: "memory");   // tile t landed; t+1 in flight
        } else {
            asm volatile("s_waitcnt vmcnt(0)" ::: "memory");
        }
        __builtin_amdgcn_s_barrier();

        short8 af[FR], bf[FR];
        #pragma unroll
        for (int i = 0; i < FR; ++i)
            af[i] = *(const short8*)&As[rb][wr * (BM / 2) + i * 16 + l16][rslot];
        #pragma unroll
        for (int j = 0; j < FR; ++j)
            bf[j] = *(const short8*)&Bs[rb][wc * (BM / 2) + j * 16 + l16][rslot];
        __builtin_amdgcn_s_setprio(1);
        #pragma unroll
        for (int i = 0; i < FR; ++i)
            #pragma unroll
            for (int j = 0; j < FR; ++j)
                acc[i][j] = __builtin_amdgcn_mfma_f32_16x16x32_bf16(af[i], bf[j], acc[i][j], 0, 0, 0);
        __builtin_amdgcn_s_setprio(0);
    }

    float* Cf = (float*)Cout + (size_t)blockIdx.y * M * N;
    #pragma unroll
    for (int i = 0; i < FR; ++i) {
        #pragma unroll
        for (int j = 0; j < FR; ++j) {
            #pragma unroll
            for (int r = 0; r < 4; ++r) {
                int row = row0 + wr * (BM / 2) + i * 16 + g * 4 + r;
                int col = col0 + wc * (BM / 2) + j * 16 + l16;
                float v = acc[i][j][r];
                if (bias)     v += bias[col];
                if (residual) v += residual[(size_t)row * N + col];
                if (relu)     v = fmaxf(v, 0.f);
                if (OUT_BF16) ((unsigned short*)Cout)[(size_t)row * N + col] = f2bf(v);
                else          Cf[(size_t)row * N + col] = v;
            }
        }
    }
}

// ---------------- 256x128 4-phase deep-pipelined MFMA GEMM (qkv/ffn1) ----------------
template<bool OUT_BF16>
__global__ __launch_bounds__(512)
void gemm256(const unsigned short* __restrict__ A, const unsigned short* __restrict__ BT,
             const float* __restrict__ bias, void* __restrict__ Cout,
             int M, int N, int K, int relu)
{
    __shared__ __align__(16) unsigned short AS[3][256][64];   // 96 KB
    __shared__ __align__(16) unsigned short BS[3][128][64];   // 48 KB

    const int tid  = threadIdx.x;
    const int lane = tid & 63;
    const int w    = tid >> 6;
    const int wm = w >> 1, wn = w & 1;
    const int l16 = lane & 15, g = lane >> 4;

    const int nby = M / 256;
    const int nwg = nby * (N / 128);
    const int cpx = nwg >> 3;
    const int bid = (int)blockIdx.x;
    const int sbid = (bid & 7) * cpx + (bid >> 3);
    const int row0 = (sbid % nby) * 256;
    const int col0 = (sbid / nby) * 128;

    const int srow = tid >> 3;
    const int schunk = ((tid & 7) ^ (srow & 7)) << 3;
    const unsigned short* ga = A  + (size_t)(row0 + srow) * K + schunk;
    const unsigned short* gb = BT + (size_t)(col0 + srow) * K + schunk;
    const int NT = K >> 6;

    const int ch0 = ((g ^ (l16 & 7)) << 3);
    const int ch1 = (((4 | g) ^ (l16 & 7)) << 3);
    const int ar0 = wm * 64 + 0  + l16;
    const int ar1 = wm * 64 + 16 + l16;
    const int ar2 = wm * 64 + 32 + l16;
    const int ar3 = wm * 64 + 48 + l16;
    const int br0 = wn * 64 + 0  + l16;
    const int br1 = wn * 64 + 16 + l16;
    const int br2 = wn * 64 + 32 + l16;
    const int br3 = wn * 64 + 48 + l16;

    f32x4 acc[4][4] = {};

    #pragma unroll
    for (int t = 0; t < 2; ++t) {
        #pragma unroll
        for (int i = 0; i < 4; ++i)
            gload_lds16(ga + t * 64 + (size_t)(i * 64) * K,
                        (unsigned short*)AS[t] + i * 4096 + tid * 8);
        #pragma unroll
        for (int i = 0; i < 2; ++i)
            gload_lds16(gb + t * 64 + (size_t)(i * 64) * K,
                        (unsigned short*)BS[t] + i * 4096 + tid * 8);
    }
    asm volatile("s_waitcnt vmcnt(6)" ::: "memory");
    __builtin_amdgcn_s_barrier();

    short8 aE0 = *(const short8*)&AS[0][ar0][ch0];
    short8 aE1 = *(const short8*)&AS[0][ar1][ch0];
    short8 aO0, aO1;
    short8 b0f[4], b1f[4];
    b0f[0] = *(const short8*)&BS[0][br0][ch0];
    b0f[1] = *(const short8*)&BS[0][br1][ch0];
    b0f[2] = *(const short8*)&BS[0][br2][ch0];
    b0f[3] = *(const short8*)&BS[0][br3][ch0];

    for (int t = 0; t < NT; ++t) {
        const int rs = t % 3;
        const int ss = (t + 2) % 3;
        const bool pf = (t + 2 < NT);
        const unsigned short* gat = ga + (t + 2) * 64;
        const unsigned short* gbt = gb + (t + 2) * 64;

        aO0 = *(const short8*)&AS[rs][ar2][ch0];
        aO1 = *(const short8*)&AS[rs][ar3][ch0];
        if (pf) {
            gload_lds16(gat,                      (unsigned short*)AS[ss] + 0 * 4096 + tid * 8);
            gload_lds16(gat + (size_t)64 * K,     (unsigned short*)AS[ss] + 1 * 4096 + tid * 8);
        }
        __builtin_amdgcn_s_setprio(1);
        #pragma unroll
        for (int j = 0; j < 4; ++j)
            acc[0][j] = __builtin_amdgcn_mfma_f32_16x16x32_bf16(aE0, b0f[j], acc[0][j], 0, 0, 0);
        #pragma unroll
        for (int j = 0; j < 4; ++j)
            acc[1][j] = __builtin_amdgcn_mfma_f32_16x16x32_bf16(aE1, b0f[j], acc[1][j], 0, 0, 0);
        __builtin_amdgcn_s_setprio(0);
        __builtin_amdgcn_s_barrier();

        aE0 = *(const short8*)&AS[rs][ar0][ch1];
        aE1 = *(const short8*)&AS[rs][ar1][ch1];
        b1f[0] = *(const short8*)&BS[rs][br0][ch1];
        b1f[1] = *(const short8*)&BS[rs][br1][ch1];
        b1f[2] = *(const short8*)&BS[rs][br2][ch1];
        b1f[3] = *(const short8*)&BS[rs][br3][ch1];
        if (pf) {
            gload_lds16(gat + (size_t)128 * K,    (unsigned short*)AS[ss] + 2 * 4096 + tid * 8);
            gload_lds16(gat + (size_t)192 * K,    (unsigned short*)AS[ss] + 3 * 4096 + tid * 8);
        }
        __builtin_amdgcn_s_setprio(1);
        #pragma unroll
        for (int j = 0; j < 4; ++j)
            acc[2][j] = __builtin_amdgcn_mfma_f32_16x16x32_bf16(aO0, b0f[j], acc[2][j], 0, 0, 0);
        #pragma unroll
        for (int j = 0; j < 4; ++j)
            acc[3][j] = __builtin_amdgcn_mfma_f32_16x16x32_bf16(aO1, b0f[j], acc[3][j], 0, 0, 0);
        __builtin_amdgcn_s_setprio(0);
        __builtin_amdgcn_s_barrier();

        aO0 = *(const short8*)&AS[rs][ar2][ch1];
        aO1 = *(const short8*)&AS[rs][ar3][ch1];
        if (pf)
            gload_lds16(gbt,                      (unsigned short*)BS[ss] + 0 * 4096 + tid * 8);
        __builtin_amdgcn_s_setprio(1);
        #pragma unroll
        for (int j = 0; j < 4; ++j)
            acc[0][j] = __builtin_amdgcn_mfma_f32_16x16x32_bf16(aE0, b1f[j], acc[0][j], 0, 0, 0);
        #pragma unroll
        for (int j = 0; j < 4; ++j)
            acc[1][j] = __builtin_amdgcn_mfma_f32_16x16x32_bf16(aE1, b1f[j], acc[1][j], 0, 0, 0);
        __builtin_amdgcn_s_setprio(0);
        __builtin_amdgcn_s_barrier();

        if (pf)
            gload_lds16(gbt + (size_t)64 * K,     (unsigned short*)BS[ss] + 1 * 4096 + tid * 8);
        __builtin_amdgcn_s_setprio(1);
        #pragma unroll
        for (int j = 0; j < 4; ++j)
            acc[2][j] = __builtin_amdgcn_mfma_f32_16x16x32_bf16(aO0, b1f[j], acc[2][j], 0, 0, 0);
        #pragma unroll
        for (int j = 0; j < 4; ++j)
            acc[3][j] = __builtin_amdgcn_mfma_f32_16x16x32_bf16(aO1, b1f[j], acc[3][j], 0, 0, 0);
        __builtin_amdgcn_s_setprio(0);
        if (pf) { asm volatile("s_waitcnt vmcnt(6)" ::: "memory"); }
        else    { asm volatile("s_waitcnt vmcnt(0)" ::: "memory"); }
        __builtin_amdgcn_s_barrier();

        if (t + 1 < NT) {
            const int rs2 = (t + 1) % 3;
            aE0 = *(const short8*)&AS[rs2][ar0][ch0];
            aE1 = *(const short8*)&AS[rs2][ar1][ch0];
            b0f[0] = *(const short8*)&BS[rs2][br0][ch0];
            b0f[1] = *(const short8*)&BS[rs2][br1][ch0];
            b0f[2] = *(const short8*)&BS[rs2][br2][ch0];
            b0f[3] = *(const short8*)&BS[rs2][br3][ch0];
        }
    }

    #pragma unroll
    for (int i = 0; i < 4; ++i) {
        #pragma unroll
        for (int j = 0; j < 4; ++j) {
            #pragma unroll
            for (int r = 0; r < 4; ++r) {
                int row = row0 + wm * 64 + i * 16 + g * 4 + r;
                int col = col0 + wn * 64 + j * 16 + l16;
                float v = acc[i][j][r];
                if (bias) v += bias[col];
                if (relu) v = fmaxf(v, 0.f);
                if (OUT_BF16) ((unsigned short*)Cout)[(size_t)row * N + col] = f2bf(v);
                else          ((float*)Cout)[(size_t)row * N + col] = v;
            }
        }
    }
}

// ---------------- MFMA flash attention (paired q-tiles + async reg-stage) ----------------
__global__ __launch_bounds__(256)
void attn_flash_k(const unsigned short* __restrict__ qkv, unsigned short* __restrict__ out)
{
    __shared__ unsigned short Ks[64][72];
    __shared__ unsigned short Vt[64][72];
    __shared__ unsigned short Ps[4][16][72];

    const int tid = threadIdx.x;
    const int lane = tid & 63;
    const int w = tid >> 6;
    const int l16 = lane & 15, g = lane >> 4;
    const int h = blockIdx.y;
    const int b = blockIdx.z;

    const size_t rstr = 3 * DM;
    const unsigned short* base = qkv + (size_t)b * TSEQ * rstr + h * HDIM;

    const int krow0 = tid >> 3, kcol = (tid & 7) * 8;
    const int vkv = tid & 63, vdg = tid >> 6;

    short8 kreg0, kreg1, vreg0, vreg1;

    #pragma unroll
    for (int pass = 0; pass < 2; ++pass) {
        const int qb = pass ? (15 - (int)blockIdx.x) : (int)blockIdx.x;
        const int q0 = qb * 64;
        const int nt = qb + 1;

        const int qrow_w = q0 + w * 16 + l16;
        short8 aq0 = *(const short8*)(base + (size_t)qrow_w * rstr + g * 8);
        short8 aq1 = *(const short8*)(base + (size_t)qrow_w * rstr + 32 + g * 8);

        f32x4 acc_o[4] = {};
        float m_r[4] = {-INFINITY, -INFINITY, -INFINITY, -INFINITY};
        float l_r[4] = {};

        {
            const unsigned short* kb = base + DM;
            kreg0 = *(const short8*)(kb + (size_t)krow0 * rstr + kcol);
            kreg1 = *(const short8*)(kb + (size_t)(32 + krow0) * rstr + kcol);
            const unsigned short* vsrc = base + (size_t)vkv * rstr + 2 * DM + vdg * 16;
            vreg0 = *(const short8*)vsrc;
            vreg1 = *(const short8*)(vsrc + 8);
        }

        for (int t = 0; t < nt; ++t) {
            *(short8*)&Ks[krow0][kcol] = kreg0;
            *(short8*)&Ks[32 + krow0][kcol] = kreg1;
            #pragma unroll
            for (int j = 0; j < 8; ++j) Vt[vdg * 16 + j][vkv] = (unsigned short)vreg0[j];
            #pragma unroll
            for (int j = 0; j < 8; ++j) Vt[vdg * 16 + 8 + j][vkv] = (unsigned short)vreg1[j];
            __syncthreads();

            if (t + 1 < nt) {
                const int kv0n = (t + 1) * 64;
                const unsigned short* kb = base + (size_t)kv0n * rstr + DM;
                kreg0 = *(const short8*)(kb + (size_t)krow0 * rstr + kcol);
                kreg1 = *(const short8*)(kb + (size_t)(32 + krow0) * rstr + kcol);
                const unsigned short* vsrc = base + (size_t)(kv0n + vkv) * rstr + 2 * DM + vdg * 16;
                vreg0 = *(const short8*)vsrc;
                vreg1 = *(const short8*)(vsrc + 8);
            }

            const int kv0 = t * 64;
            f32x4 acc_s[4] = {};
            #pragma unroll
            for (int ks = 0; ks < 4; ++ks) {
                short8 bk0 = *(const short8*)&Ks[ks * 16 + l16][g * 8];
                short8 bk1 = *(const short8*)&Ks[ks * 16 + l16][32 + g * 8];
                acc_s[ks] = __builtin_amdgcn_mfma_f32_16x16x32_bf16(aq0, bk0, acc_s[ks], 0, 0, 0);
                acc_s[ks] = __builtin_amdgcn_mfma_f32_16x16x32_bf16(aq1, bk1, acc_s[ks], 0, 0, 0);
            }
            const bool need_mask = (kv0 + 63 > q0 + w * 16);
            float alpha[4];
            #pragma unroll
            for (int r = 0; r < 4; ++r) {
                const int q_abs = q0 + w * 16 + g * 4 + r;
                float s[4];
                #pragma unroll
                for (int ks = 0; ks < 4; ++ks) {
                    s[ks] = acc_s[ks][r] * 0.125f;
                    if (need_mask && (kv0 + ks * 16 + l16 > q_abs)) s[ks] = -INFINITY;
                }
                float pm = fmaxf(fmaxf(s[0], s[1]), fmaxf(s[2], s[3]));
                #pragma unroll
                for (int msk = 1; msk <= 8; msk <<= 1)
                    pm = fmaxf(pm, __shfl_xor(pm, msk));
                float mnew = fmaxf(m_r[r], pm);
                alpha[r] = __expf(m_r[r] - mnew);
                m_r[r] = mnew;
                float p[4], psum = 0.f;
                #pragma unroll
                for (int ks = 0; ks < 4; ++ks) {
                    p[ks] = (s[ks] == -INFINITY) ? 0.f : __expf(s[ks] - mnew);
                    psum += p[ks];
                }
                #pragma unroll
                for (int msk = 1; msk <= 8; msk <<= 1)
                    psum += __shfl_xor(psum, msk);
                l_r[r] = l_r[r] * alpha[r] + psum;
                #pragma unroll
                for (int ks = 0; ks < 4; ++ks)
                    Ps[w][g * 4 + r][ks * 16 + l16] = f2bf(p[ks]);
            }
            #pragma unroll
            for (int ds = 0; ds < 4; ++ds)
                #pragma unroll
                for (int r = 0; r < 4; ++r)
                    acc_o[ds][r] *= alpha[r];
            short8 ap0 = *(const short8*)&Ps[w][l16][g * 8];
            short8 ap1 = *(const short8*)&Ps[w][l16][32 + g * 8];
            #pragma unroll
            for (int ds = 0; ds < 4; ++ds) {
                short8 bv0 = *(const short8*)&Vt[ds * 16 + l16][g * 8];
                short8 bv1 = *(const short8*)&Vt[ds * 16 + l16][32 + g * 8];
                acc_o[ds] = __builtin_amdgcn_mfma_f32_16x16x32_bf16(ap0, bv0, acc_o[ds], 0, 0, 0);
                acc_o[ds] = __builtin_amdgcn_mfma_f32_16x16x32_bf16(ap1, bv1, acc_o[ds], 0, 0, 0);
            }
            __syncthreads();
        }

        #pragma unroll
        for (int ds = 0; ds < 4; ++ds)
            #pragma unroll
            for (int r = 0; r < 4; ++r) {
                int row = q0 + w * 16 + g * 4 + r;
                out[((size_t)b * TSEQ + row) * DM + h * HDIM + ds * 16 + l16] =
                    f2bf(acc_o[ds][r] * (1.f / l_r[r]));
            }
    }
}

// ---------------- orchestration ----------------
extern "C" void kernel_launch(void* const* d_in, const int* in_sizes, int n_in,
                              void* d_out, int out_size, void* d_ws, size_t ws_size,
                              hipStream_t stream)
{
    const int*   idx    = (const int*)  d_in[0];
    const float* embed  = (const float*)d_in[1];
    const float* Wqkv   = (const float*)d_in[2];
    const float* Wproj  = (const float*)d_in[3];
    const float* bproj  = (const float*)d_in[4];
    const float* ln1_g  = (const float*)d_in[5];
    const float* ln1_b  = (const float*)d_in[6];
    const float* ln2_g  = (const float*)d_in[7];
    const float* ln2_b  = (const float*)d_in[8];
    const float* W1     = (const float*)d_in[9];
    const float* b1     = (const float*)d_in[10];
    const float* W2     = (const float*)d_in[11];
    const float* b2     = (const float*)d_in[12];
    const float* lnf_g  = (const float*)d_in[13];
    const float* lnf_b  = (const float*)d_in[14];
    const float* Whead  = (const float*)d_in[15];
    float* out = (float*)d_out;

    float* X = (float*)d_ws;
    float* PK = X + (size_t)NROWS * DM;
    unsigned short* u = (unsigned short*)(PK + (size_t)4 * NROWS * DM);
    unsigned short* XN     = u;  u += (size_t)NROWS * DM;
    unsigned short* QKVb   = u;  u += (size_t)NROWS * 3 * DM;
    unsigned short* ATT    = u;  u += (size_t)NROWS * DM;
    unsigned short* FFH    = u;  u += (size_t)NROWS * DFFN;
    unsigned short* WqkvT  = u;  u += (size_t)NLAYER * 3 * DM * DM;
    unsigned short* WprojT = u;  u += (size_t)NLAYER * DM * DM;
    unsigned short* W1T    = u;  u += (size_t)NLAYER * DFFN * DM;
    unsigned short* W2T    = u;  u += (size_t)NLAYER * DM * DFFN;
    unsigned short* WheadT = u;  u += (size_t)NVOC * DM;

    convt_k<<<dim3(3 * DM / 64, DM / 64, NLAYER), 256, 0, stream>>>(Wqkv,  WqkvT,  DM,   3 * DM);
    convt_k<<<dim3(DM / 64,     DM / 64, NLAYER), 256, 0, stream>>>(Wproj, WprojT, DM,   DM);
    convt_k<<<dim3(DFFN / 64,   DM / 64, NLAYER), 256, 0, stream>>>(W1,    W1T,    DM,   DFFN);
    convt_k<<<dim3(DM / 64,   DFFN / 64, NLAYER), 256, 0, stream>>>(W2,    W2T,    DFFN, DM);
    convt_k<<<dim3(NVOC / 64,   DM / 64, 1),      256, 0, stream>>>(Whead, WheadT, DM,   NVOC);

    embed_pos_k<<<NROWS, 256, 0, stream>>>(idx, embed, X);
    layernorm_k<<<NROWS, 256, 0, stream>>>(X, ln1_g, ln1_b, XN);   // layer-0 ln1

    for (int l = 0; l < NLAYER; ++l) {
        const unsigned short* wqkvT_l  = WqkvT  + (size_t)l * 3 * DM * DM;
        const unsigned short* wprojT_l = WprojT + (size_t)l * DM * DM;
        const unsigned short* w1T_l    = W1T    + (size_t)l * DFFN * DM;
        const unsigned short* w2T_l    = W2T    + (size_t)l * DM * DFFN;
        const float* bproj_l = bproj + (size_t)l * DM;
        const float* b1_l = b1 + (size_t)l * DFFN;
        const float* b2_l = b2 + (size_t)l * DM;

        {   // qkv = ln1(x) @ Wqkv  (bf16 out), gemm256: 192 blocks
            int nwg = (NROWS / 256) * (3 * DM / 128);
            gemm256<true><<<nwg, 512, 0, stream>>>(XN, wqkvT_l, nullptr,
                                                   QKVb, NROWS, 3 * DM, DM, 0);
        }
        {   // flash attention (paired q-tiles)
            dim3 grid(TSEQ / 128, NHEAD, NB);
            attn_flash_k<<<grid, 256, 0, stream>>>(QKVb, ATT);
        }
        {   // proj: split-K=2 -> partials; fused reduce + residual + bias + ln2
            dim3 grid((NROWS / 128) * (DM / 128), 2);
            gemm_tn<128, false><<<grid, 256, 0, stream>>>(ATT, wprojT_l, nullptr, nullptr,
                                                          PK, NROWS, DM, 512, DM, 0);
            reduce_ln_k<<<NROWS, 256, 0, stream>>>(PK, 2, bproj_l, X,
                                                   ln2_g + (size_t)l * DM,
                                                   ln2_b + (size_t)l * DM, XN);
        }
        {   // ffh = relu(ln2 @ W1 + b1): gemm256, 256 blocks
            int nwg = (NROWS / 256) * (DFFN / 128);
            gemm256<true><<<nwg, 512, 0, stream>>>(XN, w1T_l, b1_l,
                                                   FFH, NROWS, DFFN, DM, 1);
        }
        {   // ffn2: split-K=4 -> partials; fused reduce + residual + bias + ln1[l+1]/lnf
            dim3 grid((NROWS / 128) * (DM / 128), 4);
            gemm_tn<128, false><<<grid, 256, 0, stream>>>(FFH, w2T_l, nullptr, nullptr,
                                                          PK, NROWS, DM, 1024, DFFN, 0);
            const float* ng = (l + 1 < NLAYER) ? ln1_g + (size_t)(l + 1) * DM : lnf_g;
            const float* nb = (l + 1 < NLAYER) ? ln1_b + (size_t)(l + 1) * DM : lnf_b;
            reduce_ln_k<<<NROWS, 256, 0, stream>>>(PK, 4, b2_l, X, ng, nb, XN);
        }
    }

    {   // logits = lnf(x) @ Whead: ring-3 gemm_tn, 4000 blocks
        int nwg = (NROWS / 128) * (NVOC / 128);
        gemm_tn<128, false><<<nwg, 256, 0, stream>>>(XN, WheadT, nullptr, nullptr,
                                                     out, NROWS, NVOC, DM, DM, 0);
    }
}